// Round 2
// baseline (642.928 us; speedup 1.0000x reference)
//
#include <hip/hip_runtime.h>
#include <math.h>

#define BB 64
#define N1 201
#define DD 128
#define HALF 100
#define NN (N1*N1)
#define NEGV (-1e20f)
#define QSCALE 0.08838834764831845f  /* 1/sqrt(128) */
#define TCH 7
#define SCH 29   /* ceil(201/7) */

/* ws offsets in floats */
#define OFF_M    0u          /* 12 * 16384 = 196608 : Mrm[0..3], N1m[4..7], N2m[8..11] */
#define OFF_G    196608u     /* 64*128 */
#define OFF_HHAT 204800u     /* 64*201*128 = 1646592 */
#define OFF_A    1851392u    /* 4*64*201*128 = 6586368 */
#define OFF_Q    8437760u    /* 16*64*128 = 131072 */
#define OFF_ROWH 8568832u    /* 64*201*32 = 411648 */
#define OFF_COLH 8980480u    /* 411648 */
#define OFF_SC   9392128u    /* int a1[64], pp[64], pd[64]; float ll1[64] */
#define OFF_PM   9392384u    /* 64*29 */
#define OFF_PS   9394240u
#define OFF_PI   9396096u

/* ---- M_h = WQ_h @ WK_h^T for 12 (mat,head) combos ---- */
__global__ void kprep(const float* rmWQ, const float* rmWK,
                      const float* i1Wq, const float* i1Wk,
                      const float* i2Wq, const float* i2Wk, float* ws) {
    int bid = blockIdx.x;
    int m = bid >> 7;        /* 0..11 */
    int i = bid & 127;       /* row */
    int j = threadIdx.x;     /* col */
    const float* WQ; const float* WK;
    if (m < 4)      { WQ = rmWQ + m*16384;     WK = rmWK + m*16384; }
    else if (m < 8) { WQ = i1Wq + (m-4)*16384; WK = i1Wk + (m-4)*16384; }
    else            { WQ = i2Wq + (m-8)*16384; WK = i2Wk + (m-8)*16384; }
    __shared__ float lq[128];
    lq[j] = WQ[i*128 + j];
    __syncthreads();
    const float* wkr = WK + j*128;
    float acc = 0.f;
    #pragma unroll 8
    for (int e = 0; e < 128; ++e) acc += lq[e] * wkr[e];
    ws[OFF_M + m*16384 + i*128 + j] = acc;
}

/* ---- h_max over N1, then g = h_max @ Wg ---- */
__global__ void khmaxg(const float* hw, const float* Wg, float* ws) {
    int b = blockIdx.x, d = threadIdx.x;
    __shared__ float hm[128];
    float m = -INFINITY;
    const float* p = hw + b*N1*DD + d;
    for (int n = 0; n < N1; ++n) m = fmaxf(m, p[n*DD]);
    hm[d] = m;
    __syncthreads();
    float acc = 0.f;
    for (int k = 0; k < 128; ++k) acc += hm[k] * Wg[k*128 + d];
    ws[OFF_G + b*128 + d] = acc;
}

/* ---- h_hat = h_wave @ Wn + g (16-row tiles) ---- */
__global__ void khhat(const float* hw, const float* Wn, float* ws) {
    int bid = blockIdx.x;
    int b = bid / 13, rt = bid % 13, r0 = rt*16, d = threadIdx.x;
    __shared__ float xs[16][128];
    for (int r = 0; r < 16; ++r) {
        int n = r0 + r; if (n > 200) n = 200;
        xs[r][d] = hw[(b*N1 + n)*DD + d];
    }
    __syncthreads();
    float gv = ws[OFF_G + b*128 + d];
    float acc[16];
    #pragma unroll
    for (int r = 0; r < 16; ++r) acc[r] = gv;
    for (int k = 0; k < 128; ++k) {
        float wv = Wn[k*128 + d];
        #pragma unroll
        for (int r = 0; r < 16; ++r) acc[r] += xs[r][k] * wv;
    }
    for (int r = 0; r < 16; ++r) {
        int n = r0 + r;
        if (n < N1) ws[OFF_HHAT + (b*N1 + n)*DD + d] = acc[r];
    }
}

/* ---- A[h] = h_hat @ Mrm[h] ---- */
__global__ void kA(float* ws) {
    int bid = blockIdx.x;
    int h = bid / (64*13);
    int rem = bid % (64*13);
    int b = rem / 13, rt = rem % 13, r0 = rt*16, d = threadIdx.x;
    const float* hhat = ws + OFF_HHAT;
    const float* M = ws + OFF_M + h*16384;
    __shared__ float xs[16][128];
    for (int r = 0; r < 16; ++r) {
        int n = r0 + r; if (n > 200) n = 200;
        xs[r][d] = hhat[(b*N1 + n)*DD + d];
    }
    __syncthreads();
    float acc[16];
    #pragma unroll
    for (int r = 0; r < 16; ++r) acc[r] = 0.f;
    for (int k = 0; k < 128; ++k) {
        float wv = M[k*128 + d];
        #pragma unroll
        for (int r = 0; r < 16; ++r) acc[r] += xs[r][k] * wv;
    }
    float* A = ws + OFF_A;
    for (int r = 0; r < 16; ++r) {
        int n = r0 + r;
        if (n < N1) A[((h*64 + b)*N1 + n)*DD + d] = acc[r];
    }
}

/* ---- removal: comp -> feat -> MLP -> t1 -> softmax/argmax ---- */
__global__ void kremoval(const float* sel, const int* solution, const int* pre_action,
                         const float* w1g, const float* b1g, const float* w2g,
                         const float* b2g, const float* w3g, const float* b3g, float* ws) {
    int b = blockIdx.x, t = threadIdx.x;
    __shared__ int sol[201], pre[201], post[201];
    __shared__ float cmp_[4*200];
    __shared__ float w1[384], b1[32], w2[1024], b2[32], w3[32];
    __shared__ float t1l[100];
    if (t < 201) sol[t] = solution[b*N1 + t];
    for (int idx = t; idx < 384;  idx += 256) w1[idx] = w1g[idx];
    for (int idx = t; idx < 1024; idx += 256) w2[idx] = w2g[idx];
    if (t < 32) { b1[t] = b1g[t]; b2[t] = b2g[t]; w3[t] = w3g[t]; }
    __syncthreads();
    if (t < 201) { pre[sol[t]] = t; post[t] = sol[sol[t]]; }
    __syncthreads();
    const float* hhat = ws + OFF_HHAT + b*N1*DD;
    const float* A = ws + OFF_A;
    int wave = t >> 6, lane = t & 63;
    for (int n = 1 + wave; n <= 200; n += 4) {
        int pn = pre[n], po = post[n];
        const float* xn = hhat + n*DD;
        const float* xp = hhat + po*DD;
        float xn0 = xn[lane], xn1 = xn[lane+64];
        float xp0 = xp[lane], xp1 = xp[lane+64];
        float d0 = xn0 - xp0, d1 = xn1 - xp1;
        #pragma unroll
        for (int h = 0; h < 4; ++h) {
            const float* Ab = A + ((h*64 + b)*N1)*DD;
            const float* Ap = Ab + pn*DD;
            const float* An = Ab + n*DD;
            float v = Ap[lane]*d0 + Ap[lane+64]*d1 + An[lane]*xp0 + An[lane+64]*xp1;
            #pragma unroll
            for (int off = 32; off; off >>= 1) v += __shfl_xor(v, off);
            if (lane == 0) cmp_[h*200 + n - 1] = v;
        }
    }
    __syncthreads();
    if (t < 100) {
        int i = t;
        float f[12];
        #pragma unroll
        for (int h = 0; h < 4; ++h) { f[h] = cmp_[h*200 + i]; f[4+h] = cmp_[h*200 + 100 + i]; }
        #pragma unroll
        for (int s = 0; s < 4; ++s) f[8+s] = sel[b*400 + s*100 + i];
        float h1[32];
        #pragma unroll
        for (int k = 0; k < 32; ++k) {
            float a = b1[k];
            #pragma unroll
            for (int j = 0; j < 12; ++j) a += f[j]*w1[j*32 + k];
            h1[k] = fmaxf(a, 0.f);
        }
        float out = b3g[0];
        for (int j = 0; j < 32; ++j) {
            float a = b2[j];
            #pragma unroll
            for (int k = 0; k < 32; ++k) a += h1[k]*w2[k*32 + j];
            out += fmaxf(a, 0.f)*w3[j];
        }
        t1l[i] = tanhf(out)*6.0f;
    }
    __syncthreads();
    if (t == 0) {
        if (pre_action[0] > 0) {            /* pre_action[0,0] gates ALL batches */
            int ib = pre_action[b*2];
            t1l[ib] = NEGV;
        }
        float M = -INFINITY; int a1 = 0;
        for (int i = 0; i < 100; ++i) if (t1l[i] > M) { M = t1l[i]; a1 = i; }
        float S = 0.f;
        for (int i = 0; i < 100; ++i) S += expf(t1l[i] - M);
        float ll1 = -logf(S);
        int* ia = (int*)(ws + OFF_SC);
        ia[b] = a1; ia[64 + b] = 1 + a1; ia[128 + b] = 101 + a1;
        ws[OFF_SC + 192 + b] = ll1;
    }
}

/* ---- 16 query vectors per batch: (h_p|h_d) @ N{1,2}[h] * scale ---- */
__global__ void kqvec(float* ws) {
    int b = blockIdx.x, j = threadIdx.x;
    const int* ia = (const int*)(ws + OFF_SC);
    int pp = ia[64 + b], pd = ia[128 + b];
    __shared__ float xp[128], xd[128];
    const float* hhat = ws + OFF_HHAT + b*N1*DD;
    xp[j] = hhat[pp*DD + j];
    xd[j] = hhat[pd*DD + j];
    __syncthreads();
    float* q = ws + OFF_Q;
    #pragma unroll
    for (int h = 0; h < 4; ++h) {
        const float* M1 = ws + OFF_M + (4 + h)*16384;
        const float* M2 = ws + OFF_M + (8 + h)*16384;
        float a1p = 0, a2p = 0, a1d = 0, a2d = 0;
        for (int i = 0; i < 128; ++i) {
            float w1v = M1[i*128 + j], w2v = M2[i*128 + j];
            a1p += xp[i]*w1v; a1d += xd[i]*w1v;
            a2p += xp[i]*w2v; a2d += xd[i]*w2v;
        }
        q[((0*4 + h)*64 + b)*128 + j] = a1p*QSCALE;  /* c1: q1p */
        q[((1*4 + h)*64 + b)*128 + j] = a2p*QSCALE;  /* c2: q2p */
        q[((2*4 + h)*64 + b)*128 + j] = a1d*QSCALE;  /* c3: q1d */
        q[((3*4 + h)*64 + b)*128 + j] = a2d*QSCALE;  /* c4: q2d */
    }
}

/* ---- c1..c4 dots -> rowH/colH (first reinsertion-MLP layer, separable part) ---- */
__global__ void krowcol(const int* solution, const float* w1g, float* ws) {
    int b = blockIdx.x, t = threadIdx.x;
    __shared__ float qv[2048];
    __shared__ float carr[16*201];
    __shared__ int sol[201];
    __shared__ float w1l[512];
    const float* q = ws + OFF_Q;
    for (int idx = t; idx < 2048; idx += 256)
        qv[idx] = q[((idx >> 7)*64 + b)*128 + (idx & 127)];
    for (int idx = t; idx < 512; idx += 256) w1l[idx] = w1g[idx];
    if (t < 201) sol[t] = solution[b*N1 + t];
    __syncthreads();
    const float* hhat = ws + OFF_HHAT + b*N1*DD;
    for (int idx = t; idx < 16*201; idx += 256) {
        int j = idx / 201, n = idx % 201;      /* consecutive threads: same j -> qv broadcast */
        int kind = j >> 2;
        int row = (kind & 1) ? sol[n] : n;     /* kinds 1,3 use h_nb rows */
        const float* xr = hhat + row*DD;
        const float* qp = qv + j*128;
        float acc = 0.f;
        for (int e = 0; e < 128; ++e) acc += qp[e]*xr[e];
        carr[j*201 + n] = acc;
    }
    __syncthreads();
    float* rowH = ws + OFF_ROWH + b*N1*32;
    float* colH = ws + OFF_COLH + b*N1*32;
    for (int idx = t; idx < N1*32; idx += 256) {
        int n = idx >> 5, k = idx & 31;
        float rh = 0, ch = 0;
        #pragma unroll
        for (int j = 0; j < 8; ++j)  rh += carr[j*201 + n]*w1l[j*32 + k];
        #pragma unroll
        for (int j = 8; j < 16; ++j) ch += carr[j*201 + n]*w1l[j*32 + k];
        rowH[idx] = rh; colH[idx] = ch;
    }
}

/* ---- t2 cells + online softmax partials (7 rows x 201 cols per block) ---- */
__global__ void kt2(const unsigned char* maskt, const float* b1g, const float* w2g,
                    const float* b2g, const float* w3g, const float* b3g, float* ws) {
    int bid = blockIdx.x;
    int b = bid / SCH, ct = bid % SCH, r0 = ct*TCH;
    int t = threadIdx.x;
    __shared__ float colHs[201*33];   /* stride 33: consecutive c -> distinct banks */
    __shared__ float rowHt[TCH*32];
    __shared__ float w2l[1024], b2l[32], w3l[32];
    __shared__ float redm[256], reds[256];
    __shared__ int redi[256];
    const float* colH = ws + OFF_COLH + b*N1*32;
    for (int idx = t; idx < N1*32; idx += 256) {
        int c = idx >> 5, k = idx & 31;
        colHs[c*33 + k] = colH[idx];
    }
    for (int idx = t; idx < TCH*32; idx += 256) {
        int r = idx >> 5, k = idx & 31, R = r0 + r;
        rowHt[idx] = (R < N1 ? ws[OFF_ROWH + b*N1*32 + R*32 + k] : 0.f) + b1g[k];
    }
    for (int idx = t; idx < 1024; idx += 256) w2l[idx] = w2g[idx];
    if (t < 32) { b2l[t] = b2g[t]; w3l[t] = w3g[t]; }
    __syncthreads();
    float b3v = b3g[0];
    float m = -INFINITY, s = 0.f;
    int mi = 0x7fffffff;
    for (int cc = t; cc < TCH*N1; cc += 256) {
        int r = cc / 201, c = cc - r*201;
        int R = r0 + r;
        if (R >= N1) break;               /* r nondecreasing in cc */
        float h1[32];
        #pragma unroll
        for (int k = 0; k < 32; ++k)
            h1[k] = fmaxf(rowHt[r*32 + k] + colHs[c*33 + k], 0.f);
        float out = b3v;
        for (int j = 0; j < 32; ++j) {
            float a = b2l[j];
            #pragma unroll
            for (int k = 0; k < 32; ++k) a += h1[k]*w2l[k*32 + j];
            out += fmaxf(a, 0.f)*w3l[j];
        }
        float tv = tanhf(out)*6.0f;
        if (maskt[b*NN + R*N1 + c]) tv = NEGV;
        if (tv > m) { s = s*expf(m - tv) + 1.f; m = tv; mi = R*N1 + c; }
        else        { s += expf(tv - m); }
    }
    redm[t] = m; reds[t] = s; redi[t] = mi;
    __syncthreads();
    for (int off = 128; off > 0; off >>= 1) {
        if (t < off) {
            float ma = redm[t], mb = redm[t+off];
            float sa = reds[t], sb = reds[t+off];
            int ia = redi[t], ib = redi[t+off];
            float M2 = fmaxf(ma, mb);
            float sn = (sa > 0.f ? sa*expf(ma - M2) : 0.f)
                     + (sb > 0.f ? sb*expf(mb - M2) : 0.f);
            int in_;
            if (ma > mb) in_ = ia; else if (mb > ma) in_ = ib; else in_ = (ia < ib ? ia : ib);
            redm[t] = M2; reds[t] = sn; redi[t] = in_;
        }
        __syncthreads();
    }
    if (t == 0) {
        ws[OFF_PM + b*SCH + ct] = redm[0];
        ws[OFF_PS + b*SCH + ct] = reds[0];
        ((int*)(ws + OFF_PI))[b*SCH + ct] = redi[0];
    }
}

/* ---- final reduce + outputs ---- */
__global__ void kfinal(float* out, float* ws) {
    int b = blockIdx.x, lane = threadIdx.x;
    float m = -INFINITY, s = 0.f;
    int mi = 0x7fffffff;
    if (lane < SCH) {
        m = ws[OFF_PM + b*SCH + lane];
        s = ws[OFF_PS + b*SCH + lane];
        mi = ((const int*)(ws + OFF_PI))[b*SCH + lane];
    }
    for (int off = 32; off; off >>= 1) {
        float om = __shfl_xor(m, off);
        float os = __shfl_xor(s, off);
        int oi = __shfl_xor(mi, off);
        float M2 = fmaxf(m, om);
        float sn = (s > 0.f ? s*expf(m - M2) : 0.f)
                 + (os > 0.f ? os*expf(om - M2) : 0.f);
        int in_;
        if (m > om) in_ = mi; else if (om > m) in_ = oi; else in_ = (mi < oi ? mi : oi);
        m = M2; s = sn; mi = in_;
    }
    if (lane == 0) {
        float ll2 = -logf(s);
        const int* ia = (const int*)(ws + OFF_SC);
        int a1 = ia[b];
        float ll1 = ws[OFF_SC + 192 + b];
        out[b*3 + 0] = (float)a1;
        out[b*3 + 1] = (float)(mi / N1);
        out[b*3 + 2] = (float)(mi % N1);
        out[192 + b] = ll1 + ll2;
    }
}

extern "C" void kernel_launch(void* const* d_in, const int* in_sizes, int n_in,
                              void* d_out, int out_size, void* d_ws, size_t ws_size,
                              hipStream_t stream) {
    const float* h_wave    = (const float*)d_in[0];
    const int*   solution  = (const int*)d_in[1];
    const float* sel       = (const float*)d_in[2];
    const int*   pre_act   = (const int*)d_in[3];
    const unsigned char* maskt = (const unsigned char*)d_in[4];
    const float* Wn    = (const float*)d_in[5];
    const float* Wg    = (const float*)d_in[6];
    const float* rmWQ  = (const float*)d_in[7];
    const float* rmWK  = (const float*)d_in[8];
    const float* rm_w1 = (const float*)d_in[9];
    const float* rm_b1 = (const float*)d_in[10];
    const float* rm_w2 = (const float*)d_in[11];
    const float* rm_b2 = (const float*)d_in[12];
    const float* rm_w3 = (const float*)d_in[13];
    const float* rm_b3 = (const float*)d_in[14];
    const float* i1Wq  = (const float*)d_in[15];
    const float* i1Wk  = (const float*)d_in[16];
    const float* i2Wq  = (const float*)d_in[17];
    const float* i2Wk  = (const float*)d_in[18];
    const float* re_w1 = (const float*)d_in[19];
    const float* re_b1 = (const float*)d_in[20];
    const float* re_w2 = (const float*)d_in[21];
    const float* re_b2 = (const float*)d_in[22];
    const float* re_w3 = (const float*)d_in[23];
    const float* re_b3 = (const float*)d_in[24];
    float* ws = (float*)d_ws;
    float* out = (float*)d_out;

    kprep<<<dim3(1536), dim3(128), 0, stream>>>(rmWQ, rmWK, i1Wq, i1Wk, i2Wq, i2Wk, ws);
    khmaxg<<<dim3(64), dim3(128), 0, stream>>>(h_wave, Wg, ws);
    khhat<<<dim3(64*13), dim3(128), 0, stream>>>(h_wave, Wn, ws);
    kA<<<dim3(4*64*13), dim3(128), 0, stream>>>(ws);
    kremoval<<<dim3(64), dim3(256), 0, stream>>>(sel, solution, pre_act,
                                                 rm_w1, rm_b1, rm_w2, rm_b2, rm_w3, rm_b3, ws);
    kqvec<<<dim3(64), dim3(128), 0, stream>>>(ws);
    krowcol<<<dim3(64), dim3(256), 0, stream>>>(solution, re_w1, ws);
    kt2<<<dim3(64*SCH), dim3(256), 0, stream>>>(maskt, re_b1, re_w2, re_b2, re_w3, re_b3, ws);
    kfinal<<<dim3(64), dim3(64), 0, stream>>>(out, ws);
}

// Round 3
// 513.010 us; speedup vs baseline: 1.2532x; 1.2532x over previous
//
#include <hip/hip_runtime.h>
#include <math.h>

#define BB 64
#define N1 201
#define DD 128
#define HALF 100
#define NN (N1*N1)
#define NEGV (-1e20f)
#define QSCALE 0.08838834764831845f  /* 1/sqrt(128) */

/* ws offsets in floats */
#define OFF_M    0u          /* 12*16384 */
#define OFF_PMAX 196608u     /* 64*4*128 */
#define OFF_HHAT 229376u     /* 64*201*128 */
#define OFF_A    1875968u    /* 4*64*201*128 */
#define OFF_Q    8462336u    /* 16*64*128 */
#define OFF_ROWH 8593408u    /* 64*201*32 (includes +b1) */
#define OFF_COLH 9005056u    /* 64*201*32 */
#define OFF_CMP  9416704u    /* 4*64*200 */
#define OFF_SC   9467904u    /* int a1[64], pp[64], pd[64]; float ll1[64] */
#define OFF_PM   9468160u    /* 64*16 */
#define OFF_PS   9469184u
#define OFF_PI   9470208u
#define OFF_W2T  9471232u    /* 32*32 transposed re_w2 */

/* ---- transpose re_w2 -> w2t[j][k] = w2[k][j] ---- */
__global__ void ktrw2(const float* __restrict__ w2, float* __restrict__ ws) {
    int t = threadIdx.x;  /* 1024 */
    ws[OFF_W2T + t] = w2[(t & 31)*32 + (t >> 5)];
}

/* ---- M_h = WQ_h @ WK_h^T for 12 (mat,head) combos ---- */
__global__ void kprep(const float* __restrict__ rmWQ, const float* __restrict__ rmWK,
                      const float* __restrict__ i1Wq, const float* __restrict__ i1Wk,
                      const float* __restrict__ i2Wq, const float* __restrict__ i2Wk,
                      float* __restrict__ ws) {
    int bid = blockIdx.x;
    int m = bid >> 7, i = bid & 127, j = threadIdx.x;
    const float* WQ; const float* WK;
    if (m < 4)      { WQ = rmWQ + m*16384;     WK = rmWK + m*16384; }
    else if (m < 8) { WQ = i1Wq + (m-4)*16384; WK = i1Wk + (m-4)*16384; }
    else            { WQ = i2Wq + (m-8)*16384; WK = i2Wk + (m-8)*16384; }
    __shared__ float lq[128];
    lq[j] = WQ[i*128 + j];
    __syncthreads();
    const float* wkr = WK + j*128;
    float acc = 0.f;
    #pragma unroll 8
    for (int e = 0; e < 128; ++e) acc += lq[e] * wkr[e];
    ws[OFF_M + m*16384 + i*128 + j] = acc;
}

/* ---- partial max over n-chunks: pmax[b][p][d] ---- */
__global__ void kpartmax(const float* __restrict__ hw, float* __restrict__ ws) {
    int b = blockIdx.x, p = blockIdx.y, d = threadIdx.x;
    int n0 = p*51, ne = n0 + 51; if (ne > N1) ne = N1;
    float m = -INFINITY;
    const float* src = hw + ((size_t)b*N1)*DD + d;
    for (int n = n0; n < ne; ++n) m = fmaxf(m, src[n*DD]);
    ws[OFF_PMAX + (b*4 + p)*128 + d] = m;
}

/* ---- h_hat = h_wave @ Wn + (hmax @ Wg), 16-row tiles ---- */
__global__ void khhat(const float* __restrict__ hw, const float* __restrict__ Wn,
                      const float* __restrict__ Wg, float* __restrict__ ws) {
    int bid = blockIdx.x;
    int b = bid / 13, rt = bid % 13, r0 = rt*16, d = threadIdx.x;
    __shared__ float hm[128];
    __shared__ float xs[16][128];
    const float* pm = ws + OFF_PMAX + b*4*128 + d;
    float mx = fmaxf(fmaxf(pm[0], pm[128]), fmaxf(pm[256], pm[384]));
    hm[d] = mx;
    for (int r = 0; r < 16; ++r) {
        int n = r0 + r; if (n > 200) n = 200;
        xs[r][d] = hw[((size_t)b*N1 + n)*DD + d];
    }
    __syncthreads();
    float gv = 0.f;
    for (int k = 0; k < 128; ++k) gv += hm[k] * Wg[k*128 + d];
    float acc[16];
    #pragma unroll
    for (int r = 0; r < 16; ++r) acc[r] = gv;
    for (int k = 0; k < 128; ++k) {
        float wv = Wn[k*128 + d];
        #pragma unroll
        for (int r = 0; r < 16; ++r) acc[r] += xs[r][k] * wv;
    }
    for (int r = 0; r < 16; ++r) {
        int n = r0 + r;
        if (n < N1) ws[OFF_HHAT + ((size_t)b*N1 + n)*DD + d] = acc[r];
    }
}

/* ---- A[h] = h_hat @ Mrm[h] ---- */
__global__ void kA(float* __restrict__ ws) {
    int bid = blockIdx.x;
    int h = bid / (64*13);
    int rem = bid % (64*13);
    int b = rem / 13, rt = rem % 13, r0 = rt*16, d = threadIdx.x;
    const float* hhat = ws + OFF_HHAT;
    const float* M = ws + OFF_M + h*16384;
    __shared__ float xs[16][128];
    for (int r = 0; r < 16; ++r) {
        int n = r0 + r; if (n > 200) n = 200;
        xs[r][d] = hhat[((size_t)b*N1 + n)*DD + d];
    }
    __syncthreads();
    float acc[16];
    #pragma unroll
    for (int r = 0; r < 16; ++r) acc[r] = 0.f;
    for (int k = 0; k < 128; ++k) {
        float wv = M[k*128 + d];
        #pragma unroll
        for (int r = 0; r < 16; ++r) acc[r] += xs[r][k] * wv;
    }
    float* A = ws + OFF_A;
    for (int r = 0; r < 16; ++r) {
        int n = r0 + r;
        if (n < N1) A[(((size_t)h*64 + b)*N1 + n)*DD + d] = acc[r];
    }
}

/* ---- comp[h][b][n-1] : per-(b,h) block, float2 coalesced, shuffle reduce ---- */
__global__ void kcomp(const int* __restrict__ solution, float* __restrict__ ws) {
    int b = blockIdx.x, h = blockIdx.y, t = threadIdx.x;
    __shared__ int sol[201], pre[201], post[201];
    if (t < 201) sol[t] = solution[b*N1 + t];
    __syncthreads();
    if (t < 201) { pre[sol[t]] = t; post[t] = sol[sol[t]]; }
    __syncthreads();
    int w = t >> 6, lane = t & 63;
    const float2* X  = (const float2*)(ws + OFF_HHAT) + (size_t)b*N1*64;
    const float2* Ah = (const float2*)(ws + OFF_A) + ((size_t)h*64 + b)*N1*64;
    float* cmp = ws + OFF_CMP + (h*64 + b)*200;
    for (int n = 1 + w; n <= 200; n += 4) {
        int pn = pre[n], po = post[n];
        float2 xn = X[n*64 + lane], xp = X[po*64 + lane];
        float2 ap = Ah[pn*64 + lane], an = Ah[n*64 + lane];
        float v = ap.x*(xn.x - xp.x) + ap.y*(xn.y - xp.y) + an.x*xp.x + an.y*xp.y;
        #pragma unroll
        for (int off = 32; off; off >>= 1) v += __shfl_xor(v, off);
        if (lane == 0) cmp[n - 1] = v;
    }
}

/* ---- removal MLP + softmax/argmax ---- */
__global__ void krm2(const float* __restrict__ sel, const int* __restrict__ pre_action,
                     const float* __restrict__ w1, const float* __restrict__ b1,
                     const float* __restrict__ w2, const float* __restrict__ b2,
                     const float* __restrict__ w3, const float* __restrict__ b3,
                     float* __restrict__ ws) {
    int b = blockIdx.x, t = threadIdx.x;  /* 128 */
    __shared__ float t1l[100];
    if (t < 100) {
        const float* cmp = ws + OFF_CMP;
        float f[12];
        #pragma unroll
        for (int h = 0; h < 4; ++h) {
            f[h]     = cmp[(h*64 + b)*200 + t];
            f[4 + h] = cmp[(h*64 + b)*200 + 100 + t];
        }
        #pragma unroll
        for (int s = 0; s < 4; ++s) f[8 + s] = sel[b*400 + s*100 + t];
        float h1[32];
        #pragma unroll
        for (int k = 0; k < 32; ++k) h1[k] = b1[k];
        #pragma unroll
        for (int j = 0; j < 12; ++j) {
            const float* wr = w1 + j*32;
            #pragma unroll
            for (int k = 0; k < 32; ++k) h1[k] += f[j]*wr[k];
        }
        #pragma unroll
        for (int k = 0; k < 32; ++k) h1[k] = fmaxf(h1[k], 0.f);
        float acc[32];
        #pragma unroll
        for (int j = 0; j < 32; ++j) acc[j] = b2[j];
        #pragma unroll
        for (int k = 0; k < 32; ++k) {
            const float* wr = w2 + k*32;
            #pragma unroll
            for (int j = 0; j < 32; ++j) acc[j] += h1[k]*wr[j];
        }
        float out = b3[0];
        #pragma unroll
        for (int j = 0; j < 32; ++j) out += fmaxf(acc[j], 0.f)*w3[j];
        t1l[t] = tanhf(out)*6.0f;
    }
    __syncthreads();
    if (t == 0) {
        if (pre_action[0] > 0) t1l[pre_action[b*2]] = NEGV;
        float M = -INFINITY; int a1 = 0;
        for (int i = 0; i < 100; ++i) if (t1l[i] > M) { M = t1l[i]; a1 = i; }
        float S = 0.f;
        for (int i = 0; i < 100; ++i) S += __expf(t1l[i] - M);
        int* ia = (int*)(ws + OFF_SC);
        ia[b] = a1; ia[64 + b] = 1 + a1; ia[128 + b] = 101 + a1;
        ws[OFF_SC + 192 + b] = -__logf(S);
    }
}

/* ---- 16 query vectors: grid (64,4h), block 128 ---- */
__global__ void kqvec(float* __restrict__ ws) {
    int b = blockIdx.x, h = blockIdx.y, j = threadIdx.x;
    const int* ia = (const int*)(ws + OFF_SC);
    int pp = ia[64 + b], pd = ia[128 + b];
    __shared__ float xp[128], xd[128];
    const float* hhat = ws + OFF_HHAT + (size_t)b*N1*DD;
    xp[j] = hhat[pp*DD + j];
    xd[j] = hhat[pd*DD + j];
    __syncthreads();
    const float* M1 = ws + OFF_M + (4 + h)*16384;
    const float* M2 = ws + OFF_M + (8 + h)*16384;
    float a1p = 0, a2p = 0, a1d = 0, a2d = 0;
    for (int i = 0; i < 128; ++i) {
        float w1v = M1[i*128 + j], w2v = M2[i*128 + j];
        a1p += xp[i]*w1v; a1d += xd[i]*w1v;
        a2p += xp[i]*w2v; a2d += xd[i]*w2v;
    }
    float* q = ws + OFF_Q;
    q[((0*4 + h)*64 + b)*128 + j] = a1p*QSCALE;
    q[((1*4 + h)*64 + b)*128 + j] = a2p*QSCALE;
    q[((2*4 + h)*64 + b)*128 + j] = a1d*QSCALE;
    q[((3*4 + h)*64 + b)*128 + j] = a2d*QSCALE;
}

/* ---- rowH(+b1)/colH: thread-per-row, chunked register dots, scalar q/w1 ---- */
__global__ void krowcol(const int* __restrict__ solution, const float* __restrict__ w1,
                        const float* __restrict__ b1, const float* __restrict__ qg,
                        const float* __restrict__ hhat, float* __restrict__ rowH,
                        float* __restrict__ colH) {
    int b = blockIdx.x, ch = blockIdx.y, t = threadIdx.x;  /* block 64 */
    int n = ch*51 + t;
    int ne = ch*51 + 51; if (ne > N1) ne = N1;
    if (n >= ne || t >= 51) return;
    int sn = solution[b*N1 + n];
    const float* ra = hhat + ((size_t)b*N1 + n)*DD;
    const float* rb = hhat + ((size_t)b*N1 + sn)*DD;
    float cv[16];
    #pragma unroll
    for (int j = 0; j < 16; ++j) cv[j] = 0.f;
    for (int ec = 0; ec < 4; ++ec) {
        float xa[32], xb[32];
        #pragma unroll
        for (int q4 = 0; q4 < 8; ++q4) {
            float4 va = ((const float4*)(ra + ec*32))[q4];
            float4 vb = ((const float4*)(rb + ec*32))[q4];
            xa[q4*4+0]=va.x; xa[q4*4+1]=va.y; xa[q4*4+2]=va.z; xa[q4*4+3]=va.w;
            xb[q4*4+0]=vb.x; xb[q4*4+1]=vb.y; xb[q4*4+2]=vb.z; xb[q4*4+3]=vb.w;
        }
        #pragma unroll
        for (int j = 0; j < 16; ++j) {
            const float* qp = qg + ((size_t)j*64 + b)*128 + ec*32;
            int kind = j >> 2;
            float a = 0.f;
            if (kind & 1) {
                #pragma unroll
                for (int e = 0; e < 32; ++e) a += qp[e]*xb[e];
            } else {
                #pragma unroll
                for (int e = 0; e < 32; ++e) a += qp[e]*xa[e];
            }
            cv[j] += a;
        }
    }
    float* rO = rowH + ((size_t)b*N1 + n)*32;
    float* cO = colH + ((size_t)b*N1 + n)*32;
    #pragma unroll
    for (int k = 0; k < 32; ++k) {
        float rh = b1[k], chh = 0.f;
        #pragma unroll
        for (int j = 0; j < 8; ++j)  rh  += cv[j]*w1[j*32 + k];
        #pragma unroll
        for (int j = 8; j < 16; ++j) chh += cv[j]*w1[j*32 + k];
        rO[k] = rh; cO[k] = chh;
    }
}

/* ---- t2: col-per-lane (colH in regs), wave-uniform rows (scalar rowH/w2t) ---- */
__global__ __launch_bounds__(256, 4) void kt2(
        const unsigned char* __restrict__ maskt,
        const float* __restrict__ rowH, const float* __restrict__ colH,
        const float* __restrict__ w2t, const float* __restrict__ b2g,
        const float* __restrict__ w3g, const float* __restrict__ b3g,
        float* __restrict__ pm, float* __restrict__ ps, int* __restrict__ pi) {
    int bid = blockIdx.x;
    int b = bid >> 4, sub = bid & 15;
    int cchunk = sub & 3, rchunk = sub >> 2;
    int t = threadIdx.x, lane = t & 63, w = t >> 6;
    int c = cchunk*64 + lane;
    bool active = (c < N1);
    int cS = active ? c : (N1 - 1);
    float colr[32];
    {
        const float4* cb = (const float4*)(colH + ((size_t)b*N1 + cS)*32);
        #pragma unroll
        for (int q4 = 0; q4 < 8; ++q4) {
            float4 v = cb[q4];
            colr[q4*4+0]=v.x; colr[q4*4+1]=v.y; colr[q4*4+2]=v.z; colr[q4*4+3]=v.w;
        }
    }
    int r0 = rchunk*51;
    int rend = r0 + 51; if (rend > N1) rend = N1;
    const float* rbase = rowH + (size_t)b*N1*32;
    float b3v = b3g[0];
    float m = -INFINITY, s = 0.f;
    int mi = 0x7fffffff;
    for (int r = r0 + w; r < rend; r += 4) {
        int ru = __builtin_amdgcn_readfirstlane(r);
        const float* rp = rbase + ru*32;
        float h1[32];
        #pragma unroll
        for (int k = 0; k < 32; ++k) h1[k] = fmaxf(rp[k] + colr[k], 0.f);
        float out = b3v;
        #pragma unroll
        for (int j = 0; j < 32; ++j) {
            const float* wr = w2t + j*32;
            float a0 = b2g[j], a1 = 0.f;
            #pragma unroll
            for (int k = 0; k < 32; k += 2) {
                a0 += h1[k]*wr[k];
                a1 += h1[k+1]*wr[k+1];
            }
            out += fmaxf(a0 + a1, 0.f)*w3g[j];
        }
        float tv = tanhf(out)*6.0f;
        if (maskt[((size_t)b*N1 + ru)*N1 + cS]) tv = NEGV;
        if (active) {
            if (tv > m) { s = s*__expf(m - tv) + 1.f; m = tv; mi = ru*N1 + c; }
            else        { s += __expf(tv - m); }
        }
    }
    __shared__ float redm[256], reds[256];
    __shared__ int redi[256];
    redm[t] = m; reds[t] = s; redi[t] = mi;
    __syncthreads();
    for (int off = 128; off > 0; off >>= 1) {
        if (t < off) {
            float ma = redm[t], mb = redm[t+off];
            float sa = reds[t], sb = reds[t+off];
            int ia = redi[t], ib = redi[t+off];
            float M2 = fmaxf(ma, mb);
            float sn = (sa > 0.f ? sa*__expf(ma - M2) : 0.f)
                     + (sb > 0.f ? sb*__expf(mb - M2) : 0.f);
            int in_;
            if (ma > mb) in_ = ia; else if (mb > ma) in_ = ib; else in_ = (ia < ib ? ia : ib);
            redm[t] = M2; reds[t] = sn; redi[t] = in_;
        }
        __syncthreads();
    }
    if (t == 0) {
        pm[b*16 + sub] = redm[0];
        ps[b*16 + sub] = reds[0];
        pi[b*16 + sub] = redi[0];
    }
}

/* ---- final reduce + outputs ---- */
__global__ void kfinal(float* __restrict__ out, float* __restrict__ ws) {
    int b = blockIdx.x, lane = threadIdx.x;  /* 64 */
    float m = -INFINITY, s = 0.f;
    int mi = 0x7fffffff;
    if (lane < 16) {
        m = ws[OFF_PM + b*16 + lane];
        s = ws[OFF_PS + b*16 + lane];
        mi = ((const int*)(ws + OFF_PI))[b*16 + lane];
    }
    for (int off = 32; off; off >>= 1) {
        float om = __shfl_xor(m, off);
        float os = __shfl_xor(s, off);
        int oi = __shfl_xor(mi, off);
        float M2 = fmaxf(m, om);
        float sn = (s > 0.f ? s*__expf(m - M2) : 0.f)
                 + (os > 0.f ? os*__expf(om - M2) : 0.f);
        int in_;
        if (m > om) in_ = mi; else if (om > m) in_ = oi; else in_ = (mi < oi ? mi : oi);
        m = M2; s = sn; mi = in_;
    }
    if (lane == 0) {
        float ll2 = -__logf(s);
        const int* ia = (const int*)(ws + OFF_SC);
        out[b*3 + 0] = (float)ia[b];
        out[b*3 + 1] = (float)(mi / N1);
        out[b*3 + 2] = (float)(mi % N1);
        out[192 + b] = ws[OFF_SC + 192 + b] + ll2;
    }
}

extern "C" void kernel_launch(void* const* d_in, const int* in_sizes, int n_in,
                              void* d_out, int out_size, void* d_ws, size_t ws_size,
                              hipStream_t stream) {
    const float* h_wave    = (const float*)d_in[0];
    const int*   solution  = (const int*)d_in[1];
    const float* sel       = (const float*)d_in[2];
    const int*   pre_act   = (const int*)d_in[3];
    const unsigned char* maskt = (const unsigned char*)d_in[4];
    const float* Wn    = (const float*)d_in[5];
    const float* Wg    = (const float*)d_in[6];
    const float* rmWQ  = (const float*)d_in[7];
    const float* rmWK  = (const float*)d_in[8];
    const float* rm_w1 = (const float*)d_in[9];
    const float* rm_b1 = (const float*)d_in[10];
    const float* rm_w2 = (const float*)d_in[11];
    const float* rm_b2 = (const float*)d_in[12];
    const float* rm_w3 = (const float*)d_in[13];
    const float* rm_b3 = (const float*)d_in[14];
    const float* i1Wq  = (const float*)d_in[15];
    const float* i1Wk  = (const float*)d_in[16];
    const float* i2Wq  = (const float*)d_in[17];
    const float* i2Wk  = (const float*)d_in[18];
    const float* re_w1 = (const float*)d_in[19];
    const float* re_b1 = (const float*)d_in[20];
    const float* re_w2 = (const float*)d_in[21];
    const float* re_b2 = (const float*)d_in[22];
    const float* re_w3 = (const float*)d_in[23];
    const float* re_b3 = (const float*)d_in[24];
    float* ws = (float*)d_ws;
    float* out = (float*)d_out;

    ktrw2<<<dim3(1), dim3(1024), 0, stream>>>(re_w2, ws);
    kprep<<<dim3(1536), dim3(128), 0, stream>>>(rmWQ, rmWK, i1Wq, i1Wk, i2Wq, i2Wk, ws);
    kpartmax<<<dim3(64, 4), dim3(128), 0, stream>>>(h_wave, ws);
    khhat<<<dim3(64*13), dim3(128), 0, stream>>>(h_wave, Wn, Wg, ws);
    kA<<<dim3(4*64*13), dim3(128), 0, stream>>>(ws);
    kcomp<<<dim3(64, 4), dim3(256), 0, stream>>>(solution, ws);
    krm2<<<dim3(64), dim3(128), 0, stream>>>(sel, pre_act, rm_w1, rm_b1, rm_w2, rm_b2,
                                             rm_w3, rm_b3, ws);
    kqvec<<<dim3(64, 4), dim3(128), 0, stream>>>(ws);
    krowcol<<<dim3(64, 4), dim3(64), 0, stream>>>(solution, re_w1, re_b1,
                                                  ws + OFF_Q, ws + OFF_HHAT,
                                                  ws + OFF_ROWH, ws + OFF_COLH);
    kt2<<<dim3(1024), dim3(256), 0, stream>>>(maskt, ws + OFF_ROWH, ws + OFF_COLH,
                                              ws + OFF_W2T, re_b2, re_w3, re_b3,
                                              ws + OFF_PM, ws + OFF_PS,
                                              (int*)(ws + OFF_PI));
    kfinal<<<dim3(64), dim3(64), 0, stream>>>(out, ws);
}

// Round 4
// 429.455 us; speedup vs baseline: 1.4971x; 1.1946x over previous
//
#include <hip/hip_runtime.h>
#include <math.h>

#define BB 64
#define N1 201
#define DD 128
#define HALF 100
#define NN (N1*N1)
#define NEGV (-1e20f)
#define QSCALE 0.08838834764831845f  /* 1/sqrt(128) */

typedef __attribute__((ext_vector_type(8))) short short8v;
typedef __attribute__((ext_vector_type(4))) float float4v;

/* ws offsets in floats */
#define OFF_M    0u          /* 12*16384 = 196608 */
#define OFF_PMAX 196608u     /* 64*4*128 */
#define OFF_G    229376u     /* 64*128 */
#define OFF_HHAT 237568u     /* 64*201*128 */
#define OFF_A    1884160u    /* 4*64*201*128 */
#define OFF_Q    8470528u    /* 16*64*128 */
#define OFF_ROWH 8601600u    /* 64*201*32 (includes +b1) */
#define OFF_COLH 9013248u    /* 64*201*32 */
#define OFF_CMP  9424896u    /* 4*64*200 */
#define OFF_SC   9476096u    /* ints a1/pp/pd + float ll1 */
#define OFF_PM   9476352u    /* 64*32 */
#define OFF_PS   9478400u
#define OFF_PI   9480448u
#define OFF_W2F  9482496u    /* 4*64*8 ushort = 1024 floats */

__device__ __forceinline__ unsigned short f2bf(float x) {
    unsigned u = __float_as_uint(x);
    unsigned r = u + 0x7fffu + ((u >> 16) & 1u);
    return (unsigned short)(r >> 16);
}

/* ---- M_h = WQ_h @ WK_h^T (12 combos); block 1536 builds w2 hi/lo MFMA frags ---- */
__global__ void kprep(const float* __restrict__ rmWQ, const float* __restrict__ rmWK,
                      const float* __restrict__ i1Wq, const float* __restrict__ i1Wk,
                      const float* __restrict__ i2Wq, const float* __restrict__ i2Wk,
                      const float* __restrict__ re_w2, float* __restrict__ ws) {
    int bid = blockIdx.x;
    if (bid == 1536) {  /* w2 fragment prep: fs = jh*2+part, lane, i */
        int t = threadIdx.x;
        unsigned short* w2f = (unsigned short*)(ws + OFF_W2F);
        for (int idx = t; idx < 4*64*8; idx += 128) {
            int fs = idx >> 9, l = (idx >> 3) & 63, i = idx & 7;
            int j = 16*(fs >> 1) + (l & 15);
            int k = ((l >> 4) * 8) + i;
            float v = re_w2[k*32 + j];
            unsigned short hi = f2bf(v);
            unsigned short out;
            if (fs & 1) {
                float hf = __uint_as_float(((unsigned)hi) << 16);
                out = f2bf(v - hf);
            } else out = hi;
            w2f[idx] = out;
        }
        return;
    }
    int m = bid >> 7, i = bid & 127, j = threadIdx.x;
    const float* WQ; const float* WK;
    if (m < 4)      { WQ = rmWQ + m*16384;     WK = rmWK + m*16384; }
    else if (m < 8) { WQ = i1Wq + (m-4)*16384; WK = i1Wk + (m-4)*16384; }
    else            { WQ = i2Wq + (m-8)*16384; WK = i2Wk + (m-8)*16384; }
    __shared__ float lq[128];
    lq[j] = WQ[i*128 + j];
    __syncthreads();
    const float* wkr = WK + j*128;
    float acc = 0.f;
    #pragma unroll 8
    for (int e = 0; e < 128; ++e) acc += lq[e] * wkr[e];
    ws[OFF_M + m*16384 + i*128 + j] = acc;
}

/* ---- partial max over n-chunks ---- */
__global__ void kpartmax(const float* __restrict__ hw, float* __restrict__ pmax) {
    int b = blockIdx.x, p = blockIdx.y, d = threadIdx.x;
    int n0 = p*51, ne = n0 + 51; if (ne > N1) ne = N1;
    float m = -INFINITY;
    const float* src = hw + ((size_t)b*N1)*DD + d;
    for (int n = n0; n < ne; ++n) m = fmaxf(m, src[n*DD]);
    pmax[(b*4 + p)*128 + d] = m;
}

/* ---- reduce partial max, g = hmax @ Wg ---- */
__global__ void khmaxg(const float* __restrict__ pmax, const float* __restrict__ Wg,
                       float* __restrict__ g) {
    int b = blockIdx.x, d = threadIdx.x;
    __shared__ float hm[128];
    const float* pm = pmax + b*4*128 + d;
    hm[d] = fmaxf(fmaxf(pm[0], pm[128]), fmaxf(pm[256], pm[384]));
    __syncthreads();
    float acc = 0.f;
    for (int k = 0; k < 128; ++k) acc += hm[k] * Wg[k*128 + d];
    g[b*128 + d] = acc;
}

/* ---- h_hat = h_wave @ Wn + g ; rows via uniform (scalar) loads ---- */
__global__ void khhat(const float* __restrict__ hw, const float* __restrict__ Wn,
                      const float* __restrict__ g, float* __restrict__ hhat) {
    int bid = blockIdx.x;
    int b = bid / 13, rt = bid % 13, r0 = rt*16, d = threadIdx.x;
    const float* xp[16];
    #pragma unroll
    for (int r = 0; r < 16; ++r) {
        int n = r0 + r; if (n > 200) n = 200;
        xp[r] = hw + ((size_t)b*N1 + n)*DD;
    }
    float gv = g[b*128 + d];
    float acc[16];
    #pragma unroll
    for (int r = 0; r < 16; ++r) acc[r] = gv;
    for (int k = 0; k < 128; ++k) {
        float wv = Wn[k*128 + d];
        #pragma unroll
        for (int r = 0; r < 16; ++r) acc[r] += xp[r][k] * wv;
    }
    #pragma unroll
    for (int r = 0; r < 16; ++r) {
        int n = r0 + r;
        if (n < N1) hhat[((size_t)b*N1 + n)*DD + d] = acc[r];
    }
}

/* ---- A[h] = h_hat @ M[h] ; rows via uniform (scalar) loads ---- */
__global__ void kA(const float* __restrict__ hhat, const float* __restrict__ Mall,
                   float* __restrict__ A) {
    int bid = blockIdx.x;
    int h = bid / (64*13);
    int rem = bid % (64*13);
    int b = rem / 13, rt = rem % 13, r0 = rt*16, d = threadIdx.x;
    const float* M = Mall + h*16384;
    const float* xp[16];
    #pragma unroll
    for (int r = 0; r < 16; ++r) {
        int n = r0 + r; if (n > 200) n = 200;
        xp[r] = hhat + ((size_t)b*N1 + n)*DD;
    }
    float acc[16];
    #pragma unroll
    for (int r = 0; r < 16; ++r) acc[r] = 0.f;
    for (int k = 0; k < 128; ++k) {
        float wv = M[k*128 + d];
        #pragma unroll
        for (int r = 0; r < 16; ++r) acc[r] += xp[r][k] * wv;
    }
    #pragma unroll
    for (int r = 0; r < 16; ++r) {
        int n = r0 + r;
        if (n < N1) A[(((size_t)h*64 + b)*N1 + n)*DD + d] = acc[r];
    }
}

/* ---- comp[h][b][n-1] ---- */
__global__ void kcomp(const int* __restrict__ solution, const float* __restrict__ hhat,
                      const float* __restrict__ A, float* __restrict__ cmpg) {
    int b = blockIdx.x, h = blockIdx.y, t = threadIdx.x;
    __shared__ int sol[201], pre[201], post[201];
    if (t < 201) sol[t] = solution[b*N1 + t];
    __syncthreads();
    if (t < 201) { pre[sol[t]] = t; post[t] = sol[sol[t]]; }
    __syncthreads();
    int w = t >> 6, lane = t & 63;
    const float2* X  = (const float2*)hhat + (size_t)b*N1*64;
    const float2* Ah = (const float2*)A + ((size_t)h*64 + b)*N1*64;
    float* cmp = cmpg + (h*64 + b)*200;
    for (int n = 1 + w; n <= 200; n += 4) {
        int pn = pre[n], po = post[n];
        float2 xn = X[n*64 + lane], xp = X[po*64 + lane];
        float2 ap = Ah[pn*64 + lane], an = Ah[n*64 + lane];
        float v = ap.x*(xn.x - xp.x) + ap.y*(xn.y - xp.y) + an.x*xp.x + an.y*xp.y;
        #pragma unroll
        for (int off = 32; off; off >>= 1) v += __shfl_xor(v, off);
        if (lane == 0) cmp[n - 1] = v;
    }
}

/* ---- removal MLP + softmax/argmax ---- */
__global__ void krm2(const float* __restrict__ sel, const int* __restrict__ pre_action,
                     const float* __restrict__ w1, const float* __restrict__ b1,
                     const float* __restrict__ w2, const float* __restrict__ b2,
                     const float* __restrict__ w3, const float* __restrict__ b3,
                     const float* __restrict__ cmpg, float* __restrict__ sc) {
    int b = blockIdx.x, t = threadIdx.x;  /* 128 */
    __shared__ float t1l[100];
    if (t < 100) {
        float f[12];
        #pragma unroll
        for (int h = 0; h < 4; ++h) {
            f[h]     = cmpg[(h*64 + b)*200 + t];
            f[4 + h] = cmpg[(h*64 + b)*200 + 100 + t];
        }
        #pragma unroll
        for (int s = 0; s < 4; ++s) f[8 + s] = sel[b*400 + s*100 + t];
        float h1[32];
        #pragma unroll
        for (int k = 0; k < 32; ++k) h1[k] = b1[k];
        #pragma unroll
        for (int j = 0; j < 12; ++j) {
            const float* wr = w1 + j*32;
            #pragma unroll
            for (int k = 0; k < 32; ++k) h1[k] += f[j]*wr[k];
        }
        #pragma unroll
        for (int k = 0; k < 32; ++k) h1[k] = fmaxf(h1[k], 0.f);
        float acc[32];
        #pragma unroll
        for (int j = 0; j < 32; ++j) acc[j] = b2[j];
        #pragma unroll
        for (int k = 0; k < 32; ++k) {
            const float* wr = w2 + k*32;
            #pragma unroll
            for (int j = 0; j < 32; ++j) acc[j] += h1[k]*wr[j];
        }
        float out = b3[0];
        #pragma unroll
        for (int j = 0; j < 32; ++j) out += fmaxf(acc[j], 0.f)*w3[j];
        t1l[t] = tanhf(out)*6.0f;
    }
    __syncthreads();
    if (t == 0) {
        if (pre_action[0] > 0) t1l[pre_action[b*2]] = NEGV;
        float M = -INFINITY; int a1 = 0;
        for (int i = 0; i < 100; ++i) if (t1l[i] > M) { M = t1l[i]; a1 = i; }
        float S = 0.f;
        for (int i = 0; i < 100; ++i) S += __expf(t1l[i] - M);
        int* ia = (int*)sc;
        ia[b] = a1; ia[64 + b] = 1 + a1; ia[128 + b] = 101 + a1;
        sc[192 + b] = -__logf(S);
    }
}

/* ---- 16 query vectors ---- */
__global__ void kqvec(const float* __restrict__ Mall, const float* __restrict__ hhat,
                      const float* __restrict__ sc, float* __restrict__ q) {
    int b = blockIdx.x, h = blockIdx.y, j = threadIdx.x;
    const int* ia = (const int*)sc;
    int pp = ia[64 + b], pd = ia[128 + b];
    __shared__ float xp[128], xd[128];
    const float* hb = hhat + (size_t)b*N1*DD;
    xp[j] = hb[pp*DD + j];
    xd[j] = hb[pd*DD + j];
    __syncthreads();
    const float* M1 = Mall + (4 + h)*16384;
    const float* M2 = Mall + (8 + h)*16384;
    float a1p = 0, a2p = 0, a1d = 0, a2d = 0;
    for (int i = 0; i < 128; ++i) {
        float w1v = M1[i*128 + j], w2v = M2[i*128 + j];
        a1p += xp[i]*w1v; a1d += xd[i]*w1v;
        a2p += xp[i]*w2v; a2d += xd[i]*w2v;
    }
    q[((0*4 + h)*64 + b)*128 + j] = a1p*QSCALE;
    q[((1*4 + h)*64 + b)*128 + j] = a2p*QSCALE;
    q[((2*4 + h)*64 + b)*128 + j] = a1d*QSCALE;
    q[((3*4 + h)*64 + b)*128 + j] = a2d*QSCALE;
}

/* ---- rowH(+b1)/colH ---- */
__global__ void krowcol(const int* __restrict__ solution, const float* __restrict__ w1,
                        const float* __restrict__ b1, const float* __restrict__ qg,
                        const float* __restrict__ hhat, float* __restrict__ rowH,
                        float* __restrict__ colH) {
    int b = blockIdx.x, ch = blockIdx.y, t = threadIdx.x;  /* block 64 */
    int n = ch*51 + t;
    int ne = ch*51 + 51; if (ne > N1) ne = N1;
    if (n >= ne || t >= 51) return;
    int sn = solution[b*N1 + n];
    const float* ra = hhat + ((size_t)b*N1 + n)*DD;
    const float* rb = hhat + ((size_t)b*N1 + sn)*DD;
    float cv[16];
    #pragma unroll
    for (int j = 0; j < 16; ++j) cv[j] = 0.f;
    for (int ec = 0; ec < 4; ++ec) {
        float xa[32], xb[32];
        #pragma unroll
        for (int q4 = 0; q4 < 8; ++q4) {
            float4 va = ((const float4*)(ra + ec*32))[q4];
            float4 vb = ((const float4*)(rb + ec*32))[q4];
            xa[q4*4+0]=va.x; xa[q4*4+1]=va.y; xa[q4*4+2]=va.z; xa[q4*4+3]=va.w;
            xb[q4*4+0]=vb.x; xb[q4*4+1]=vb.y; xb[q4*4+2]=vb.z; xb[q4*4+3]=vb.w;
        }
        #pragma unroll
        for (int j = 0; j < 16; ++j) {
            const float* qp = qg + ((size_t)j*64 + b)*128 + ec*32;
            int kind = j >> 2;
            float a = 0.f;
            if (kind & 1) {
                #pragma unroll
                for (int e = 0; e < 32; ++e) a += qp[e]*xb[e];
            } else {
                #pragma unroll
                for (int e = 0; e < 32; ++e) a += qp[e]*xa[e];
            }
            cv[j] += a;
        }
    }
    float* rO = rowH + ((size_t)b*N1 + n)*32;
    float* cO = colH + ((size_t)b*N1 + n)*32;
    #pragma unroll
    for (int k = 0; k < 32; ++k) {
        float rh = b1[k], chh = 0.f;
        #pragma unroll
        for (int j = 0; j < 8; ++j)  rh  += cv[j]*w1[j*32 + k];
        #pragma unroll
        for (int j = 8; j < 16; ++j) chh += cv[j]*w1[j*32 + k];
        rO[k] = rh; cO[k] = chh;
    }
}

/* ---- t2 via bf16 hi/lo MFMA: 1 wave, 64 cols x 26 rows per block ---- */
__global__ __launch_bounds__(64) void kt2(
        const unsigned char* __restrict__ maskt,
        const float* __restrict__ rowH, const float* __restrict__ colH,
        const unsigned short* __restrict__ w2f,
        const float* __restrict__ b2g, const float* __restrict__ w3g,
        const float* __restrict__ b3g,
        float* __restrict__ pm, float* __restrict__ ps, int* __restrict__ pi) {
    int b = blockIdx.x, cy = blockIdx.y, rz = blockIdx.z;
    int l = threadIdx.x;
    int c0 = cy*64;
    int r0 = rz*26, rend = r0 + 26; if (rend > N1) rend = N1;
    int rcnt = rend - r0;
    __shared__ float colc[64*36];
    __shared__ float rowr[26*36];

    const short8v* wf = (const short8v*)w2f;
    short8v w2hi0 = wf[0*64 + l];
    short8v w2lo0 = wf[1*64 + l];
    short8v w2hi1 = wf[2*64 + l];
    short8v w2lo1 = wf[3*64 + l];
    int sg = l >> 4;
    float4v b2f0 = *(const float4v*)(b2g + sg*4);
    float4v b2f1 = *(const float4v*)(b2g + 16 + sg*4);
    float4v w3f0 = *(const float4v*)(w3g + sg*4);
    float4v w3f1 = *(const float4v*)(w3g + 16 + sg*4);
    float b3v = b3g[0];

    {   /* stage colH tile: lane = local col */
        int cg = c0 + l;
        float4v* dst = (float4v*)(colc + l*36);
        if (cg < N1) {
            const float4v* src = (const float4v*)(colH + ((size_t)b*N1 + cg)*32);
            #pragma unroll
            for (int q = 0; q < 8; ++q) dst[q] = src[q];
        } else {
            float4v z = {0.f, 0.f, 0.f, 0.f};
            #pragma unroll
            for (int q = 0; q < 8; ++q) dst[q] = z;
        }
    }
    for (int idx = l; idx < rcnt*32; idx += 64) {
        int rr = idx >> 5, k = idx & 31;
        rowr[rr*36 + k] = rowH[((size_t)b*N1 + r0 + rr)*32 + k];
    }
    __syncthreads();

    float m = -INFINITY, s = 0.f;
    int mi = 0x7fffffff;
    int c = c0 + l;
    bool valid = c < N1;
    const unsigned char* mrow = maskt + (size_t)b*NN + c0 + (l < 64 ? l : 0);

    for (int rr = 0; rr < rcnt; ++rr) {
        int r = r0 + rr;
        const float4v* rp = (const float4v*)(rowr + rr*36 + sg*8);
        float4v ra = rp[0], rb = rp[1];
        float outv = 0.f;
        #pragma unroll
        for (int g = 0; g < 4; ++g) {
            const float4v* cp = (const float4v*)(colc + (16*g + (l & 15))*36 + sg*8);
            float4v ca = cp[0], cb = cp[1];
            float h[8];
            #pragma unroll
            for (int e = 0; e < 4; ++e) {
                h[e]   = fmaxf(ra[e] + ca[e], 0.f);
                h[4+e] = fmaxf(rb[e] + cb[e], 0.f);
            }
            short8v bh, bl;
            #pragma unroll
            for (int e = 0; e < 8; ++e) {
                unsigned short hb = f2bf(h[e]);
                bh[e] = (short)hb;
                float hf = __uint_as_float(((unsigned)hb) << 16);
                bl[e] = (short)f2bf(h[e] - hf);
            }
            float4v a0 = b2f0, a1 = b2f1;
            a0 = __builtin_amdgcn_mfma_f32_16x16x32_bf16(w2hi0, bh, a0, 0, 0, 0);
            a0 = __builtin_amdgcn_mfma_f32_16x16x32_bf16(w2hi0, bl, a0, 0, 0, 0);
            a0 = __builtin_amdgcn_mfma_f32_16x16x32_bf16(w2lo0, bh, a0, 0, 0, 0);
            a0 = __builtin_amdgcn_mfma_f32_16x16x32_bf16(w2lo0, bl, a0, 0, 0, 0);
            a1 = __builtin_amdgcn_mfma_f32_16x16x32_bf16(w2hi1, bh, a1, 0, 0, 0);
            a1 = __builtin_amdgcn_mfma_f32_16x16x32_bf16(w2hi1, bl, a1, 0, 0, 0);
            a1 = __builtin_amdgcn_mfma_f32_16x16x32_bf16(w2lo1, bh, a1, 0, 0, 0);
            a1 = __builtin_amdgcn_mfma_f32_16x16x32_bf16(w2lo1, bl, a1, 0, 0, 0);
            float p = 0.f;
            #pragma unroll
            for (int reg = 0; reg < 4; ++reg) {
                p += fmaxf(a0[reg], 0.f)*w3f0[reg];
                p += fmaxf(a1[reg], 0.f)*w3f1[reg];
            }
            p += __shfl_xor(p, 16);
            p += __shfl_xor(p, 32);
            if (sg == g) outv = p + b3v;
        }
        float ex = __expf(2.f*outv);
        float tv = 6.f - 12.f/(ex + 1.f);
        if (mrow[(size_t)r*N1]) tv = NEGV;
        if (valid) {
            if (tv > m) { s = s*__expf(m - tv) + 1.f; m = tv; mi = r*N1 + c; }
            else        { s += __expf(tv - m); }
        }
    }
    /* wave reduce */
    #pragma unroll
    for (int off = 1; off < 64; off <<= 1) {
        float om = __shfl_xor(m, off);
        float os = __shfl_xor(s, off);
        int oi = __shfl_xor(mi, off);
        float M2 = fmaxf(m, om);
        float sn = (s > 0.f ? s*__expf(m - M2) : 0.f)
                 + (os > 0.f ? os*__expf(om - M2) : 0.f);
        int in_;
        if (m > om) in_ = mi; else if (om > m) in_ = oi; else in_ = (mi < oi ? mi : oi);
        m = M2; s = sn; mi = in_;
    }
    if (l == 0) {
        int slot = b*32 + cy*8 + rz;
        pm[slot] = m; ps[slot] = s; pi[slot] = mi;
    }
}

/* ---- final reduce + outputs ---- */
__global__ void kfinal(float* __restrict__ out, const float* __restrict__ pm,
                       const float* __restrict__ ps, const int* __restrict__ pi,
                       const float* __restrict__ sc) {
    int b = blockIdx.x, lane = threadIdx.x;  /* 64 */
    float m = -INFINITY, s = 0.f;
    int mi = 0x7fffffff;
    if (lane < 32) {
        m = pm[b*32 + lane];
        s = ps[b*32 + lane];
        mi = pi[b*32 + lane];
    }
    #pragma unroll
    for (int off = 1; off < 64; off <<= 1) {
        float om = __shfl_xor(m, off);
        float os = __shfl_xor(s, off);
        int oi = __shfl_xor(mi, off);
        float M2 = fmaxf(m, om);
        float sn = (s > 0.f ? s*__expf(m - M2) : 0.f)
                 + (os > 0.f ? os*__expf(om - M2) : 0.f);
        int in_;
        if (m > om) in_ = mi; else if (om > m) in_ = oi; else in_ = (mi < oi ? mi : oi);
        m = M2; s = sn; mi = in_;
    }
    if (lane == 0) {
        float ll2 = -__logf(s);
        const int* ia = (const int*)sc;
        out[b*3 + 0] = (float)ia[b];
        out[b*3 + 1] = (float)(mi / N1);
        out[b*3 + 2] = (float)(mi % N1);
        out[192 + b] = sc[192 + b] + ll2;
    }
}

extern "C" void kernel_launch(void* const* d_in, const int* in_sizes, int n_in,
                              void* d_out, int out_size, void* d_ws, size_t ws_size,
                              hipStream_t stream) {
    const float* h_wave    = (const float*)d_in[0];
    const int*   solution  = (const int*)d_in[1];
    const float* sel       = (const float*)d_in[2];
    const int*   pre_act   = (const int*)d_in[3];
    const unsigned char* maskt = (const unsigned char*)d_in[4];
    const float* Wn    = (const float*)d_in[5];
    const float* Wg    = (const float*)d_in[6];
    const float* rmWQ  = (const float*)d_in[7];
    const float* rmWK  = (const float*)d_in[8];
    const float* rm_w1 = (const float*)d_in[9];
    const float* rm_b1 = (const float*)d_in[10];
    const float* rm_w2 = (const float*)d_in[11];
    const float* rm_b2 = (const float*)d_in[12];
    const float* rm_w3 = (const float*)d_in[13];
    const float* rm_b3 = (const float*)d_in[14];
    const float* i1Wq  = (const float*)d_in[15];
    const float* i1Wk  = (const float*)d_in[16];
    const float* i2Wq  = (const float*)d_in[17];
    const float* i2Wk  = (const float*)d_in[18];
    const float* re_w1 = (const float*)d_in[19];
    const float* re_b1 = (const float*)d_in[20];
    const float* re_w2 = (const float*)d_in[21];
    const float* re_b2 = (const float*)d_in[22];
    const float* re_w3 = (const float*)d_in[23];
    const float* re_b3 = (const float*)d_in[24];
    float* ws = (float*)d_ws;
    float* out = (float*)d_out;

    kprep<<<dim3(1537), dim3(128), 0, stream>>>(rmWQ, rmWK, i1Wq, i1Wk, i2Wq, i2Wk,
                                                re_w2, ws);
    kpartmax<<<dim3(64, 4), dim3(128), 0, stream>>>(h_wave, ws + OFF_PMAX);
    khmaxg<<<dim3(64), dim3(128), 0, stream>>>(ws + OFF_PMAX, Wg, ws + OFF_G);
    khhat<<<dim3(64*13), dim3(128), 0, stream>>>(h_wave, Wn, ws + OFF_G, ws + OFF_HHAT);
    kA<<<dim3(4*64*13), dim3(128), 0, stream>>>(ws + OFF_HHAT, ws + OFF_M, ws + OFF_A);
    kcomp<<<dim3(64, 4), dim3(256), 0, stream>>>(solution, ws + OFF_HHAT, ws + OFF_A,
                                                 ws + OFF_CMP);
    krm2<<<dim3(64), dim3(128), 0, stream>>>(sel, pre_act, rm_w1, rm_b1, rm_w2, rm_b2,
                                             rm_w3, rm_b3, ws + OFF_CMP, ws + OFF_SC);
    kqvec<<<dim3(64, 4), dim3(128), 0, stream>>>(ws + OFF_M, ws + OFF_HHAT,
                                                 ws + OFF_SC, ws + OFF_Q);
    krowcol<<<dim3(64, 4), dim3(64), 0, stream>>>(solution, re_w1, re_b1,
                                                  ws + OFF_Q, ws + OFF_HHAT,
                                                  ws + OFF_ROWH, ws + OFF_COLH);
    kt2<<<dim3(64, 4, 8), dim3(64), 0, stream>>>(maskt, ws + OFF_ROWH, ws + OFF_COLH,
                                                 (const unsigned short*)(ws + OFF_W2F),
                                                 re_b2, re_w3, re_b3,
                                                 ws + OFF_PM, ws + OFF_PS,
                                                 (int*)(ws + OFF_PI));
    kfinal<<<dim3(64), dim3(64), 0, stream>>>(out, ws + OFF_PM, ws + OFF_PS,
                                              (const int*)(ws + OFF_PI), ws + OFF_SC);
}

// Round 5
// 363.132 us; speedup vs baseline: 1.7705x; 1.1826x over previous
//
#include <hip/hip_runtime.h>
#include <math.h>

#define BB 64
#define N1 201
#define DD 128
#define HALF 100
#define NN (N1*N1)
#define NEGV (-1e20f)
#define QSCALE 0.08838834764831845f  /* 1/sqrt(128) */
#define NELE 1646592u                /* 64*201*128 */

typedef __attribute__((ext_vector_type(8))) short short8v;
typedef __attribute__((ext_vector_type(4))) float float4v;

/* ws offsets in floats */
#define OFF_M    0u          /* 12*16384 f32 M matrices */
#define OFF_MF   196608u     /* 13 mats * 24576 (3-split bf16 frags) */
#define OFF_HWB  516096u     /* h_wave 3-split: 3*823296 */
#define OFF_HHAT 2985984u    /* f32 1646592 */
#define OFF_HBF  4632576u    /* hhat 3-split: 3*823296 */
#define OFF_G    7102464u    /* 64*128 */
#define OFF_PMAX 7110656u    /* 64*4*128 */
#define OFF_CMP  7143424u    /* 4*64*200 */
#define OFF_Q    7194624u    /* 16*64*128 */
#define OFF_ROWH 7325696u    /* 64*201*32 */
#define OFF_COLH 7737344u    /* 64*201*32 */
#define OFF_SC   8148992u
#define OFF_PM   8149248u
#define OFF_PS   8151296u
#define OFF_PI   8153344u
#define OFF_W2F  8155392u    /* kt2 w2 frags (2-split) */

__device__ __forceinline__ unsigned short f2bf(float x) {
    unsigned u = __float_as_uint(x);
    unsigned r = u + 0x7fffu + ((u >> 16) & 1u);
    return (unsigned short)(r >> 16);
}
__device__ __forceinline__ float bf2f(unsigned short h) {
    return __uint_as_float(((unsigned)h) << 16);
}

/* ---- M_h = WQ_h @ WK_h^T (12 combos, LDS-staged, coalesced) + w2 frag prep ---- */
__global__ void kprep2(const float* __restrict__ rmWQ, const float* __restrict__ rmWK,
                       const float* __restrict__ i1Wq, const float* __restrict__ i1Wk,
                       const float* __restrict__ i2Wq, const float* __restrict__ i2Wk,
                       const float* __restrict__ re_w2, float* __restrict__ ws) {
    int m = blockIdx.x, jg = blockIdx.y, t = threadIdx.x;  /* block 128 */
    if (m == 12) {
        if (jg != 0) return;
        unsigned short* w2f = (unsigned short*)(ws + OFF_W2F);
        for (int idx = t; idx < 4*64*8; idx += 128) {
            int fs = idx >> 9, l = (idx >> 3) & 63, i = idx & 7;
            int j = 16*(fs >> 1) + (l & 15);
            int k = ((l >> 4) * 8) + i;
            float v = re_w2[k*32 + j];
            unsigned short hi = f2bf(v);
            unsigned short outv;
            if (fs & 1) outv = f2bf(v - bf2f(hi));
            else        outv = hi;
            w2f[idx] = outv;
        }
        return;
    }
    const float* WQ; const float* WK;
    if (m < 4)      { WQ = rmWQ + m*16384;     WK = rmWK + m*16384; }
    else if (m < 8) { WQ = i1Wq + (m-4)*16384; WK = i1Wk + (m-4)*16384; }
    else            { WQ = i2Wq + (m-8)*16384; WK = i2Wk + (m-8)*16384; }
    __shared__ float wq[128*132];
    __shared__ float wk[32*133];
    for (int idx = t; idx < 128*128; idx += 128) {
        int r = idx >> 7, e = idx & 127;
        wq[r*132 + e] = WQ[idx];
    }
    for (int idx = t; idx < 32*128; idx += 128) {
        int r = idx >> 7, e = idx & 127;
        wk[r*133 + e] = WK[(jg*32 + r)*128 + e];
    }
    __syncthreads();
    int j = t & 31, iq = t >> 5;
    for (int i2 = 0; i2 < 32; ++i2) {
        int i = iq*32 + i2;
        float acc = 0.f;
        #pragma unroll 8
        for (int e = 0; e < 128; ++e) acc += wq[i*132 + e]*wk[j*133 + e];
        ws[OFF_M + m*16384 + i*128 + jg*32 + j] = acc;
    }
}

/* ---- build 3-split bf16 MFMA B-fragments for 12 M's + Wn ---- */
__global__ void kfrag(const float* __restrict__ Wn, float* __restrict__ ws) {
    int bid = blockIdx.x;  /* 416 = 13*32 */
    int mat = bid >> 5, rem = bid & 31, nt = rem >> 2, ks = rem & 3;
    const float* src = (mat < 12) ? (ws + OFF_M + mat*16384) : Wn;
    int l = threadIdx.x;   /* 64 */
    unsigned short* mf = (unsigned short*)(ws + OFF_MF)
                       + (size_t)mat*49152 + (size_t)((nt*4 + ks)*3)*512 + l*8;
    #pragma unroll
    for (int i = 0; i < 8; ++i) {
        int k = ks*32 + (l >> 4)*8 + i;
        int col = nt*16 + (l & 15);
        float v = src[k*128 + col];
        unsigned short h = f2bf(v);
        float r1 = v - bf2f(h);
        unsigned short mm = f2bf(r1);
        unsigned short lo = f2bf(r1 - bf2f(mm));
        mf[i] = h; mf[512 + i] = mm; mf[1024 + i] = lo;
    }
}

/* ---- 3-split h_wave ---- */
__global__ void khw3(const float* __restrict__ hw, float* __restrict__ ws) {
    unsigned idx = blockIdx.x*256u + threadIdx.x;
    if (idx >= NELE) return;
    unsigned short* hh = (unsigned short*)(ws + OFF_HWB);
    unsigned short* hm = hh + NELE;
    unsigned short* hl = hh + 2u*NELE;
    float v = hw[idx];
    unsigned short a = f2bf(v);
    float r1 = v - bf2f(a);
    unsigned short b = f2bf(r1);
    unsigned short c = f2bf(r1 - bf2f(b));
    hh[idx] = a; hm[idx] = b; hl[idx] = c;
}

/* ---- partial max over n-chunks ---- */
__global__ void kpartmax(const float* __restrict__ hw, float* __restrict__ pmax) {
    int b = blockIdx.x, p = blockIdx.y, d = threadIdx.x;
    int n0 = p*51, ne = n0 + 51; if (ne > N1) ne = N1;
    float m = -INFINITY;
    const float* src = hw + ((size_t)b*N1)*DD + d;
    for (int n = n0; n < ne; ++n) m = fmaxf(m, src[n*DD]);
    pmax[(b*4 + p)*128 + d] = m;
}

/* ---- reduce partial max, g = hmax @ Wg ---- */
__global__ void khmaxg(const float* __restrict__ pmax, const float* __restrict__ Wg,
                       float* __restrict__ g) {
    int b = blockIdx.x, d = threadIdx.x;
    __shared__ float hm[128];
    const float* pm = pmax + b*4*128 + d;
    hm[d] = fmaxf(fmaxf(pm[0], pm[128]), fmaxf(pm[256], pm[384]));
    __syncthreads();
    float acc = 0.f;
    for (int k = 0; k < 128; ++k) acc += hm[k] * Wg[k*128 + d];
    g[b*128 + d] = acc;
}

/* ---- h_hat = h_wave @ Wn + g via MFMA (3-split, 6 products) ---- */
__global__ __launch_bounds__(256) void khhat2(const float* __restrict__ g,
                                              float* __restrict__ ws) {
    int b = blockIdx.x, cg = blockIdx.y;
    int t = threadIdx.x, w = t >> 6, l = t & 63;
    const unsigned short* hwh = (const unsigned short*)(ws + OFF_HWB);
    const unsigned short* hwm = hwh + NELE;
    const unsigned short* hwl = hwh + 2u*NELE;
    const unsigned short* wnf = (const unsigned short*)(ws + OFF_MF) + (size_t)12*49152;
    float* hhat = ws + OFF_HHAT;
    unsigned short* hbh = (unsigned short*)(ws + OFF_HBF);
    unsigned short* hbm = hbh + NELE;
    unsigned short* hbl = hbh + 2u*NELE;
    int col0 = cg*32 + (l & 15);
    float g0 = g[b*128 + col0];
    float g1 = g[b*128 + col0 + 16];
    for (int mt = w; mt < 13; mt += 4) {
        int arow = mt*16 + (l & 15); if (arow > 200) arow = 200;
        size_t abase = ((size_t)b*N1 + arow)*DD;
        float4v acc0 = {g0, g0, g0, g0};
        float4v acc1 = {g1, g1, g1, g1};
        #pragma unroll
        for (int ks = 0; ks < 4; ++ks) {
            size_t ao = abase + ks*32 + (l >> 4)*8;
            short8v ah = *(const short8v*)(hwh + ao);
            short8v am = *(const short8v*)(hwm + ao);
            short8v al = *(const short8v*)(hwl + ao);
            const short8v* bf0 = (const short8v*)(wnf + (size_t)(((cg*2 + 0)*4 + ks)*3)*512) + l;
            const short8v* bf1 = (const short8v*)(wnf + (size_t)(((cg*2 + 1)*4 + ks)*3)*512) + l;
            short8v bh0 = bf0[0], bm0 = bf0[64], bl0 = bf0[128];
            short8v bh1 = bf1[0], bm1 = bf1[64], bl1 = bf1[128];
            acc0 = __builtin_amdgcn_mfma_f32_16x16x32_bf16(ah, bh0, acc0, 0, 0, 0);
            acc1 = __builtin_amdgcn_mfma_f32_16x16x32_bf16(ah, bh1, acc1, 0, 0, 0);
            acc0 = __builtin_amdgcn_mfma_f32_16x16x32_bf16(ah, bm0, acc0, 0, 0, 0);
            acc1 = __builtin_amdgcn_mfma_f32_16x16x32_bf16(ah, bm1, acc1, 0, 0, 0);
            acc0 = __builtin_amdgcn_mfma_f32_16x16x32_bf16(am, bh0, acc0, 0, 0, 0);
            acc1 = __builtin_amdgcn_mfma_f32_16x16x32_bf16(am, bh1, acc1, 0, 0, 0);
            acc0 = __builtin_amdgcn_mfma_f32_16x16x32_bf16(ah, bl0, acc0, 0, 0, 0);
            acc1 = __builtin_amdgcn_mfma_f32_16x16x32_bf16(ah, bl1, acc1, 0, 0, 0);
            acc0 = __builtin_amdgcn_mfma_f32_16x16x32_bf16(al, bh0, acc0, 0, 0, 0);
            acc1 = __builtin_amdgcn_mfma_f32_16x16x32_bf16(al, bh1, acc1, 0, 0, 0);
            acc0 = __builtin_amdgcn_mfma_f32_16x16x32_bf16(am, bm0, acc0, 0, 0, 0);
            acc1 = __builtin_amdgcn_mfma_f32_16x16x32_bf16(am, bm1, acc1, 0, 0, 0);
        }
        #pragma unroll
        for (int r = 0; r < 4; ++r) {
            int row = mt*16 + (l >> 4)*4 + r;
            if (row < N1) {
                size_t i0 = ((size_t)b*N1 + row)*DD + col0;
                float v0 = acc0[r], v1 = acc1[r];
                hhat[i0] = v0; hhat[i0 + 16] = v1;
                unsigned short a0 = f2bf(v0); float r10 = v0 - bf2f(a0);
                unsigned short b0 = f2bf(r10);
                hbh[i0] = a0; hbm[i0] = b0; hbl[i0] = f2bf(r10 - bf2f(b0));
                unsigned short a1 = f2bf(v1); float r11 = v1 - bf2f(a1);
                unsigned short b1 = f2bf(r11);
                hbh[i0+16] = a1; hbm[i0+16] = b1; hbl[i0+16] = f2bf(r11 - bf2f(b1));
            }
        }
    }
}

/* ---- fused: A = hhat @ M[h] (MFMA -> LDS) then comp dots ---- */
__global__ __launch_bounds__(256) void kAC(const int* __restrict__ solution,
                                           float* __restrict__ ws) {
    int b = blockIdx.x, h = blockIdx.y;
    int t = threadIdx.x, w = t >> 6, l = t & 63;
    __shared__ float As[N1*132];
    __shared__ int sol[N1], pre[N1], post[N1];
    if (t < N1) sol[t] = solution[b*N1 + t];
    __syncthreads();
    if (t < N1) { pre[sol[t]] = t; post[t] = sol[sol[t]]; }
    const unsigned short* hbh = (const unsigned short*)(ws + OFF_HBF);
    const unsigned short* hbm = hbh + NELE;
    const unsigned short* hbl = hbh + 2u*NELE;
    const unsigned short* mfm = (const unsigned short*)(ws + OFF_MF) + (size_t)h*49152;
    for (int mt = 0; mt < 13; ++mt) {
        int arow = mt*16 + (l & 15); if (arow > 200) arow = 200;
        size_t abase = ((size_t)b*N1 + arow)*DD;
        float4v acc0 = {0.f, 0.f, 0.f, 0.f};
        float4v acc1 = {0.f, 0.f, 0.f, 0.f};
        #pragma unroll
        for (int ks = 0; ks < 4; ++ks) {
            size_t ao = abase + ks*32 + (l >> 4)*8;
            short8v ah = *(const short8v*)(hbh + ao);
            short8v am = *(const short8v*)(hbm + ao);
            short8v al = *(const short8v*)(hbl + ao);
            const short8v* bf0 = (const short8v*)(mfm + (size_t)(((2*w + 0)*4 + ks)*3)*512) + l;
            const short8v* bf1 = (const short8v*)(mfm + (size_t)(((2*w + 1)*4 + ks)*3)*512) + l;
            short8v bh0 = bf0[0], bm0 = bf0[64], bl0 = bf0[128];
            short8v bh1 = bf1[0], bm1 = bf1[64], bl1 = bf1[128];
            acc0 = __builtin_amdgcn_mfma_f32_16x16x32_bf16(ah, bh0, acc0, 0, 0, 0);
            acc1 = __builtin_amdgcn_mfma_f32_16x16x32_bf16(ah, bh1, acc1, 0, 0, 0);
            acc0 = __builtin_amdgcn_mfma_f32_16x16x32_bf16(ah, bm0, acc0, 0, 0, 0);
            acc1 = __builtin_amdgcn_mfma_f32_16x16x32_bf16(ah, bm1, acc1, 0, 0, 0);
            acc0 = __builtin_amdgcn_mfma_f32_16x16x32_bf16(am, bh0, acc0, 0, 0, 0);
            acc1 = __builtin_amdgcn_mfma_f32_16x16x32_bf16(am, bh1, acc1, 0, 0, 0);
            acc0 = __builtin_amdgcn_mfma_f32_16x16x32_bf16(ah, bl0, acc0, 0, 0, 0);
            acc1 = __builtin_amdgcn_mfma_f32_16x16x32_bf16(ah, bl1, acc1, 0, 0, 0);
            acc0 = __builtin_amdgcn_mfma_f32_16x16x32_bf16(al, bh0, acc0, 0, 0, 0);
            acc1 = __builtin_amdgcn_mfma_f32_16x16x32_bf16(al, bh1, acc1, 0, 0, 0);
            acc0 = __builtin_amdgcn_mfma_f32_16x16x32_bf16(am, bm0, acc0, 0, 0, 0);
            acc1 = __builtin_amdgcn_mfma_f32_16x16x32_bf16(am, bm1, acc1, 0, 0, 0);
        }
        #pragma unroll
        for (int r = 0; r < 4; ++r) {
            int row = mt*16 + (l >> 4)*4 + r;
            if (row < N1) {
                int col = 2*w*16 + (l & 15);
                As[row*132 + col] = acc0[r];
                As[row*132 + col + 16] = acc1[r];
            }
        }
    }
    __syncthreads();
    const float2* X = (const float2*)(ws + OFF_HHAT) + (size_t)b*N1*64;
    float* cmp = ws + OFF_CMP + (h*64 + b)*200;
    for (int n = 1 + w; n <= 200; n += 4) {
        int pn = pre[n], po = post[n];
        float2 xn = X[n*64 + l], xp = X[po*64 + l];
        float2 ap = *(const float2*)&As[pn*132 + 2*l];
        float2 an = *(const float2*)&As[n*132 + 2*l];
        float v = ap.x*(xn.x - xp.x) + ap.y*(xn.y - xp.y) + an.x*xp.x + an.y*xp.y;
        #pragma unroll
        for (int off = 32; off; off >>= 1) v += __shfl_xor(v, off);
        if (l == 0) cmp[n - 1] = v;
    }
}

/* ---- removal MLP + softmax/argmax ---- */
__global__ void krm2(const float* __restrict__ sel, const int* __restrict__ pre_action,
                     const float* __restrict__ w1, const float* __restrict__ b1,
                     const float* __restrict__ w2, const float* __restrict__ b2,
                     const float* __restrict__ w3, const float* __restrict__ b3,
                     const float* __restrict__ cmpg, float* __restrict__ sc) {
    int b = blockIdx.x, t = threadIdx.x;  /* 128 */
    __shared__ float t1l[100];
    if (t < 100) {
        float f[12];
        #pragma unroll
        for (int h = 0; h < 4; ++h) {
            f[h]     = cmpg[(h*64 + b)*200 + t];
            f[4 + h] = cmpg[(h*64 + b)*200 + 100 + t];
        }
        #pragma unroll
        for (int s = 0; s < 4; ++s) f[8 + s] = sel[b*400 + s*100 + t];
        float h1[32];
        #pragma unroll
        for (int k = 0; k < 32; ++k) h1[k] = b1[k];
        #pragma unroll
        for (int j = 0; j < 12; ++j) {
            const float* wr = w1 + j*32;
            #pragma unroll
            for (int k = 0; k < 32; ++k) h1[k] += f[j]*wr[k];
        }
        #pragma unroll
        for (int k = 0; k < 32; ++k) h1[k] = fmaxf(h1[k], 0.f);
        float acc[32];
        #pragma unroll
        for (int j = 0; j < 32; ++j) acc[j] = b2[j];
        #pragma unroll
        for (int k = 0; k < 32; ++k) {
            const float* wr = w2 + k*32;
            #pragma unroll
            for (int j = 0; j < 32; ++j) acc[j] += h1[k]*wr[j];
        }
        float out = b3[0];
        #pragma unroll
        for (int j = 0; j < 32; ++j) out += fmaxf(acc[j], 0.f)*w3[j];
        t1l[t] = tanhf(out)*6.0f;
    }
    __syncthreads();
    if (t == 0) {
        if (pre_action[0] > 0) t1l[pre_action[b*2]] = NEGV;
        float M = -INFINITY; int a1 = 0;
        for (int i = 0; i < 100; ++i) if (t1l[i] > M) { M = t1l[i]; a1 = i; }
        float S = 0.f;
        for (int i = 0; i < 100; ++i) S += __expf(t1l[i] - M);
        int* ia = (int*)sc;
        ia[b] = a1; ia[64 + b] = 1 + a1; ia[128 + b] = 101 + a1;
        sc[192 + b] = -__logf(S);
    }
}

/* ---- 16 query vectors ---- */
__global__ void kqvec(const float* __restrict__ Mall, const float* __restrict__ hhat,
                      const float* __restrict__ sc, float* __restrict__ q) {
    int b = blockIdx.x, h = blockIdx.y, j = threadIdx.x;
    const int* ia = (const int*)sc;
    int pp = ia[64 + b], pd = ia[128 + b];
    __shared__ float xp[128], xd[128];
    const float* hb = hhat + (size_t)b*N1*DD;
    xp[j] = hb[pp*DD + j];
    xd[j] = hb[pd*DD + j];
    __syncthreads();
    const float* M1 = Mall + (4 + h)*16384;
    const float* M2 = Mall + (8 + h)*16384;
    float a1p = 0, a2p = 0, a1d = 0, a2d = 0;
    for (int i = 0; i < 128; ++i) {
        float w1v = M1[i*128 + j], w2v = M2[i*128 + j];
        a1p += xp[i]*w1v; a1d += xd[i]*w1v;
        a2p += xp[i]*w2v; a2d += xd[i]*w2v;
    }
    q[((0*4 + h)*64 + b)*128 + j] = a1p*QSCALE;
    q[((1*4 + h)*64 + b)*128 + j] = a2p*QSCALE;
    q[((2*4 + h)*64 + b)*128 + j] = a1d*QSCALE;
    q[((3*4 + h)*64 + b)*128 + j] = a2d*QSCALE;
}

/* ---- rowH(+b1)/colH ---- */
__global__ void krowcol(const int* __restrict__ solution, const float* __restrict__ w1,
                        const float* __restrict__ b1, const float* __restrict__ qg,
                        const float* __restrict__ hhat, float* __restrict__ rowH,
                        float* __restrict__ colH) {
    int b = blockIdx.x, ch = blockIdx.y, t = threadIdx.x;  /* block 64 */
    int n = ch*51 + t;
    int ne = ch*51 + 51; if (ne > N1) ne = N1;
    if (n >= ne || t >= 51) return;
    int sn = solution[b*N1 + n];
    const float* ra = hhat + ((size_t)b*N1 + n)*DD;
    const float* rb = hhat + ((size_t)b*N1 + sn)*DD;
    float cv[16];
    #pragma unroll
    for (int j = 0; j < 16; ++j) cv[j] = 0.f;
    for (int ec = 0; ec < 4; ++ec) {
        float xa[32], xb[32];
        #pragma unroll
        for (int q4 = 0; q4 < 8; ++q4) {
            float4 va = ((const float4*)(ra + ec*32))[q4];
            float4 vb = ((const float4*)(rb + ec*32))[q4];
            xa[q4*4+0]=va.x; xa[q4*4+1]=va.y; xa[q4*4+2]=va.z; xa[q4*4+3]=va.w;
            xb[q4*4+0]=vb.x; xb[q4*4+1]=vb.y; xb[q4*4+2]=vb.z; xb[q4*4+3]=vb.w;
        }
        #pragma unroll
        for (int j = 0; j < 16; ++j) {
            const float* qp = qg + ((size_t)j*64 + b)*128 + ec*32;
            int kind = j >> 2;
            float a = 0.f;
            if (kind & 1) {
                #pragma unroll
                for (int e = 0; e < 32; ++e) a += qp[e]*xb[e];
            } else {
                #pragma unroll
                for (int e = 0; e < 32; ++e) a += qp[e]*xa[e];
            }
            cv[j] += a;
        }
    }
    float* rO = rowH + ((size_t)b*N1 + n)*32;
    float* cO = colH + ((size_t)b*N1 + n)*32;
    #pragma unroll
    for (int k = 0; k < 32; ++k) {
        float rh = b1[k], chh = 0.f;
        #pragma unroll
        for (int j = 0; j < 8; ++j)  rh  += cv[j]*w1[j*32 + k];
        #pragma unroll
        for (int j = 8; j < 16; ++j) chh += cv[j]*w1[j*32 + k];
        rO[k] = rh; cO[k] = chh;
    }
}

/* ---- t2 via bf16 hi/lo MFMA: 1 wave, 64 cols x 26 rows per block ---- */
__global__ __launch_bounds__(64) void kt2(
        const unsigned char* __restrict__ maskt,
        const float* __restrict__ rowH, const float* __restrict__ colH,
        const unsigned short* __restrict__ w2f,
        const float* __restrict__ b2g, const float* __restrict__ w3g,
        const float* __restrict__ b3g,
        float* __restrict__ pm, float* __restrict__ ps, int* __restrict__ pi) {
    int b = blockIdx.x, cy = blockIdx.y, rz = blockIdx.z;
    int l = threadIdx.x;
    int c0 = cy*64;
    int r0 = rz*26, rend = r0 + 26; if (rend > N1) rend = N1;
    int rcnt = rend - r0;
    __shared__ float colc[64*36];
    __shared__ float rowr[26*36];

    const short8v* wf = (const short8v*)w2f;
    short8v w2hi0 = wf[0*64 + l];
    short8v w2lo0 = wf[1*64 + l];
    short8v w2hi1 = wf[2*64 + l];
    short8v w2lo1 = wf[3*64 + l];
    int sg = l >> 4;
    float4v b2f0 = *(const float4v*)(b2g + sg*4);
    float4v b2f1 = *(const float4v*)(b2g + 16 + sg*4);
    float4v w3f0 = *(const float4v*)(w3g + sg*4);
    float4v w3f1 = *(const float4v*)(w3g + 16 + sg*4);
    float b3v = b3g[0];

    {
        int cg = c0 + l;
        float4v* dst = (float4v*)(colc + l*36);
        if (cg < N1) {
            const float4v* src = (const float4v*)(colH + ((size_t)b*N1 + cg)*32);
            #pragma unroll
            for (int q = 0; q < 8; ++q) dst[q] = src[q];
        } else {
            float4v z = {0.f, 0.f, 0.f, 0.f};
            #pragma unroll
            for (int q = 0; q < 8; ++q) dst[q] = z;
        }
    }
    for (int idx = l; idx < rcnt*32; idx += 64) {
        int rr = idx >> 5, k = idx & 31;
        rowr[rr*36 + k] = rowH[((size_t)b*N1 + r0 + rr)*32 + k];
    }
    __syncthreads();

    float m = -INFINITY, s = 0.f;
    int mi = 0x7fffffff;
    int c = c0 + l;
    bool valid = c < N1;
    const unsigned char* mrow = maskt + (size_t)b*NN + c0 + (l < 64 ? l : 0);

    for (int rr = 0; rr < rcnt; ++rr) {
        int r = r0 + rr;
        const float4v* rp = (const float4v*)(rowr + rr*36 + sg*8);
        float4v ra = rp[0], rb = rp[1];
        float outv = 0.f;
        #pragma unroll
        for (int g = 0; g < 4; ++g) {
            const float4v* cp = (const float4v*)(colc + (16*g + (l & 15))*36 + sg*8);
            float4v ca = cp[0], cb = cp[1];
            float h[8];
            #pragma unroll
            for (int e = 0; e < 4; ++e) {
                h[e]   = fmaxf(ra[e] + ca[e], 0.f);
                h[4+e] = fmaxf(rb[e] + cb[e], 0.f);
            }
            short8v bh, bl;
            #pragma unroll
            for (int e = 0; e < 8; ++e) {
                unsigned short hb = f2bf(h[e]);
                bh[e] = (short)hb;
                bl[e] = (short)f2bf(h[e] - bf2f(hb));
            }
            float4v a0 = b2f0, a1 = b2f1;
            a0 = __builtin_amdgcn_mfma_f32_16x16x32_bf16(w2hi0, bh, a0, 0, 0, 0);
            a0 = __builtin_amdgcn_mfma_f32_16x16x32_bf16(w2hi0, bl, a0, 0, 0, 0);
            a0 = __builtin_amdgcn_mfma_f32_16x16x32_bf16(w2lo0, bh, a0, 0, 0, 0);
            a0 = __builtin_amdgcn_mfma_f32_16x16x32_bf16(w2lo0, bl, a0, 0, 0, 0);
            a1 = __builtin_amdgcn_mfma_f32_16x16x32_bf16(w2hi1, bh, a1, 0, 0, 0);
            a1 = __builtin_amdgcn_mfma_f32_16x16x32_bf16(w2hi1, bl, a1, 0, 0, 0);
            a1 = __builtin_amdgcn_mfma_f32_16x16x32_bf16(w2lo1, bh, a1, 0, 0, 0);
            a1 = __builtin_amdgcn_mfma_f32_16x16x32_bf16(w2lo1, bl, a1, 0, 0, 0);
            float p = 0.f;
            #pragma unroll
            for (int reg = 0; reg < 4; ++reg) {
                p += fmaxf(a0[reg], 0.f)*w3f0[reg];
                p += fmaxf(a1[reg], 0.f)*w3f1[reg];
            }
            p += __shfl_xor(p, 16);
            p += __shfl_xor(p, 32);
            if (sg == g) outv = p + b3v;
        }
        float ex = __expf(2.f*outv);
        float tv = 6.f - 12.f/(ex + 1.f);
        if (mrow[(size_t)r*N1]) tv = NEGV;
        if (valid) {
            if (tv > m) { s = s*__expf(m - tv) + 1.f; m = tv; mi = r*N1 + c; }
            else        { s += __expf(tv - m); }
        }
    }
    #pragma unroll
    for (int off = 1; off < 64; off <<= 1) {
        float om = __shfl_xor(m, off);
        float os = __shfl_xor(s, off);
        int oi = __shfl_xor(mi, off);
        float M2 = fmaxf(m, om);
        float sn = (s > 0.f ? s*__expf(m - M2) : 0.f)
                 + (os > 0.f ? os*__expf(om - M2) : 0.f);
        int in_;
        if (m > om) in_ = mi; else if (om > m) in_ = oi; else in_ = (mi < oi ? mi : oi);
        m = M2; s = sn; mi = in_;
    }
    if (l == 0) {
        int slot = b*32 + cy*8 + rz;
        pm[slot] = m; ps[slot] = s; pi[slot] = mi;
    }
}

/* ---- final reduce + outputs ---- */
__global__ void kfinal(float* __restrict__ out, const float* __restrict__ pm,
                       const float* __restrict__ ps, const int* __restrict__ pi,
                       const float* __restrict__ sc) {
    int b = blockIdx.x, lane = threadIdx.x;  /* 64 */
    float m = -INFINITY, s = 0.f;
    int mi = 0x7fffffff;
    if (lane < 32) {
        m = pm[b*32 + lane];
        s = ps[b*32 + lane];
        mi = pi[b*32 + lane];
    }
    #pragma unroll
    for (int off = 1; off < 64; off <<= 1) {
        float om = __shfl_xor(m, off);
        float os = __shfl_xor(s, off);
        int oi = __shfl_xor(mi, off);
        float M2 = fmaxf(m, om);
        float sn = (s > 0.f ? s*__expf(m - M2) : 0.f)
                 + (os > 0.f ? os*__expf(om - M2) : 0.f);
        int in_;
        if (m > om) in_ = mi; else if (om > m) in_ = oi; else in_ = (mi < oi ? mi : oi);
        m = M2; s = sn; mi = in_;
    }
    if (lane == 0) {
        float ll2 = -__logf(s);
        const int* ia = (const int*)sc;
        out[b*3 + 0] = (float)ia[b];
        out[b*3 + 1] = (float)(mi / N1);
        out[b*3 + 2] = (float)(mi % N1);
        out[192 + b] = sc[192 + b] + ll2;
    }
}

extern "C" void kernel_launch(void* const* d_in, const int* in_sizes, int n_in,
                              void* d_out, int out_size, void* d_ws, size_t ws_size,
                              hipStream_t stream) {
    const float* h_wave    = (const float*)d_in[0];
    const int*   solution  = (const int*)d_in[1];
    const float* sel       = (const float*)d_in[2];
    const int*   pre_act   = (const int*)d_in[3];
    const unsigned char* maskt = (const unsigned char*)d_in[4];
    const float* Wn    = (const float*)d_in[5];
    const float* Wg    = (const float*)d_in[6];
    const float* rmWQ  = (const float*)d_in[7];
    const float* rmWK  = (const float*)d_in[8];
    const float* rm_w1 = (const float*)d_in[9];
    const float* rm_b1 = (const float*)d_in[10];
    const float* rm_w2 = (const float*)d_in[11];
    const float* rm_b2 = (const float*)d_in[12];
    const float* rm_w3 = (const float*)d_in[13];
    const float* rm_b3 = (const float*)d_in[14];
    const float* i1Wq  = (const float*)d_in[15];
    const float* i1Wk  = (const float*)d_in[16];
    const float* i2Wq  = (const float*)d_in[17];
    const float* i2Wk  = (const float*)d_in[18];
    const float* re_w1 = (const float*)d_in[19];
    const float* re_b1 = (const float*)d_in[20];
    const float* re_w2 = (const float*)d_in[21];
    const float* re_b2 = (const float*)d_in[22];
    const float* re_w3 = (const float*)d_in[23];
    const float* re_b3 = (const float*)d_in[24];
    float* ws = (float*)d_ws;
    float* out = (float*)d_out;

    kprep2<<<dim3(13, 4), dim3(128), 0, stream>>>(rmWQ, rmWK, i1Wq, i1Wk, i2Wq, i2Wk,
                                                  re_w2, ws);
    kfrag<<<dim3(416), dim3(64), 0, stream>>>(Wn, ws);
    khw3<<<dim3(6432), dim3(256), 0, stream>>>(h_wave, ws);
    kpartmax<<<dim3(64, 4), dim3(128), 0, stream>>>(h_wave, ws + OFF_PMAX);
    khmaxg<<<dim3(64), dim3(128), 0, stream>>>(ws + OFF_PMAX, Wg, ws + OFF_G);
    khhat2<<<dim3(64, 4), dim3(256), 0, stream>>>(ws + OFF_G, ws);
    kAC<<<dim3(64, 4), dim3(256), 0, stream>>>(solution, ws);
    krm2<<<dim3(64), dim3(128), 0, stream>>>(sel, pre_act, rm_w1, rm_b1, rm_w2, rm_b2,
                                             rm_w3, rm_b3, ws + OFF_CMP, ws + OFF_SC);
    kqvec<<<dim3(64, 4), dim3(128), 0, stream>>>(ws + OFF_M, ws + OFF_HHAT,
                                                 ws + OFF_SC, ws + OFF_Q);
    krowcol<<<dim3(64, 4), dim3(64), 0, stream>>>(solution, re_w1, re_b1,
                                                  ws + OFF_Q, ws + OFF_HHAT,
                                                  ws + OFF_ROWH, ws + OFF_COLH);
    kt2<<<dim3(64, 4, 8), dim3(64), 0, stream>>>(maskt, ws + OFF_ROWH, ws + OFF_COLH,
                                                 (const unsigned short*)(ws + OFF_W2F),
                                                 re_b2, re_w3, re_b3,
                                                 ws + OFF_PM, ws + OFF_PS,
                                                 (int*)(ws + OFF_PI));
    kfinal<<<dim3(64), dim3(64), 0, stream>>>(out, ws + OFF_PM, ws + OFF_PS,
                                              (const int*)(ws + OFF_PI), ws + OFF_SC);
}

// Round 6
// 354.546 us; speedup vs baseline: 1.8134x; 1.0242x over previous
//
#include <hip/hip_runtime.h>
#include <math.h>

#define BB 64
#define N1 201
#define DD 128
#define HALF 100
#define NN (N1*N1)
#define NEGV (-1e20f)
#define QSCALE 0.08838834764831845f  /* 1/sqrt(128) */
#define NELE 1646592u                /* 64*201*128 */

typedef __attribute__((ext_vector_type(8))) short short8v;
typedef __attribute__((ext_vector_type(4))) float float4v;

/* ws offsets in floats */
#define OFF_M    0u          /* 12*16384 f32 M matrices */
#define OFF_MF   196608u     /* 13 mats * 24576 (3-split bf16 frags) */
#define OFF_HWB  516096u     /* h_wave 3-split: 3*823296 */
#define OFF_HHAT 2985984u    /* f32 1646592 */
#define OFF_HBF  4632576u    /* hhat 3-split */
#define OFF_G    7102464u    /* 64*128 */
#define OFF_CMP  7110656u    /* 4*64*200 */
#define OFF_Q    7161856u    /* 16*64*128 */
#define OFF_ROWH 7292928u    /* 64*201*32 */
#define OFF_COLH 7704576u    /* 64*201*32 */
#define OFF_SC   8116224u    /* 256 */
#define OFF_PM   8116480u    /* 64*64 */
#define OFF_PS   8120576u
#define OFF_PI   8124672u
#define OFF_W2F  8128768u    /* kt2 w2 frags (2-split) */

__device__ __forceinline__ unsigned short f2bf(float x) {
    unsigned u = __float_as_uint(x);
    unsigned r = u + 0x7fffu + ((u >> 16) & 1u);
    return (unsigned short)(r >> 16);
}
__device__ __forceinline__ float bf2f(unsigned short h) {
    return __uint_as_float(((unsigned)h) << 16);
}

/* ---- M_h = WQ_h @ WK_h^T : grid (12,4ig,4jg), 34KB LDS, 4 blocks/CU ---- */
__global__ void kprep2(const float* __restrict__ rmWQ, const float* __restrict__ rmWK,
                       const float* __restrict__ i1Wq, const float* __restrict__ i1Wk,
                       const float* __restrict__ i2Wq, const float* __restrict__ i2Wk,
                       float* __restrict__ ws) {
    int m = blockIdx.x, ig = blockIdx.y, jg = blockIdx.z, t = threadIdx.x;  /* 128 */
    const float* WQ; const float* WK;
    if (m < 4)      { WQ = rmWQ + m*16384;     WK = rmWK + m*16384; }
    else if (m < 8) { WQ = i1Wq + (m-4)*16384; WK = i1Wk + (m-4)*16384; }
    else            { WQ = i2Wq + (m-8)*16384; WK = i2Wk + (m-8)*16384; }
    __shared__ float wq[32*132];
    __shared__ float wk[32*133];
    for (int idx = t; idx < 32*128; idx += 128) {
        int r = idx >> 7, e = idx & 127;
        wq[r*132 + e] = WQ[(ig*32 + r)*128 + e];
        wk[r*133 + e] = WK[(jg*32 + r)*128 + e];
    }
    __syncthreads();
    int j = t & 31, iq = t >> 5;
    #pragma unroll
    for (int i2 = 0; i2 < 8; ++i2) {
        int i = iq*8 + i2;
        float acc = 0.f;
        #pragma unroll 8
        for (int e = 0; e < 128; ++e) acc += wq[i*132 + e]*wk[j*133 + e];
        ws[OFF_M + m*16384 + (ig*32 + i)*128 + jg*32 + j] = acc;
    }
}

/* ---- 3-split bf16 MFMA B-fragments for 12 M's + Wn; block 416 = kt2 w2 frags ---- */
__global__ void kfrag(const float* __restrict__ Wn, const float* __restrict__ re_w2,
                      float* __restrict__ ws) {
    int bid = blockIdx.x;  /* 417 */
    int l = threadIdx.x;   /* 64 */
    if (bid == 416) {
        unsigned short* w2f = (unsigned short*)(ws + OFF_W2F);
        for (int idx = l; idx < 2048; idx += 64) {
            int fs = idx >> 9, ll = (idx >> 3) & 63, i = idx & 7;
            int j = 16*(fs >> 1) + (ll & 15);
            int k = ((ll >> 4)*8) + i;
            float v = re_w2[k*32 + j];
            unsigned short hi = f2bf(v);
            w2f[idx] = (fs & 1) ? f2bf(v - bf2f(hi)) : hi;
        }
        return;
    }
    int mat = bid >> 5, rem = bid & 31, nt = rem >> 2, ks = rem & 3;
    const float* src = (mat < 12) ? (ws + OFF_M + mat*16384) : Wn;
    unsigned short* mf = (unsigned short*)(ws + OFF_MF)
                       + (size_t)mat*49152 + (size_t)((nt*4 + ks)*3)*512 + l*8;
    #pragma unroll
    for (int i = 0; i < 8; ++i) {
        int k = ks*32 + (l >> 4)*8 + i;
        int col = nt*16 + (l & 15);
        float v = src[k*128 + col];
        unsigned short h = f2bf(v);
        float r1 = v - bf2f(h);
        unsigned short mm = f2bf(r1);
        unsigned short lo = f2bf(r1 - bf2f(mm));
        mf[i] = h; mf[512 + i] = mm; mf[1024 + i] = lo;
    }
}

/* ---- 3-split h_wave ---- */
__global__ void khw3(const float* __restrict__ hw, float* __restrict__ ws) {
    unsigned idx = blockIdx.x*256u + threadIdx.x;
    if (idx >= NELE) return;
    unsigned short* hh = (unsigned short*)(ws + OFF_HWB);
    unsigned short* hm = hh + NELE;
    unsigned short* hl = hh + 2u*NELE;
    float v = hw[idx];
    unsigned short a = f2bf(v);
    float r1 = v - bf2f(a);
    unsigned short b = f2bf(r1);
    unsigned short c = f2bf(r1 - bf2f(b));
    hh[idx] = a; hm[idx] = b; hl[idx] = c;
}

/* ---- hmax over N1 + g = hmax @ Wg (fused) ---- */
__global__ void khmaxg2(const float* __restrict__ hw, const float* __restrict__ Wg,
                        float* __restrict__ g) {
    int b = blockIdx.x, d = threadIdx.x;
    __shared__ float hm[128];
    float m = -INFINITY;
    const float* src = hw + (size_t)b*N1*DD + d;
    for (int n = 0; n < N1; ++n) m = fmaxf(m, src[n*DD]);
    hm[d] = m;
    __syncthreads();
    float acc = 0.f;
    for (int k = 0; k < 128; ++k) acc += hm[k] * Wg[k*128 + d];
    g[b*128 + d] = acc;
}

/* ---- h_hat = h_wave @ Wn + g via MFMA (3-split, 6 products) ---- */
__global__ __launch_bounds__(256) void khhat2(const float* __restrict__ g,
                                              float* __restrict__ ws) {
    int b = blockIdx.x, cg = blockIdx.y;
    int t = threadIdx.x, w = t >> 6, l = t & 63;
    const unsigned short* hwh = (const unsigned short*)(ws + OFF_HWB);
    const unsigned short* hwm = hwh + NELE;
    const unsigned short* hwl = hwh + 2u*NELE;
    const unsigned short* wnf = (const unsigned short*)(ws + OFF_MF) + (size_t)12*49152;
    float* hhat = ws + OFF_HHAT;
    unsigned short* hbh = (unsigned short*)(ws + OFF_HBF);
    unsigned short* hbm = hbh + NELE;
    unsigned short* hbl = hbh + 2u*NELE;
    int col0 = cg*32 + (l & 15);
    float g0 = g[b*128 + col0];
    float g1 = g[b*128 + col0 + 16];
    for (int mt = w; mt < 13; mt += 4) {
        int arow = mt*16 + (l & 15); if (arow > 200) arow = 200;
        size_t abase = ((size_t)b*N1 + arow)*DD;
        float4v acc0 = {g0, g0, g0, g0};
        float4v acc1 = {g1, g1, g1, g1};
        #pragma unroll
        for (int ks = 0; ks < 4; ++ks) {
            size_t ao = abase + ks*32 + (l >> 4)*8;
            short8v ah = *(const short8v*)(hwh + ao);
            short8v am = *(const short8v*)(hwm + ao);
            short8v al = *(const short8v*)(hwl + ao);
            const short8v* bf0 = (const short8v*)(wnf + (size_t)(((cg*2 + 0)*4 + ks)*3)*512) + l;
            const short8v* bf1 = (const short8v*)(wnf + (size_t)(((cg*2 + 1)*4 + ks)*3)*512) + l;
            short8v bh0 = bf0[0], bm0 = bf0[64], bl0 = bf0[128];
            short8v bh1 = bf1[0], bm1 = bf1[64], bl1 = bf1[128];
            acc0 = __builtin_amdgcn_mfma_f32_16x16x32_bf16(ah, bh0, acc0, 0, 0, 0);
            acc1 = __builtin_amdgcn_mfma_f32_16x16x32_bf16(ah, bh1, acc1, 0, 0, 0);
            acc0 = __builtin_amdgcn_mfma_f32_16x16x32_bf16(ah, bm0, acc0, 0, 0, 0);
            acc1 = __builtin_amdgcn_mfma_f32_16x16x32_bf16(ah, bm1, acc1, 0, 0, 0);
            acc0 = __builtin_amdgcn_mfma_f32_16x16x32_bf16(am, bh0, acc0, 0, 0, 0);
            acc1 = __builtin_amdgcn_mfma_f32_16x16x32_bf16(am, bh1, acc1, 0, 0, 0);
            acc0 = __builtin_amdgcn_mfma_f32_16x16x32_bf16(ah, bl0, acc0, 0, 0, 0);
            acc1 = __builtin_amdgcn_mfma_f32_16x16x32_bf16(ah, bl1, acc1, 0, 0, 0);
            acc0 = __builtin_amdgcn_mfma_f32_16x16x32_bf16(al, bh0, acc0, 0, 0, 0);
            acc1 = __builtin_amdgcn_mfma_f32_16x16x32_bf16(al, bh1, acc1, 0, 0, 0);
            acc0 = __builtin_amdgcn_mfma_f32_16x16x32_bf16(am, bm0, acc0, 0, 0, 0);
            acc1 = __builtin_amdgcn_mfma_f32_16x16x32_bf16(am, bm1, acc1, 0, 0, 0);
        }
        #pragma unroll
        for (int r = 0; r < 4; ++r) {
            int row = mt*16 + (l >> 4)*4 + r;
            if (row < N1) {
                size_t i0 = ((size_t)b*N1 + row)*DD + col0;
                float v0 = acc0[r], v1 = acc1[r];
                hhat[i0] = v0; hhat[i0 + 16] = v1;
                unsigned short a0 = f2bf(v0); float r10 = v0 - bf2f(a0);
                unsigned short b0 = f2bf(r10);
                hbh[i0] = a0; hbm[i0] = b0; hbl[i0] = f2bf(r10 - bf2f(b0));
                unsigned short a1 = f2bf(v1); float r11 = v1 - bf2f(a1);
                unsigned short b1 = f2bf(r11);
                hbh[i0+16] = a1; hbm[i0+16] = b1; hbl[i0+16] = f2bf(r11 - bf2f(b1));
            }
        }
    }
}

/* ---- fused: A = hhat @ M[h] (MFMA -> LDS) then comp dots ---- */
__global__ __launch_bounds__(256) void kAC(const int* __restrict__ solution,
                                           float* __restrict__ ws) {
    int b = blockIdx.x, h = blockIdx.y;
    int t = threadIdx.x, w = t >> 6, l = t & 63;
    __shared__ float As[N1*132];
    __shared__ int sol[N1], pre[N1], post[N1];
    if (t < N1) sol[t] = solution[b*N1 + t];
    __syncthreads();
    if (t < N1) { pre[sol[t]] = t; post[t] = sol[sol[t]]; }
    const unsigned short* hbh = (const unsigned short*)(ws + OFF_HBF);
    const unsigned short* hbm = hbh + NELE;
    const unsigned short* hbl = hbh + 2u*NELE;
    const unsigned short* mfm = (const unsigned short*)(ws + OFF_MF) + (size_t)h*49152;
    for (int mt = 0; mt < 13; ++mt) {
        int arow = mt*16 + (l & 15); if (arow > 200) arow = 200;
        size_t abase = ((size_t)b*N1 + arow)*DD;
        float4v acc0 = {0.f, 0.f, 0.f, 0.f};
        float4v acc1 = {0.f, 0.f, 0.f, 0.f};
        #pragma unroll
        for (int ks = 0; ks < 4; ++ks) {
            size_t ao = abase + ks*32 + (l >> 4)*8;
            short8v ah = *(const short8v*)(hbh + ao);
            short8v am = *(const short8v*)(hbm + ao);
            short8v al = *(const short8v*)(hbl + ao);
            const short8v* bf0 = (const short8v*)(mfm + (size_t)(((2*w + 0)*4 + ks)*3)*512) + l;
            const short8v* bf1 = (const short8v*)(mfm + (size_t)(((2*w + 1)*4 + ks)*3)*512) + l;
            short8v bh0 = bf0[0], bm0 = bf0[64], bl0 = bf0[128];
            short8v bh1 = bf1[0], bm1 = bf1[64], bl1 = bf1[128];
            acc0 = __builtin_amdgcn_mfma_f32_16x16x32_bf16(ah, bh0, acc0, 0, 0, 0);
            acc1 = __builtin_amdgcn_mfma_f32_16x16x32_bf16(ah, bh1, acc1, 0, 0, 0);
            acc0 = __builtin_amdgcn_mfma_f32_16x16x32_bf16(ah, bm0, acc0, 0, 0, 0);
            acc1 = __builtin_amdgcn_mfma_f32_16x16x32_bf16(ah, bm1, acc1, 0, 0, 0);
            acc0 = __builtin_amdgcn_mfma_f32_16x16x32_bf16(am, bh0, acc0, 0, 0, 0);
            acc1 = __builtin_amdgcn_mfma_f32_16x16x32_bf16(am, bh1, acc1, 0, 0, 0);
            acc0 = __builtin_amdgcn_mfma_f32_16x16x32_bf16(ah, bl0, acc0, 0, 0, 0);
            acc1 = __builtin_amdgcn_mfma_f32_16x16x32_bf16(ah, bl1, acc1, 0, 0, 0);
            acc0 = __builtin_amdgcn_mfma_f32_16x16x32_bf16(al, bh0, acc0, 0, 0, 0);
            acc1 = __builtin_amdgcn_mfma_f32_16x16x32_bf16(al, bh1, acc1, 0, 0, 0);
            acc0 = __builtin_amdgcn_mfma_f32_16x16x32_bf16(am, bm0, acc0, 0, 0, 0);
            acc1 = __builtin_amdgcn_mfma_f32_16x16x32_bf16(am, bm1, acc1, 0, 0, 0);
        }
        #pragma unroll
        for (int r = 0; r < 4; ++r) {
            int row = mt*16 + (l >> 4)*4 + r;
            if (row < N1) {
                int col = 2*w*16 + (l & 15);
                As[row*132 + col] = acc0[r];
                As[row*132 + col + 16] = acc1[r];
            }
        }
    }
    __syncthreads();
    const float2* X = (const float2*)(ws + OFF_HHAT) + (size_t)b*N1*64;
    float* cmp = ws + OFF_CMP + (h*64 + b)*200;
    for (int n = 1 + w; n <= 200; n += 4) {
        int pn = pre[n], po = post[n];
        float2 xn = X[n*64 + l], xp = X[po*64 + l];
        float2 ap = *(const float2*)&As[pn*132 + 2*l];
        float2 an = *(const float2*)&As[n*132 + 2*l];
        float v = ap.x*(xn.x - xp.x) + ap.y*(xn.y - xp.y) + an.x*xp.x + an.y*xp.y;
        #pragma unroll
        for (int off = 32; off; off >>= 1) v += __shfl_xor(v, off);
        if (l == 0) cmp[n - 1] = v;
    }
}

/* ---- removal MLP + softmax/argmax + 16 query vectors (fused) ---- */
__global__ void krmq(const float* __restrict__ sel, const int* __restrict__ pre_action,
                     const float* __restrict__ w1, const float* __restrict__ b1,
                     const float* __restrict__ w2, const float* __restrict__ b2,
                     const float* __restrict__ w3, const float* __restrict__ b3,
                     const float* __restrict__ Mall, const float* __restrict__ hhat,
                     const float* __restrict__ cmpg, float* __restrict__ sc,
                     float* __restrict__ q) {
    int b = blockIdx.x, t = threadIdx.x;  /* 128 */
    __shared__ float t1l[100];
    __shared__ int ppd[2];
    __shared__ float xp[128], xd[128];
    if (t < 100) {
        float f[12];
        #pragma unroll
        for (int h = 0; h < 4; ++h) {
            f[h]     = cmpg[(h*64 + b)*200 + t];
            f[4 + h] = cmpg[(h*64 + b)*200 + 100 + t];
        }
        #pragma unroll
        for (int s = 0; s < 4; ++s) f[8 + s] = sel[b*400 + s*100 + t];
        float h1[32];
        #pragma unroll
        for (int k = 0; k < 32; ++k) h1[k] = b1[k];
        #pragma unroll
        for (int j = 0; j < 12; ++j) {
            const float* wr = w1 + j*32;
            #pragma unroll
            for (int k = 0; k < 32; ++k) h1[k] += f[j]*wr[k];
        }
        #pragma unroll
        for (int k = 0; k < 32; ++k) h1[k] = fmaxf(h1[k], 0.f);
        float acc[32];
        #pragma unroll
        for (int j = 0; j < 32; ++j) acc[j] = b2[j];
        #pragma unroll
        for (int k = 0; k < 32; ++k) {
            const float* wr = w2 + k*32;
            #pragma unroll
            for (int j = 0; j < 32; ++j) acc[j] += h1[k]*wr[j];
        }
        float out = b3[0];
        #pragma unroll
        for (int j = 0; j < 32; ++j) out += fmaxf(acc[j], 0.f)*w3[j];
        t1l[t] = tanhf(out)*6.0f;
    }
    __syncthreads();
    if (t == 0) {
        if (pre_action[0] > 0) t1l[pre_action[b*2]] = NEGV;
        float M = -INFINITY; int a1 = 0;
        for (int i = 0; i < 100; ++i) if (t1l[i] > M) { M = t1l[i]; a1 = i; }
        float S = 0.f;
        for (int i = 0; i < 100; ++i) S += __expf(t1l[i] - M);
        int* ia = (int*)sc;
        ia[b] = a1;
        sc[192 + b] = -__logf(S);
        ppd[0] = 1 + a1; ppd[1] = 101 + a1;
    }
    __syncthreads();
    int pp = ppd[0], pd = ppd[1];
    const float* hb = hhat + (size_t)b*N1*DD;
    xp[t] = hb[pp*DD + t];
    xd[t] = hb[pd*DD + t];
    __syncthreads();
    int j = t;
    #pragma unroll
    for (int h = 0; h < 4; ++h) {
        const float* M1 = Mall + (4 + h)*16384;
        const float* M2 = Mall + (8 + h)*16384;
        float a1p = 0, a2p = 0, a1d = 0, a2d = 0;
        for (int i = 0; i < 128; ++i) {
            float w1v = M1[i*128 + j], w2v = M2[i*128 + j];
            a1p += xp[i]*w1v; a1d += xd[i]*w1v;
            a2p += xp[i]*w2v; a2d += xd[i]*w2v;
        }
        q[((0*4 + h)*64 + b)*128 + j] = a1p*QSCALE;
        q[((1*4 + h)*64 + b)*128 + j] = a2p*QSCALE;
        q[((2*4 + h)*64 + b)*128 + j] = a1d*QSCALE;
        q[((3*4 + h)*64 + b)*128 + j] = a2d*QSCALE;
    }
}

/* ---- rowH(+b1)/colH ---- */
__global__ void krowcol(const int* __restrict__ solution, const float* __restrict__ w1,
                        const float* __restrict__ b1, const float* __restrict__ qg,
                        const float* __restrict__ hhat, float* __restrict__ rowH,
                        float* __restrict__ colH) {
    int b = blockIdx.x, ch = blockIdx.y, t = threadIdx.x;  /* block 64 */
    int n = ch*51 + t;
    int ne = ch*51 + 51; if (ne > N1) ne = N1;
    if (n >= ne || t >= 51) return;
    int sn = solution[b*N1 + n];
    const float* ra = hhat + ((size_t)b*N1 + n)*DD;
    const float* rb = hhat + ((size_t)b*N1 + sn)*DD;
    float cv[16];
    #pragma unroll
    for (int j = 0; j < 16; ++j) cv[j] = 0.f;
    for (int ec = 0; ec < 4; ++ec) {
        float xa[32], xb[32];
        #pragma unroll
        for (int q4 = 0; q4 < 8; ++q4) {
            float4 va = ((const float4*)(ra + ec*32))[q4];
            float4 vb = ((const float4*)(rb + ec*32))[q4];
            xa[q4*4+0]=va.x; xa[q4*4+1]=va.y; xa[q4*4+2]=va.z; xa[q4*4+3]=va.w;
            xb[q4*4+0]=vb.x; xb[q4*4+1]=vb.y; xb[q4*4+2]=vb.z; xb[q4*4+3]=vb.w;
        }
        #pragma unroll
        for (int j = 0; j < 16; ++j) {
            const float* qp = qg + ((size_t)j*64 + b)*128 + ec*32;
            int kind = j >> 2;
            float a = 0.f;
            if (kind & 1) {
                #pragma unroll
                for (int e = 0; e < 32; ++e) a += qp[e]*xb[e];
            } else {
                #pragma unroll
                for (int e = 0; e < 32; ++e) a += qp[e]*xa[e];
            }
            cv[j] += a;
        }
    }
    float* rO = rowH + ((size_t)b*N1 + n)*32;
    float* cO = colH + ((size_t)b*N1 + n)*32;
    #pragma unroll
    for (int k = 0; k < 32; ++k) {
        float rh = b1[k], chh = 0.f;
        #pragma unroll
        for (int j = 0; j < 8; ++j)  rh  += cv[j]*w1[j*32 + k];
        #pragma unroll
        for (int j = 8; j < 16; ++j) chh += cv[j]*w1[j*32 + k];
        rO[k] = rh; cO[k] = chh;
    }
}

/* ---- t2 via bf16 hi/lo MFMA + v_cvt_pk; 64 cols x 13 rows per block ---- */
__global__ __launch_bounds__(64) void kt2(
        const unsigned char* __restrict__ maskt,
        const float* __restrict__ rowH, const float* __restrict__ colH,
        const unsigned short* __restrict__ w2f,
        const float* __restrict__ b2g, const float* __restrict__ w3g,
        const float* __restrict__ b3g,
        float* __restrict__ pm, float* __restrict__ ps, int* __restrict__ pi) {
    int b = blockIdx.x, cy = blockIdx.y, rz = blockIdx.z;
    int l = threadIdx.x;
    int c0 = cy*64;
    int r0 = rz*13, rend = r0 + 13; if (rend > N1) rend = N1;
    int rcnt = rend - r0;
    __shared__ float colc[64*36];
    __shared__ float rowr[13*36];

    const short8v* wf = (const short8v*)w2f;
    short8v w2hi0 = wf[0*64 + l];
    short8v w2lo0 = wf[1*64 + l];
    short8v w2hi1 = wf[2*64 + l];
    short8v w2lo1 = wf[3*64 + l];
    int sg = l >> 4;
    float4v b2f0 = *(const float4v*)(b2g + sg*4);
    float4v b2f1 = *(const float4v*)(b2g + 16 + sg*4);
    float4v w3f0 = *(const float4v*)(w3g + sg*4);
    float4v w3f1 = *(const float4v*)(w3g + 16 + sg*4);
    float b3v = b3g[0];

    {
        int cg = c0 + l;
        float4v* dst = (float4v*)(colc + l*36);
        if (cg < N1) {
            const float4v* src = (const float4v*)(colH + ((size_t)b*N1 + cg)*32);
            #pragma unroll
            for (int q = 0; q < 8; ++q) dst[q] = src[q];
        } else {
            float4v z = {0.f, 0.f, 0.f, 0.f};
            #pragma unroll
            for (int q = 0; q < 8; ++q) dst[q] = z;
        }
    }
    for (int idx = l; idx < rcnt*32; idx += 64) {
        int rr = idx >> 5, k = idx & 31;
        rowr[rr*36 + k] = rowH[((size_t)b*N1 + r0 + rr)*32 + k];
    }
    __syncthreads();

    float m = -INFINITY, s = 0.f;
    int mi = 0x7fffffff;
    int c = c0 + l;
    bool valid = c < N1;
    const unsigned char* mrow = maskt + (size_t)b*NN + c0 + l;

    union U8 { unsigned u[4]; short8v s8; };

    for (int rr = 0; rr < rcnt; ++rr) {
        int r = r0 + rr;
        const float4v* rp = (const float4v*)(rowr + rr*36 + sg*8);
        float4v ra = rp[0], rb = rp[1];
        float outv = 0.f;
        #pragma unroll
        for (int g = 0; g < 4; ++g) {
            const float4v* cp = (const float4v*)(colc + (16*g + (l & 15))*36 + sg*8);
            float4v ca = cp[0], cb = cp[1];
            float h[8];
            #pragma unroll
            for (int e = 0; e < 4; ++e) {
                h[e]   = fmaxf(ra[e] + ca[e], 0.f);
                h[4+e] = fmaxf(rb[e] + cb[e], 0.f);
            }
            U8 B, L;
            #pragma unroll
            for (int e = 0; e < 4; ++e) {
                unsigned ph, pl;
                asm("v_cvt_pk_bf16_f32 %0, %1, %2" : "=v"(ph) : "v"(h[2*e]), "v"(h[2*e+1]));
                float h0 = __uint_as_float(ph << 16);
                float h1f = __uint_as_float(ph & 0xffff0000u);
                float l0 = h[2*e] - h0, l1 = h[2*e+1] - h1f;
                asm("v_cvt_pk_bf16_f32 %0, %1, %2" : "=v"(pl) : "v"(l0), "v"(l1));
                B.u[e] = ph; L.u[e] = pl;
            }
            short8v bh = B.s8, bl = L.s8;
            float4v a0 = b2f0, a1 = b2f1;
            a0 = __builtin_amdgcn_mfma_f32_16x16x32_bf16(w2hi0, bh, a0, 0, 0, 0);
            a0 = __builtin_amdgcn_mfma_f32_16x16x32_bf16(w2hi0, bl, a0, 0, 0, 0);
            a0 = __builtin_amdgcn_mfma_f32_16x16x32_bf16(w2lo0, bh, a0, 0, 0, 0);
            a0 = __builtin_amdgcn_mfma_f32_16x16x32_bf16(w2lo0, bl, a0, 0, 0, 0);
            a1 = __builtin_amdgcn_mfma_f32_16x16x32_bf16(w2hi1, bh, a1, 0, 0, 0);
            a1 = __builtin_amdgcn_mfma_f32_16x16x32_bf16(w2hi1, bl, a1, 0, 0, 0);
            a1 = __builtin_amdgcn_mfma_f32_16x16x32_bf16(w2lo1, bh, a1, 0, 0, 0);
            a1 = __builtin_amdgcn_mfma_f32_16x16x32_bf16(w2lo1, bl, a1, 0, 0, 0);
            float p = 0.f;
            #pragma unroll
            for (int reg = 0; reg < 4; ++reg) {
                p += fmaxf(a0[reg], 0.f)*w3f0[reg];
                p += fmaxf(a1[reg], 0.f)*w3f1[reg];
            }
            p += __shfl_xor(p, 16);
            p += __shfl_xor(p, 32);
            if (sg == g) outv = p + b3v;
        }
        float ex = __expf(2.f*outv);
        float tv = 6.f - 12.f/(ex + 1.f);
        if (mrow[(size_t)r*N1]) tv = NEGV;
        if (valid) {
            if (tv > m) { s = s*__expf(m - tv) + 1.f; m = tv; mi = r*N1 + c; }
            else        { s += __expf(tv - m); }
        }
    }
    #pragma unroll
    for (int off = 1; off < 64; off <<= 1) {
        float om = __shfl_xor(m, off);
        float os = __shfl_xor(s, off);
        int oi = __shfl_xor(mi, off);
        float M2 = fmaxf(m, om);
        float sn = (s > 0.f ? s*__expf(m - M2) : 0.f)
                 + (os > 0.f ? os*__expf(om - M2) : 0.f);
        int in_;
        if (m > om) in_ = mi; else if (om > m) in_ = oi; else in_ = (mi < oi ? mi : oi);
        m = M2; s = sn; mi = in_;
    }
    if (l == 0) {
        int slot = b*64 + cy*16 + rz;
        pm[slot] = m; ps[slot] = s; pi[slot] = mi;
    }
}

/* ---- final reduce + outputs ---- */
__global__ void kfinal(float* __restrict__ out, const float* __restrict__ pm,
                       const float* __restrict__ ps, const int* __restrict__ pi,
                       const float* __restrict__ sc) {
    int b = blockIdx.x, lane = threadIdx.x;  /* 64 */
    float m = pm[b*64 + lane];
    float s = ps[b*64 + lane];
    int mi = pi[b*64 + lane];
    #pragma unroll
    for (int off = 1; off < 64; off <<= 1) {
        float om = __shfl_xor(m, off);
        float os = __shfl_xor(s, off);
        int oi = __shfl_xor(mi, off);
        float M2 = fmaxf(m, om);
        float sn = (s > 0.f ? s*__expf(m - M2) : 0.f)
                 + (os > 0.f ? os*__expf(om - M2) : 0.f);
        int in_;
        if (m > om) in_ = mi; else if (om > m) in_ = oi; else in_ = (mi < oi ? mi : oi);
        m = M2; s = sn; mi = in_;
    }
    if (lane == 0) {
        float ll2 = -__logf(s);
        const int* ia = (const int*)sc;
        out[b*3 + 0] = (float)ia[b];
        out[b*3 + 1] = (float)(mi / N1);
        out[b*3 + 2] = (float)(mi % N1);
        out[192 + b] = sc[192 + b] + ll2;
    }
}

extern "C" void kernel_launch(void* const* d_in, const int* in_sizes, int n_in,
                              void* d_out, int out_size, void* d_ws, size_t ws_size,
                              hipStream_t stream) {
    const float* h_wave    = (const float*)d_in[0];
    const int*   solution  = (const int*)d_in[1];
    const float* sel       = (const float*)d_in[2];
    const int*   pre_act   = (const int*)d_in[3];
    const unsigned char* maskt = (const unsigned char*)d_in[4];
    const float* Wn    = (const float*)d_in[5];
    const float* Wg    = (const float*)d_in[6];
    const float* rmWQ  = (const float*)d_in[7];
    const float* rmWK  = (const float*)d_in[8];
    const float* rm_w1 = (const float*)d_in[9];
    const float* rm_b1 = (const float*)d_in[10];
    const float* rm_w2 = (const float*)d_in[11];
    const float* rm_b2 = (const float*)d_in[12];
    const float* rm_w3 = (const float*)d_in[13];
    const float* rm_b3 = (const float*)d_in[14];
    const float* i1Wq  = (const float*)d_in[15];
    const float* i1Wk  = (const float*)d_in[16];
    const float* i2Wq  = (const float*)d_in[17];
    const float* i2Wk  = (const float*)d_in[18];
    const float* re_w1 = (const float*)d_in[19];
    const float* re_b1 = (const float*)d_in[20];
    const float* re_w2 = (const float*)d_in[21];
    const float* re_b2 = (const float*)d_in[22];
    const float* re_w3 = (const float*)d_in[23];
    const float* re_b3 = (const float*)d_in[24];
    float* ws = (float*)d_ws;
    float* out = (float*)d_out;

    kprep2<<<dim3(12, 4, 4), dim3(128), 0, stream>>>(rmWQ, rmWK, i1Wq, i1Wk, i2Wq, i2Wk, ws);
    kfrag<<<dim3(417), dim3(64), 0, stream>>>(Wn, re_w2, ws);
    khw3<<<dim3(6432), dim3(256), 0, stream>>>(h_wave, ws);
    khmaxg2<<<dim3(64), dim3(128), 0, stream>>>(h_wave, Wg, ws + OFF_G);
    khhat2<<<dim3(64, 4), dim3(256), 0, stream>>>(ws + OFF_G, ws);
    kAC<<<dim3(64, 4), dim3(256), 0, stream>>>(solution, ws);
    krmq<<<dim3(64), dim3(128), 0, stream>>>(sel, pre_act, rm_w1, rm_b1, rm_w2, rm_b2,
                                             rm_w3, rm_b3, ws + OFF_M, ws + OFF_HHAT,
                                             ws + OFF_CMP, ws + OFF_SC, ws + OFF_Q);
    krowcol<<<dim3(64, 4), dim3(64), 0, stream>>>(solution, re_w1, re_b1,
                                                  ws + OFF_Q, ws + OFF_HHAT,
                                                  ws + OFF_ROWH, ws + OFF_COLH);
    kt2<<<dim3(64, 4, 16), dim3(64), 0, stream>>>(maskt, ws + OFF_ROWH, ws + OFF_COLH,
                                                  (const unsigned short*)(ws + OFF_W2F),
                                                  re_b2, re_w3, re_b3,
                                                  ws + OFF_PM, ws + OFF_PS,
                                                  (int*)(ws + OFF_PI));
    kfinal<<<dim3(64), dim3(64), 0, stream>>>(out, ws + OFF_PM, ws + OFF_PS,
                                              (const int*)(ws + OFF_PI), ws + OFF_SC);
}

// Round 8
// 318.334 us; speedup vs baseline: 2.0197x; 1.1138x over previous
//
#include <hip/hip_runtime.h>
#include <math.h>

#define BB 64
#define N1 201
#define DD 128
#define HALF 100
#define NN (N1*N1)
#define NEGV (-1e20f)
#define QSCALE 0.08838834764831845f  /* 1/sqrt(128) */
#define NELE 1646592u                /* 64*201*128 */

typedef __attribute__((ext_vector_type(8))) short short8v;
typedef __attribute__((ext_vector_type(4))) float float4v;

/* ws offsets in floats */
#define OFF_M    0u          /* 12*16384 f32 M matrices */
#define OFF_MF   196608u     /* 13 mats * 24576 (3-split bf16 frags) */
#define OFF_HWB  516096u     /* h_wave 3-split: 3*823296 */
#define OFF_HHAT 2985984u    /* f32 1646592 */
#define OFF_HBF  4632576u    /* hhat 3-split */
#define OFF_G    7102464u    /* 64*128 */
#define OFF_CMP  7110656u    /* 4*64*200 */
#define OFF_ROWH 7292928u    /* 64*201*32 */
#define OFF_COLH 7704576u    /* 64*201*32 */
#define OFF_SC   8116224u    /* 256 */
#define OFF_PM   8116480u    /* 64*64 */
#define OFF_PS   8120576u
#define OFF_PI   8124672u
#define OFF_W2F  8128768u    /* kt2 w2 frags (2-split), 1024 floats */
#define OFF_QS   8130816u    /* q 3-split: 3*131072 ushort = 196608 floats */

__device__ __forceinline__ unsigned short f2bf(float x) {
    unsigned u = __float_as_uint(x);
    unsigned r = u + 0x7fffu + ((u >> 16) & 1u);
    return (unsigned short)(r >> 16);
}
__device__ __forceinline__ float bf2f(unsigned short h) {
    return __uint_as_float(((unsigned)h) << 16);
}

/* ---- M_h = WQ_h @ WK_h^T : grid (12,4ig,4jg) ---- */
__global__ void kprep2(const float* __restrict__ rmWQ, const float* __restrict__ rmWK,
                       const float* __restrict__ i1Wq, const float* __restrict__ i1Wk,
                       const float* __restrict__ i2Wq, const float* __restrict__ i2Wk,
                       float* __restrict__ ws) {
    int m = blockIdx.x, ig = blockIdx.y, jg = blockIdx.z, t = threadIdx.x;  /* 128 */
    const float* WQ; const float* WK;
    if (m < 4)      { WQ = rmWQ + m*16384;     WK = rmWK + m*16384; }
    else if (m < 8) { WQ = i1Wq + (m-4)*16384; WK = i1Wk + (m-4)*16384; }
    else            { WQ = i2Wq + (m-8)*16384; WK = i2Wk + (m-8)*16384; }
    __shared__ float wq[32*132];
    __shared__ float wk[32*133];
    for (int idx = t; idx < 32*128; idx += 128) {
        int r = idx >> 7, e = idx & 127;
        wq[r*132 + e] = WQ[(ig*32 + r)*128 + e];
        wk[r*133 + e] = WK[(jg*32 + r)*128 + e];
    }
    __syncthreads();
    int j = t & 31, iq = t >> 5;
    #pragma unroll
    for (int i2 = 0; i2 < 8; ++i2) {
        int i = iq*8 + i2;
        float acc = 0.f;
        #pragma unroll 8
        for (int e = 0; e < 128; ++e) acc += wq[i*132 + e]*wk[j*133 + e];
        ws[OFF_M + m*16384 + (ig*32 + i)*128 + jg*32 + j] = acc;
    }
}

/* ---- 3-split bf16 MFMA B-fragments for 12 M's + Wn; block 416 = kt2 w2 frags ---- */
__global__ void kfrag(const float* __restrict__ Wn, const float* __restrict__ re_w2,
                      float* __restrict__ ws) {
    int bid = blockIdx.x;  /* 417 */
    int l = threadIdx.x;   /* 64 */
    if (bid == 416) {
        unsigned short* w2f = (unsigned short*)(ws + OFF_W2F);
        for (int idx = l; idx < 2048; idx += 64) {
            int fs = idx >> 9, ll = (idx >> 3) & 63, i = idx & 7;
            int j = 16*(fs >> 1) + (ll & 15);
            int k = ((ll >> 4)*8) + i;
            float v = re_w2[k*32 + j];
            unsigned short hi = f2bf(v);
            w2f[idx] = (fs & 1) ? f2bf(v - bf2f(hi)) : hi;
        }
        return;
    }
    int mat = bid >> 5, rem = bid & 31, nt = rem >> 2, ks = rem & 3;
    const float* src = (mat < 12) ? (ws + OFF_M + mat*16384) : Wn;
    unsigned short* mf = (unsigned short*)(ws + OFF_MF)
                       + (size_t)mat*49152 + (size_t)((nt*4 + ks)*3)*512 + l*8;
    #pragma unroll
    for (int i = 0; i < 8; ++i) {
        int k = ks*32 + (l >> 4)*8 + i;
        int col = nt*16 + (l & 15);
        float v = src[k*128 + col];
        unsigned short h = f2bf(v);
        float r1 = v - bf2f(h);
        unsigned short mm = f2bf(r1);
        unsigned short lo = f2bf(r1 - bf2f(mm));
        mf[i] = h; mf[512 + i] = mm; mf[1024 + i] = lo;
    }
}

/* ---- 3-split h_wave ---- */
__global__ void khw3(const float* __restrict__ hw, float* __restrict__ ws) {
    unsigned idx = blockIdx.x*256u + threadIdx.x;
    if (idx >= NELE) return;
    unsigned short* hh = (unsigned short*)(ws + OFF_HWB);
    unsigned short* hm = hh + NELE;
    unsigned short* hl = hh + 2u*NELE;
    float v = hw[idx];
    unsigned short a = f2bf(v);
    float r1 = v - bf2f(a);
    unsigned short b = f2bf(r1);
    unsigned short c = f2bf(r1 - bf2f(b));
    hh[idx] = a; hm[idx] = b; hl[idx] = c;
}

/* ---- hmax over N1 + g = hmax @ Wg (fused) ---- */
__global__ void khmaxg2(const float* __restrict__ hw, const float* __restrict__ Wg,
                        float* __restrict__ g) {
    int b = blockIdx.x, d = threadIdx.x;
    __shared__ float hm[128];
    float m = -INFINITY;
    const float* src = hw + (size_t)b*N1*DD + d;
    for (int n = 0; n < N1; ++n) m = fmaxf(m, src[n*DD]);
    hm[d] = m;
    __syncthreads();
    float acc = 0.f;
    for (int k = 0; k < 128; ++k) acc += hm[k] * Wg[k*128 + d];
    g[b*128 + d] = acc;
}

/* ---- h_hat = h_wave @ Wn + g via MFMA (3-split, 6 products) ---- */
__global__ __launch_bounds__(256) void khhat2(const float* __restrict__ g,
                                              float* __restrict__ ws) {
    int b = blockIdx.x, cg = blockIdx.y;
    int t = threadIdx.x, w = t >> 6, l = t & 63;
    const unsigned short* hwh = (const unsigned short*)(ws + OFF_HWB);
    const unsigned short* hwm = hwh + NELE;
    const unsigned short* hwl = hwh + 2u*NELE;
    const unsigned short* wnf = (const unsigned short*)(ws + OFF_MF) + (size_t)12*49152;
    float* hhat = ws + OFF_HHAT;
    unsigned short* hbh = (unsigned short*)(ws + OFF_HBF);
    unsigned short* hbm = hbh + NELE;
    unsigned short* hbl = hbh + 2u*NELE;
    int col0 = cg*32 + (l & 15);
    float g0 = g[b*128 + col0];
    float g1 = g[b*128 + col0 + 16];
    for (int mt = w; mt < 13; mt += 4) {
        int arow = mt*16 + (l & 15); if (arow > 200) arow = 200;
        size_t abase = ((size_t)b*N1 + arow)*DD;
        float4v acc0 = {g0, g0, g0, g0};
        float4v acc1 = {g1, g1, g1, g1};
        #pragma unroll
        for (int ks = 0; ks < 4; ++ks) {
            size_t ao = abase + ks*32 + (l >> 4)*8;
            short8v ah = *(const short8v*)(hwh + ao);
            short8v am = *(const short8v*)(hwm + ao);
            short8v al = *(const short8v*)(hwl + ao);
            const short8v* bf0 = (const short8v*)(wnf + (size_t)(((cg*2 + 0)*4 + ks)*3)*512) + l;
            const short8v* bf1 = (const short8v*)(wnf + (size_t)(((cg*2 + 1)*4 + ks)*3)*512) + l;
            short8v bh0 = bf0[0], bm0 = bf0[64], bl0 = bf0[128];
            short8v bh1 = bf1[0], bm1 = bf1[64], bl1 = bf1[128];
            acc0 = __builtin_amdgcn_mfma_f32_16x16x32_bf16(ah, bh0, acc0, 0, 0, 0);
            acc1 = __builtin_amdgcn_mfma_f32_16x16x32_bf16(ah, bh1, acc1, 0, 0, 0);
            acc0 = __builtin_amdgcn_mfma_f32_16x16x32_bf16(ah, bm0, acc0, 0, 0, 0);
            acc1 = __builtin_amdgcn_mfma_f32_16x16x32_bf16(ah, bm1, acc1, 0, 0, 0);
            acc0 = __builtin_amdgcn_mfma_f32_16x16x32_bf16(am, bh0, acc0, 0, 0, 0);
            acc1 = __builtin_amdgcn_mfma_f32_16x16x32_bf16(am, bh1, acc1, 0, 0, 0);
            acc0 = __builtin_amdgcn_mfma_f32_16x16x32_bf16(ah, bl0, acc0, 0, 0, 0);
            acc1 = __builtin_amdgcn_mfma_f32_16x16x32_bf16(ah, bl1, acc1, 0, 0, 0);
            acc0 = __builtin_amdgcn_mfma_f32_16x16x32_bf16(al, bh0, acc0, 0, 0, 0);
            acc1 = __builtin_amdgcn_mfma_f32_16x16x32_bf16(al, bh1, acc1, 0, 0, 0);
            acc0 = __builtin_amdgcn_mfma_f32_16x16x32_bf16(am, bm0, acc0, 0, 0, 0);
            acc1 = __builtin_amdgcn_mfma_f32_16x16x32_bf16(am, bm1, acc1, 0, 0, 0);
        }
        #pragma unroll
        for (int r = 0; r < 4; ++r) {
            int row = mt*16 + (l >> 4)*4 + r;
            if (row < N1) {
                size_t i0 = ((size_t)b*N1 + row)*DD + col0;
                float v0 = acc0[r], v1 = acc1[r];
                hhat[i0] = v0; hhat[i0 + 16] = v1;
                unsigned short a0 = f2bf(v0); float r10 = v0 - bf2f(a0);
                unsigned short b0 = f2bf(r10);
                hbh[i0] = a0; hbm[i0] = b0; hbl[i0] = f2bf(r10 - bf2f(b0));
                unsigned short a1 = f2bf(v1); float r11 = v1 - bf2f(a1);
                unsigned short b1 = f2bf(r11);
                hbh[i0+16] = a1; hbm[i0+16] = b1; hbl[i0+16] = f2bf(r11 - bf2f(b1));
            }
        }
    }
}

/* ---- fused: A = hhat @ M[h] (MFMA -> LDS) then comp dots ---- */
__global__ __launch_bounds__(256) void kAC(const int* __restrict__ solution,
                                           float* __restrict__ ws) {
    int b = blockIdx.x, h = blockIdx.y;
    int t = threadIdx.x, w = t >> 6, l = t & 63;
    __shared__ float As[N1*132];
    __shared__ int sol[N1], pre[N1], post[N1];
    if (t < N1) sol[t] = solution[b*N1 + t];
    __syncthreads();
    if (t < N1) { pre[sol[t]] = t; post[t] = sol[sol[t]]; }
    const unsigned short* hbh = (const unsigned short*)(ws + OFF_HBF);
    const unsigned short* hbm = hbh + NELE;
    const unsigned short* hbl = hbh + 2u*NELE;
    const unsigned short* mfm = (const unsigned short*)(ws + OFF_MF) + (size_t)h*49152;
    for (int mt = 0; mt < 13; ++mt) {
        int arow = mt*16 + (l & 15); if (arow > 200) arow = 200;
        size_t abase = ((size_t)b*N1 + arow)*DD;
        float4v acc0 = {0.f, 0.f, 0.f, 0.f};
        float4v acc1 = {0.f, 0.f, 0.f, 0.f};
        #pragma unroll
        for (int ks = 0; ks < 4; ++ks) {
            size_t ao = abase + ks*32 + (l >> 4)*8;
            short8v ah = *(const short8v*)(hbh + ao);
            short8v am = *(const short8v*)(hbm + ao);
            short8v al = *(const short8v*)(hbl + ao);
            const short8v* bf0 = (const short8v*)(mfm + (size_t)(((2*w + 0)*4 + ks)*3)*512) + l;
            const short8v* bf1 = (const short8v*)(mfm + (size_t)(((2*w + 1)*4 + ks)*3)*512) + l;
            short8v bh0 = bf0[0], bm0 = bf0[64], bl0 = bf0[128];
            short8v bh1 = bf1[0], bm1 = bf1[64], bl1 = bf1[128];
            acc0 = __builtin_amdgcn_mfma_f32_16x16x32_bf16(ah, bh0, acc0, 0, 0, 0);
            acc1 = __builtin_amdgcn_mfma_f32_16x16x32_bf16(ah, bh1, acc1, 0, 0, 0);
            acc0 = __builtin_amdgcn_mfma_f32_16x16x32_bf16(ah, bm0, acc0, 0, 0, 0);
            acc1 = __builtin_amdgcn_mfma_f32_16x16x32_bf16(ah, bm1, acc1, 0, 0, 0);
            acc0 = __builtin_amdgcn_mfma_f32_16x16x32_bf16(am, bh0, acc0, 0, 0, 0);
            acc1 = __builtin_amdgcn_mfma_f32_16x16x32_bf16(am, bh1, acc1, 0, 0, 0);
            acc0 = __builtin_amdgcn_mfma_f32_16x16x32_bf16(ah, bl0, acc0, 0, 0, 0);
            acc1 = __builtin_amdgcn_mfma_f32_16x16x32_bf16(ah, bl1, acc1, 0, 0, 0);
            acc0 = __builtin_amdgcn_mfma_f32_16x16x32_bf16(al, bh0, acc0, 0, 0, 0);
            acc1 = __builtin_amdgcn_mfma_f32_16x16x32_bf16(al, bh1, acc1, 0, 0, 0);
            acc0 = __builtin_amdgcn_mfma_f32_16x16x32_bf16(am, bm0, acc0, 0, 0, 0);
            acc1 = __builtin_amdgcn_mfma_f32_16x16x32_bf16(am, bm1, acc1, 0, 0, 0);
        }
        #pragma unroll
        for (int r = 0; r < 4; ++r) {
            int row = mt*16 + (l >> 4)*4 + r;
            if (row < N1) {
                int col = 2*w*16 + (l & 15);
                As[row*132 + col] = acc0[r];
                As[row*132 + col + 16] = acc1[r];
            }
        }
    }
    __syncthreads();
    const float2* X = (const float2*)(ws + OFF_HHAT) + (size_t)b*N1*64;
    float* cmp = ws + OFF_CMP + (h*64 + b)*200;
    for (int n = 1 + w; n <= 200; n += 4) {
        int pn = pre[n], po = post[n];
        float2 xn = X[n*64 + l], xp = X[po*64 + l];
        float2 ap = *(const float2*)&As[pn*132 + 2*l];
        float2 an = *(const float2*)&As[n*132 + 2*l];
        float v = ap.x*(xn.x - xp.x) + ap.y*(xn.y - xp.y) + an.x*xp.x + an.y*xp.y;
        #pragma unroll
        for (int off = 32; off; off >>= 1) v += __shfl_xor(v, off);
        if (l == 0) cmp[n - 1] = v;
    }
}

/* ---- removal MLP + softmax/argmax + q vectors (3-split out) ---- */
__global__ void krmq(const float* __restrict__ sel, const int* __restrict__ pre_action,
                     const float* __restrict__ w1, const float* __restrict__ b1,
                     const float* __restrict__ w2, const float* __restrict__ b2,
                     const float* __restrict__ w3, const float* __restrict__ b3,
                     const float* __restrict__ Mall, const float* __restrict__ hhat,
                     const float* __restrict__ cmpg, float* __restrict__ sc,
                     unsigned short* __restrict__ qs) {
    int b = blockIdx.x, t = threadIdx.x;  /* 128 */
    __shared__ float t1l[100];
    __shared__ int ppd[2];
    __shared__ float xp[128], xd[128];
    if (t < 100) {
        float f[12];
        #pragma unroll
        for (int h = 0; h < 4; ++h) {
            f[h]     = cmpg[(h*64 + b)*200 + t];
            f[4 + h] = cmpg[(h*64 + b)*200 + 100 + t];
        }
        #pragma unroll
        for (int s = 0; s < 4; ++s) f[8 + s] = sel[b*400 + s*100 + t];
        float h1[32];
        #pragma unroll
        for (int k = 0; k < 32; ++k) h1[k] = b1[k];
        #pragma unroll
        for (int j = 0; j < 12; ++j) {
            const float* wr = w1 + j*32;
            #pragma unroll
            for (int k = 0; k < 32; ++k) h1[k] += f[j]*wr[k];
        }
        #pragma unroll
        for (int k = 0; k < 32; ++k) h1[k] = fmaxf(h1[k], 0.f);
        float acc[32];
        #pragma unroll
        for (int j = 0; j < 32; ++j) acc[j] = b2[j];
        #pragma unroll
        for (int k = 0; k < 32; ++k) {
            const float* wr = w2 + k*32;
            #pragma unroll
            for (int j = 0; j < 32; ++j) acc[j] += h1[k]*wr[j];
        }
        float out = b3[0];
        #pragma unroll
        for (int j = 0; j < 32; ++j) out += fmaxf(acc[j], 0.f)*w3[j];
        t1l[t] = tanhf(out)*6.0f;
    }
    __syncthreads();
    if (t == 0) {
        if (pre_action[0] > 0) t1l[pre_action[b*2]] = NEGV;
        float M = -INFINITY; int a1 = 0;
        for (int i = 0; i < 100; ++i) if (t1l[i] > M) { M = t1l[i]; a1 = i; }
        float S = 0.f;
        for (int i = 0; i < 100; ++i) S += __expf(t1l[i] - M);
        int* ia = (int*)sc;
        ia[b] = a1;
        sc[192 + b] = -__logf(S);
        ppd[0] = 1 + a1; ppd[1] = 101 + a1;
    }
    __syncthreads();
    int pp = ppd[0], pd = ppd[1];
    const float* hb = hhat + (size_t)b*N1*DD;
    xp[t] = hb[pp*DD + t];
    xd[t] = hb[pd*DD + t];
    __syncthreads();
    int j = t;
    unsigned short* qsh = qs;
    unsigned short* qsm = qs + 131072;
    unsigned short* qsl = qs + 262144;
    #pragma unroll
    for (int h = 0; h < 4; ++h) {
        const float* M1 = Mall + (4 + h)*16384;
        const float* M2 = Mall + (8 + h)*16384;
        float a1p = 0, a2p = 0, a1d = 0, a2d = 0;
        for (int i = 0; i < 128; ++i) {
            float w1v = M1[i*128 + j], w2v = M2[i*128 + j];
            a1p += xp[i]*w1v; a1d += xd[i]*w1v;
            a2p += xp[i]*w2v; a2d += xd[i]*w2v;
        }
        float vals[4] = {a1p*QSCALE, a2p*QSCALE, a1d*QSCALE, a2d*QSCALE};
        #pragma unroll
        for (int ty = 0; ty < 4; ++ty) {
            size_t o = ((size_t)(ty*4 + h)*64 + b)*128 + j;
            float v = vals[ty];
            unsigned short hi = f2bf(v); float r1 = v - bf2f(hi);
            unsigned short md = f2bf(r1);
            qsh[o] = hi; qsm[o] = md; qsl[o] = f2bf(r1 - bf2f(md));
        }
    }
}

/* ---- rowH(+b1)/colH via MFMA: carr = hhat(gather) @ q^T, then @ w1 ---- */
__global__ __launch_bounds__(256) void krowcol2(const int* __restrict__ sol_g,
                                                const float* __restrict__ w1,
                                                const float* __restrict__ b1,
                                                float* __restrict__ ws) {
    int b = blockIdx.x, zb = blockIdx.y;  /* zb 0..1 */
    int t = threadIdx.x, w = t >> 6, l = t & 63;
    __shared__ int sol[N1];
    __shared__ float carr[N1*17];
    __shared__ float w1s[512];
    __shared__ float b1s[32];
    if (t < N1) sol[t] = sol_g[b*N1 + t];
    for (int i = t; i < 512; i += 256) w1s[i] = w1[i];
    if (t < 32) b1s[t] = b1[t];
    __syncthreads();
    const unsigned short* qsh = (const unsigned short*)(ws + OFF_QS);
    const unsigned short* qsm = qsh + 131072;
    const unsigned short* qsl = qsh + 262144;
    const unsigned short* hbh = (const unsigned short*)(ws + OFF_HBF);
    const unsigned short* hbm = hbh + NELE;
    const unsigned short* hbl = hbh + 2u*NELE;
    int j = l & 15;
    short8v Bh[4], Bm[4], Bl[4];
    #pragma unroll
    for (int ks = 0; ks < 4; ++ks) {
        size_t qo = ((size_t)j*64 + b)*128 + ks*32 + (l >> 4)*8;
        Bh[ks] = *(const short8v*)(qsh + qo);
        Bm[ks] = *(const short8v*)(qsm + qo);
        Bl[ks] = *(const short8v*)(qsl + qo);
    }
    int mt0 = zb ? 7 : 0, mt1 = zb ? 13 : 7;
    for (int mt = mt0 + w; mt < mt1; mt += 4) {
        int rA = mt*16 + j; if (rA > 200) rA = 200;
        int rB = sol[rA];
        size_t o1 = ((size_t)b*N1 + rA)*DD;
        size_t o2 = ((size_t)b*N1 + rB)*DD;
        float4v acc1 = {0.f, 0.f, 0.f, 0.f};
        float4v acc2 = {0.f, 0.f, 0.f, 0.f};
        #pragma unroll
        for (int ks = 0; ks < 4; ++ks) {
            size_t k0 = ks*32 + (l >> 4)*8;
            short8v a1h = *(const short8v*)(hbh + o1 + k0);
            short8v a1m = *(const short8v*)(hbm + o1 + k0);
            short8v a1l = *(const short8v*)(hbl + o1 + k0);
            acc1 = __builtin_amdgcn_mfma_f32_16x16x32_bf16(a1h, Bh[ks], acc1, 0, 0, 0);
            acc1 = __builtin_amdgcn_mfma_f32_16x16x32_bf16(a1h, Bm[ks], acc1, 0, 0, 0);
            acc1 = __builtin_amdgcn_mfma_f32_16x16x32_bf16(a1m, Bh[ks], acc1, 0, 0, 0);
            acc1 = __builtin_amdgcn_mfma_f32_16x16x32_bf16(a1h, Bl[ks], acc1, 0, 0, 0);
            acc1 = __builtin_amdgcn_mfma_f32_16x16x32_bf16(a1l, Bh[ks], acc1, 0, 0, 0);
            acc1 = __builtin_amdgcn_mfma_f32_16x16x32_bf16(a1m, Bm[ks], acc1, 0, 0, 0);
            short8v a2h = *(const short8v*)(hbh + o2 + k0);
            short8v a2m = *(const short8v*)(hbm + o2 + k0);
            short8v a2l = *(const short8v*)(hbl + o2 + k0);
            acc2 = __builtin_amdgcn_mfma_f32_16x16x32_bf16(a2h, Bh[ks], acc2, 0, 0, 0);
            acc2 = __builtin_amdgcn_mfma_f32_16x16x32_bf16(a2h, Bm[ks], acc2, 0, 0, 0);
            acc2 = __builtin_amdgcn_mfma_f32_16x16x32_bf16(a2m, Bh[ks], acc2, 0, 0, 0);
            acc2 = __builtin_amdgcn_mfma_f32_16x16x32_bf16(a2h, Bl[ks], acc2, 0, 0, 0);
            acc2 = __builtin_amdgcn_mfma_f32_16x16x32_bf16(a2l, Bh[ks], acc2, 0, 0, 0);
            acc2 = __builtin_amdgcn_mfma_f32_16x16x32_bf16(a2m, Bm[ks], acc2, 0, 0, 0);
        }
        int kodd = (j >> 2) & 1;
        #pragma unroll
        for (int r = 0; r < 4; ++r) {
            int row = mt*16 + (l >> 4)*4 + r;
            if (row < N1) carr[row*17 + j] = kodd ? acc2[r] : acc1[r];
        }
    }
    __syncthreads();
    int rows0 = zb*112, nrows = zb ? 89 : 112;
    float* rowH = ws + OFF_ROWH;
    float* colH = ws + OFF_COLH;
    for (int idx = t; idx < nrows*32; idx += 256) {
        int n = rows0 + (idx >> 5), k = idx & 31;
        float rh = b1s[k], ch = 0.f;
        #pragma unroll
        for (int jj = 0; jj < 8; ++jj)  rh += carr[n*17 + jj]*w1s[jj*32 + k];
        #pragma unroll
        for (int jj = 8; jj < 16; ++jj) ch += carr[n*17 + jj]*w1s[jj*32 + k];
        rowH[((size_t)b*N1 + n)*32 + k] = rh;
        colH[((size_t)b*N1 + n)*32 + k] = ch;
    }
}

/* ---- t2: zero-LDS, col-regs, 4 waves/block, 52 rows x 64 cols ---- */
__global__ __launch_bounds__(256) void kt2(
        const unsigned char* __restrict__ maskt,
        const float* __restrict__ rowH, const float* __restrict__ colH,
        const unsigned short* __restrict__ w2f,
        const float* __restrict__ b2g, const float* __restrict__ w3g,
        const float* __restrict__ b3g,
        float* __restrict__ pm, float* __restrict__ ps, int* __restrict__ pi) {
    int b = blockIdx.x, cy = blockIdx.y, rz = blockIdx.z;
    int t = threadIdx.x, w = t >> 6, l = t & 63;
    int c0 = cy*64;
    int sg = l >> 4;
    const short8v* wf = (const short8v*)w2f;
    short8v w2hi0 = wf[0*64 + l];
    short8v w2lo0 = wf[1*64 + l];
    short8v w2hi1 = wf[2*64 + l];
    short8v w2lo1 = wf[3*64 + l];
    float4v b2f0 = *(const float4v*)(b2g + sg*4);
    float4v b2f1 = *(const float4v*)(b2g + 16 + sg*4);
    float4v w3f0 = *(const float4v*)(w3g + sg*4);
    float4v w3f1 = *(const float4v*)(w3g + 16 + sg*4);
    float b3v = b3g[0];
    /* row-invariant column slices -> registers */
    float4v ca[4], cb[4];
    #pragma unroll
    for (int g = 0; g < 4; ++g) {
        int cc = c0 + 16*g + (l & 15); if (cc > 200) cc = 200;
        const float4v* cp = (const float4v*)(colH + ((size_t)b*N1 + cc)*32 + sg*8);
        ca[g] = cp[0]; cb[g] = cp[1];
    }
    int r0 = rz*52 + w*13;
    int c = c0 + l;
    bool cvalid = c < N1;
    int cS = cvalid ? c : 200;
    float m = -INFINITY, s = 0.f;
    int mi = 0x7fffffff;
    const float* rbase = rowH + (size_t)b*N1*32 + sg*8;
    union U8 { unsigned u[4]; short8v s8; };
    int rl0 = r0 > 200 ? 200 : r0;
    float4v ra = ((const float4v*)(rbase + (size_t)rl0*32))[0];
    float4v rb = ((const float4v*)(rbase + (size_t)rl0*32))[1];
    for (int rr = 0; rr < 13; ++rr) {
        int r = r0 + rr;
        int rn = r + 1; if (rn > 200) rn = 200;
        const float4v* rpn = (const float4v*)(rbase + (size_t)rn*32);
        float4v ra_n = rpn[0], rb_n = rpn[1];
        int rS = r > 200 ? 200 : r;
        unsigned char mv = maskt[(size_t)b*NN + (size_t)rS*N1 + cS];
        float outv = 0.f;
        #pragma unroll
        for (int g = 0; g < 4; ++g) {
            float h[8];
            #pragma unroll
            for (int e = 0; e < 4; ++e) {
                h[e]   = fmaxf(ra[e] + ca[g][e], 0.f);
                h[4+e] = fmaxf(rb[e] + cb[g][e], 0.f);
            }
            U8 B, L;
            #pragma unroll
            for (int e = 0; e < 4; ++e) {
                unsigned ph, pl;
                asm("v_cvt_pk_bf16_f32 %0, %1, %2" : "=v"(ph) : "v"(h[2*e]), "v"(h[2*e+1]));
                float h0 = __uint_as_float(ph << 16);
                float h1f = __uint_as_float(ph & 0xffff0000u);
                float l0 = h[2*e] - h0, l1 = h[2*e+1] - h1f;
                asm("v_cvt_pk_bf16_f32 %0, %1, %2" : "=v"(pl) : "v"(l0), "v"(l1));
                B.u[e] = ph; L.u[e] = pl;
            }
            float4v a0 = b2f0, a1 = b2f1;
            a0 = __builtin_amdgcn_mfma_f32_16x16x32_bf16(w2hi0, B.s8, a0, 0, 0, 0);
            a1 = __builtin_amdgcn_mfma_f32_16x16x32_bf16(w2hi1, B.s8, a1, 0, 0, 0);
            a0 = __builtin_amdgcn_mfma_f32_16x16x32_bf16(w2hi0, L.s8, a0, 0, 0, 0);
            a1 = __builtin_amdgcn_mfma_f32_16x16x32_bf16(w2hi1, L.s8, a1, 0, 0, 0);
            a0 = __builtin_amdgcn_mfma_f32_16x16x32_bf16(w2lo0, B.s8, a0, 0, 0, 0);
            a1 = __builtin_amdgcn_mfma_f32_16x16x32_bf16(w2lo1, B.s8, a1, 0, 0, 0);
            float p = 0.f;
            #pragma unroll
            for (int reg = 0; reg < 4; ++reg) {
                p += fmaxf(a0[reg], 0.f)*w3f0[reg];
                p += fmaxf(a1[reg], 0.f)*w3f1[reg];
            }
            p += __shfl_xor(p, 16);
            p += __shfl_xor(p, 32);
            if (sg == g) outv = p + b3v;
        }
        ra = ra_n; rb = rb_n;
        float ex = __expf(2.f*outv);
        float tv = 6.f - 12.f/(ex + 1.f);
        if (mv) tv = NEGV;
        if ((r < N1) && cvalid) {
            if (tv > m) { s = s*__expf(m - tv) + 1.f; m = tv; mi = r*N1 + c; }
            else        { s += __expf(tv - m); }
        }
    }
    #pragma unroll
    for (int off = 1; off < 64; off <<= 1) {
        float om = __shfl_xor(m, off);
        float os = __shfl_xor(s, off);
        int oi = __shfl_xor(mi, off);
        float M2 = fmaxf(m, om);
        float sn = (s > 0.f ? s*__expf(m - M2) : 0.f)
                 + (os > 0.f ? os*__expf(om - M2) : 0.f);
        int in_;
        if (m > om) in_ = mi; else if (om > m) in_ = oi; else in_ = (mi < oi ? mi : oi);
        m = M2; s = sn; mi = in_;
    }
    if (l == 0) {
        int slot = b*64 + cy*16 + rz*4 + w;
        pm[slot] = m; ps[slot] = s; pi[slot] = mi;
    }
}

/* ---- final reduce + outputs ---- */
__global__ void kfinal(float* __restrict__ out, const float* __restrict__ pm,
                       const float* __restrict__ ps, const int* __restrict__ pi,
                       const float* __restrict__ sc) {
    int b = blockIdx.x, lane = threadIdx.x;  /* 64 */
    float m = pm[b*64 + lane];
    float s = ps[b*64 + lane];
    int mi = pi[b*64 + lane];
    #pragma unroll
    for (int off = 1; off < 64; off <<= 1) {
        float om = __shfl_xor(m, off);
        float os = __shfl_xor(s, off);
        int oi = __shfl_xor(mi, off);
        float M2 = fmaxf(m, om);
        float sn = (s > 0.f ? s*__expf(m - M2) : 0.f)
                 + (os > 0.f ? os*__expf(om - M2) : 0.f);
        int in_;
        if (m > om) in_ = mi; else if (om > m) in_ = oi; else in_ = (mi < oi ? mi : oi);
        m = M2; s = sn; mi = in_;
    }
    if (lane == 0) {
        float ll2 = -__logf(s);
        const int* ia = (const int*)sc;
        out[b*3 + 0] = (float)ia[b];
        out[b*3 + 1] = (float)(mi / N1);
        out[b*3 + 2] = (float)(mi % N1);
        out[192 + b] = sc[192 + b] + ll2;
    }
}

extern "C" void kernel_launch(void* const* d_in, const int* in_sizes, int n_in,
                              void* d_out, int out_size, void* d_ws, size_t ws_size,
                              hipStream_t stream) {
    const float* h_wave    = (const float*)d_in[0];
    const int*   solution  = (const int*)d_in[1];
    const float* sel       = (const float*)d_in[2];
    const int*   pre_act   = (const int*)d_in[3];
    const unsigned char* maskt = (const unsigned char*)d_in[4];
    const float* Wn    = (const float*)d_in[5];
    const float* Wg    = (const float*)d_in[6];
    const float* rmWQ  = (const float*)d_in[7];
    const float* rmWK  = (const float*)d_in[8];
    const float* rm_w1 = (const float*)d_in[9];
    const float* rm_b1 = (const float*)d_in[10];
    const float* rm_w2 = (const float*)d_in[11];
    const float* rm_b2 = (const float*)d_in[12];
    const float* rm_w3 = (const float*)d_in[13];
    const float* rm_b3 = (const float*)d_in[14];
    const float* i1Wq  = (const float*)d_in[15];
    const float* i1Wk  = (const float*)d_in[16];
    const float* i2Wq  = (const float*)d_in[17];
    const float* i2Wk  = (const float*)d_in[18];
    const float* re_w1 = (const float*)d_in[19];
    const float* re_b1 = (const float*)d_in[20];
    const float* re_w2 = (const float*)d_in[21];
    const float* re_b2 = (const float*)d_in[22];
    const float* re_w3 = (const float*)d_in[23];
    const float* re_b3 = (const float*)d_in[24];
    float* ws = (float*)d_ws;
    float* out = (float*)d_out;

    kprep2<<<dim3(12, 4, 4), dim3(128), 0, stream>>>(rmWQ, rmWK, i1Wq, i1Wk, i2Wq, i2Wk, ws);
    kfrag<<<dim3(417), dim3(64), 0, stream>>>(Wn, re_w2, ws);
    khw3<<<dim3(6432), dim3(256), 0, stream>>>(h_wave, ws);
    khmaxg2<<<dim3(64), dim3(128), 0, stream>>>(h_wave, Wg, ws + OFF_G);
    khhat2<<<dim3(64, 4), dim3(256), 0, stream>>>(ws + OFF_G, ws);
    kAC<<<dim3(64, 4), dim3(256), 0, stream>>>(solution, ws);
    krmq<<<dim3(64), dim3(128), 0, stream>>>(sel, pre_act, rm_w1, rm_b1, rm_w2, rm_b2,
                                             rm_w3, rm_b3, ws + OFF_M, ws + OFF_HHAT,
                                             ws + OFF_CMP, ws + OFF_SC,
                                             (unsigned short*)(ws + OFF_QS));
    krowcol2<<<dim3(64, 2), dim3(256), 0, stream>>>(solution, re_w1, re_b1, ws);
    kt2<<<dim3(64, 4, 4), dim3(256), 0, stream>>>(maskt, ws + OFF_ROWH, ws + OFF_COLH,
                                                  (const unsigned short*)(ws + OFF_W2F),
                                                  re_b2, re_w3, re_b3,
                                                  ws + OFF_PM, ws + OFF_PS,
                                                  (int*)(ws + OFF_PI));
    kfinal<<<dim3(64), dim3(64), 0, stream>>>(out, ws + OFF_PM, ws + OFF_PS,
                                              (const int*)(ws + OFF_PI), ws + OFF_SC);
}

// Round 9
// 316.505 us; speedup vs baseline: 2.0313x; 1.0058x over previous
//
#include <hip/hip_runtime.h>
#include <math.h>

#define BB 64
#define N1 201
#define DD 128
#define HALF 100
#define NN (N1*N1)
#define NEGV (-1e20f)
#define QSCALE 0.08838834764831845f  /* 1/sqrt(128) */
#define NELE 1646592u                /* 64*201*128 */

typedef __attribute__((ext_vector_type(8))) short short8v;
typedef __attribute__((ext_vector_type(4))) float float4v;

/* ws offsets in floats */
#define OFF_M    0u          /* 12*16384 f32 M matrices */
#define OFF_MF   196608u     /* 13 mats * 24576 (3-split bf16 frags) */
#define OFF_HWB  516096u     /* h_wave 3-split: 3*823296 */
#define OFF_HHAT 2985984u    /* f32 1646592 */
#define OFF_HBF  4632576u    /* hhat 3-split */
#define OFF_G    7102464u    /* 64*128 */
#define OFF_CMP  7110656u    /* 4*64*200 */
#define OFF_ROWH 7292928u    /* 64*201*32 */
#define OFF_COLH 7704576u    /* 64*201*32 */
#define OFF_SC   8116224u    /* 256 */
#define OFF_PM   8116480u    /* 64*64 */
#define OFF_PS   8120576u
#define OFF_PI   8124672u
#define OFF_W2F  8128768u    /* kt2 w2 frags (2-split), 1024 floats */
#define OFF_QS   8130816u    /* q 3-split: 3*131072 ushort = 196608 floats */

__device__ __forceinline__ unsigned short f2bf(float x) {
    unsigned u = __float_as_uint(x);
    unsigned r = u + 0x7fffu + ((u >> 16) & 1u);
    return (unsigned short)(r >> 16);
}
__device__ __forceinline__ float bf2f(unsigned short h) {
    return __uint_as_float(((unsigned)h) << 16);
}

/* ---- M_h = WQ_h @ WK_h^T : grid (12,4ig,4jg) ---- */
__global__ void kprep2(const float* __restrict__ rmWQ, const float* __restrict__ rmWK,
                       const float* __restrict__ i1Wq, const float* __restrict__ i1Wk,
                       const float* __restrict__ i2Wq, const float* __restrict__ i2Wk,
                       float* __restrict__ ws) {
    int m = blockIdx.x, ig = blockIdx.y, jg = blockIdx.z, t = threadIdx.x;  /* 128 */
    const float* WQ; const float* WK;
    if (m < 4)      { WQ = rmWQ + m*16384;     WK = rmWK + m*16384; }
    else if (m < 8) { WQ = i1Wq + (m-4)*16384; WK = i1Wk + (m-4)*16384; }
    else            { WQ = i2Wq + (m-8)*16384; WK = i2Wk + (m-8)*16384; }
    __shared__ float wq[32*132];
    __shared__ float wk[32*133];
    for (int idx = t; idx < 32*128; idx += 128) {
        int r = idx >> 7, e = idx & 127;
        wq[r*132 + e] = WQ[(ig*32 + r)*128 + e];
        wk[r*133 + e] = WK[(jg*32 + r)*128 + e];
    }
    __syncthreads();
    int j = t & 31, iq = t >> 5;
    #pragma unroll
    for (int i2 = 0; i2 < 8; ++i2) {
        int i = iq*8 + i2;
        float acc = 0.f;
        #pragma unroll 8
        for (int e = 0; e < 128; ++e) acc += wq[i*132 + e]*wk[j*133 + e];
        ws[OFF_M + m*16384 + (ig*32 + i)*128 + jg*32 + j] = acc;
    }
}

/* ---- 3-split bf16 MFMA B-fragments for 12 M's + Wn; block 416 = kt2 w2 frags ---- */
__global__ void kfrag(const float* __restrict__ Wn, const float* __restrict__ re_w2,
                      float* __restrict__ ws) {
    int bid = blockIdx.x;  /* 417 */
    int l = threadIdx.x;   /* 64 */
    if (bid == 416) {
        unsigned short* w2f = (unsigned short*)(ws + OFF_W2F);
        for (int idx = l; idx < 2048; idx += 64) {
            int fs = idx >> 9, ll = (idx >> 3) & 63, i = idx & 7;
            int j = 16*(fs >> 1) + (ll & 15);
            int k = ((ll >> 4)*8) + i;
            float v = re_w2[k*32 + j];
            unsigned short hi = f2bf(v);
            w2f[idx] = (fs & 1) ? f2bf(v - bf2f(hi)) : hi;
        }
        return;
    }
    int mat = bid >> 5, rem = bid & 31, nt = rem >> 2, ks = rem & 3;
    const float* src = (mat < 12) ? (ws + OFF_M + mat*16384) : Wn;
    unsigned short* mf = (unsigned short*)(ws + OFF_MF)
                       + (size_t)mat*49152 + (size_t)((nt*4 + ks)*3)*512 + l*8;
    #pragma unroll
    for (int i = 0; i < 8; ++i) {
        int k = ks*32 + (l >> 4)*8 + i;
        int col = nt*16 + (l & 15);
        float v = src[k*128 + col];
        unsigned short h = f2bf(v);
        float r1 = v - bf2f(h);
        unsigned short mm = f2bf(r1);
        unsigned short lo = f2bf(r1 - bf2f(mm));
        mf[i] = h; mf[512 + i] = mm; mf[1024 + i] = lo;
    }
}

/* ---- 3-split h_wave ---- */
__global__ void khw3(const float* __restrict__ hw, float* __restrict__ ws) {
    unsigned idx = blockIdx.x*256u + threadIdx.x;
    if (idx >= NELE) return;
    unsigned short* hh = (unsigned short*)(ws + OFF_HWB);
    unsigned short* hm = hh + NELE;
    unsigned short* hl = hh + 2u*NELE;
    float v = hw[idx];
    unsigned short a = f2bf(v);
    float r1 = v - bf2f(a);
    unsigned short b = f2bf(r1);
    unsigned short c = f2bf(r1 - bf2f(b));
    hh[idx] = a; hm[idx] = b; hl[idx] = c;
}

/* ---- hmax over N1 + g = hmax @ Wg (fused) ---- */
__global__ void khmaxg2(const float* __restrict__ hw, const float* __restrict__ Wg,
                        float* __restrict__ g) {
    int b = blockIdx.x, d = threadIdx.x;
    __shared__ float hm[128];
    float m = -INFINITY;
    const float* src = hw + (size_t)b*N1*DD + d;
    for (int n = 0; n < N1; ++n) m = fmaxf(m, src[n*DD]);
    hm[d] = m;
    __syncthreads();
    float acc = 0.f;
    for (int k = 0; k < 128; ++k) acc += hm[k] * Wg[k*128 + d];
    g[b*128 + d] = acc;
}

/* ---- h_hat = h_wave @ Wn + g via MFMA: grid (64,4cg,13mt), 1-wave blocks ---- */
__global__ __launch_bounds__(64) void khhat3(const float* __restrict__ g,
                                             float* __restrict__ ws) {
    int b = blockIdx.x, cg = blockIdx.y, mt = blockIdx.z;
    int l = threadIdx.x;
    const unsigned short* hwh = (const unsigned short*)(ws + OFF_HWB);
    const unsigned short* hwm = hwh + NELE;
    const unsigned short* hwl = hwh + 2u*NELE;
    const unsigned short* wnf = (const unsigned short*)(ws + OFF_MF) + (size_t)12*49152;
    float* hhat = ws + OFF_HHAT;
    unsigned short* hbh = (unsigned short*)(ws + OFF_HBF);
    unsigned short* hbm = hbh + NELE;
    unsigned short* hbl = hbh + 2u*NELE;
    int col0 = cg*32 + (l & 15);
    float g0 = g[b*128 + col0];
    float g1 = g[b*128 + col0 + 16];
    int arow = mt*16 + (l & 15); if (arow > 200) arow = 200;
    size_t abase = ((size_t)b*N1 + arow)*DD;
    float4v acc0 = {g0, g0, g0, g0};
    float4v acc1 = {g1, g1, g1, g1};
    #pragma unroll
    for (int ks = 0; ks < 4; ++ks) {
        size_t ao = abase + ks*32 + (l >> 4)*8;
        short8v ah = *(const short8v*)(hwh + ao);
        short8v am = *(const short8v*)(hwm + ao);
        short8v al = *(const short8v*)(hwl + ao);
        const short8v* bf0 = (const short8v*)(wnf + (size_t)(((cg*2 + 0)*4 + ks)*3)*512) + l;
        const short8v* bf1 = (const short8v*)(wnf + (size_t)(((cg*2 + 1)*4 + ks)*3)*512) + l;
        short8v bh0 = bf0[0], bm0 = bf0[64], bl0 = bf0[128];
        short8v bh1 = bf1[0], bm1 = bf1[64], bl1 = bf1[128];
        acc0 = __builtin_amdgcn_mfma_f32_16x16x32_bf16(ah, bh0, acc0, 0, 0, 0);
        acc1 = __builtin_amdgcn_mfma_f32_16x16x32_bf16(ah, bh1, acc1, 0, 0, 0);
        acc0 = __builtin_amdgcn_mfma_f32_16x16x32_bf16(ah, bm0, acc0, 0, 0, 0);
        acc1 = __builtin_amdgcn_mfma_f32_16x16x32_bf16(ah, bm1, acc1, 0, 0, 0);
        acc0 = __builtin_amdgcn_mfma_f32_16x16x32_bf16(am, bh0, acc0, 0, 0, 0);
        acc1 = __builtin_amdgcn_mfma_f32_16x16x32_bf16(am, bh1, acc1, 0, 0, 0);
        acc0 = __builtin_amdgcn_mfma_f32_16x16x32_bf16(ah, bl0, acc0, 0, 0, 0);
        acc1 = __builtin_amdgcn_mfma_f32_16x16x32_bf16(ah, bl1, acc1, 0, 0, 0);
        acc0 = __builtin_amdgcn_mfma_f32_16x16x32_bf16(al, bh0, acc0, 0, 0, 0);
        acc1 = __builtin_amdgcn_mfma_f32_16x16x32_bf16(al, bh1, acc1, 0, 0, 0);
        acc0 = __builtin_amdgcn_mfma_f32_16x16x32_bf16(am, bm0, acc0, 0, 0, 0);
        acc1 = __builtin_amdgcn_mfma_f32_16x16x32_bf16(am, bm1, acc1, 0, 0, 0);
    }
    #pragma unroll
    for (int r = 0; r < 4; ++r) {
        int row = mt*16 + (l >> 4)*4 + r;
        if (row < N1) {
            size_t i0 = ((size_t)b*N1 + row)*DD + col0;
            float v0 = acc0[r], v1 = acc1[r];
            hhat[i0] = v0; hhat[i0 + 16] = v1;
            unsigned short a0 = f2bf(v0); float r10 = v0 - bf2f(a0);
            unsigned short b0 = f2bf(r10);
            hbh[i0] = a0; hbm[i0] = b0; hbl[i0] = f2bf(r10 - bf2f(b0));
            unsigned short a1 = f2bf(v1); float r11 = v1 - bf2f(a1);
            unsigned short b1 = f2bf(r11);
            hbh[i0+16] = a1; hbm[i0+16] = b1; hbl[i0+16] = f2bf(r11 - bf2f(b1));
        }
    }
}

/* ---- fused: A = hhat @ M[h] (MFMA -> LDS) then comp dots; 512 thr / 8 waves ---- */
__global__ __launch_bounds__(512) void kAC(const int* __restrict__ solution,
                                           float* __restrict__ ws) {
    int b = blockIdx.x, h = blockIdx.y;
    int t = threadIdx.x, w = t >> 6, l = t & 63;
    __shared__ float As[N1*132];
    __shared__ int sol[N1], pre[N1], post[N1];
    if (t < N1) sol[t] = solution[b*N1 + t];
    __syncthreads();
    if (t < N1) { pre[sol[t]] = t; post[t] = sol[sol[t]]; }
    const unsigned short* hbh = (const unsigned short*)(ws + OFF_HBF);
    const unsigned short* hbm = hbh + NELE;
    const unsigned short* hbl = hbh + 2u*NELE;
    const unsigned short* mfm = (const unsigned short*)(ws + OFF_MF) + (size_t)h*49152;
    /* wave w owns col-tile w (16 cols); loops all 13 row-tiles */
    for (int mt = 0; mt < 13; ++mt) {
        int arow = mt*16 + (l & 15); if (arow > 200) arow = 200;
        size_t abase = ((size_t)b*N1 + arow)*DD;
        float4v acc = {0.f, 0.f, 0.f, 0.f};
        #pragma unroll
        for (int ks = 0; ks < 4; ++ks) {
            size_t ao = abase + ks*32 + (l >> 4)*8;
            short8v ah = *(const short8v*)(hbh + ao);
            short8v am = *(const short8v*)(hbm + ao);
            short8v al = *(const short8v*)(hbl + ao);
            const short8v* bf = (const short8v*)(mfm + (size_t)((w*4 + ks)*3)*512) + l;
            short8v bh = bf[0], bm = bf[64], bl = bf[128];
            acc = __builtin_amdgcn_mfma_f32_16x16x32_bf16(ah, bh, acc, 0, 0, 0);
            acc = __builtin_amdgcn_mfma_f32_16x16x32_bf16(ah, bm, acc, 0, 0, 0);
            acc = __builtin_amdgcn_mfma_f32_16x16x32_bf16(am, bh, acc, 0, 0, 0);
            acc = __builtin_amdgcn_mfma_f32_16x16x32_bf16(ah, bl, acc, 0, 0, 0);
            acc = __builtin_amdgcn_mfma_f32_16x16x32_bf16(al, bh, acc, 0, 0, 0);
            acc = __builtin_amdgcn_mfma_f32_16x16x32_bf16(am, bm, acc, 0, 0, 0);
        }
        int col = w*16 + (l & 15);
        #pragma unroll
        for (int r = 0; r < 4; ++r) {
            int row = mt*16 + (l >> 4)*4 + r;
            if (row < N1) As[row*132 + col] = acc[r];
        }
    }
    __syncthreads();
    const float2* X = (const float2*)(ws + OFF_HHAT) + (size_t)b*N1*64;
    float* cmp = ws + OFF_CMP + (h*64 + b)*200;
    for (int n = 1 + w; n <= 200; n += 8) {
        int pn = pre[n], po = post[n];
        float2 xn = X[n*64 + l], xp = X[po*64 + l];
        float2 ap = *(const float2*)&As[pn*132 + 2*l];
        float2 an = *(const float2*)&As[n*132 + 2*l];
        float v = ap.x*(xn.x - xp.x) + ap.y*(xn.y - xp.y) + an.x*xp.x + an.y*xp.y;
        #pragma unroll
        for (int off = 32; off; off >>= 1) v += __shfl_xor(v, off);
        if (l == 0) cmp[n - 1] = v;
    }
}

/* ---- removal MLP + softmax/argmax + q vectors (3-split out) ---- */
__global__ void krmq(const float* __restrict__ sel, const int* __restrict__ pre_action,
                     const float* __restrict__ w1, const float* __restrict__ b1,
                     const float* __restrict__ w2, const float* __restrict__ b2,
                     const float* __restrict__ w3, const float* __restrict__ b3,
                     const float* __restrict__ Mall, const float* __restrict__ hhat,
                     const float* __restrict__ cmpg, float* __restrict__ sc,
                     unsigned short* __restrict__ qs) {
    int b = blockIdx.x, t = threadIdx.x;  /* 128 */
    __shared__ float t1l[100];
    __shared__ int ppd[2];
    __shared__ float xp[128], xd[128];
    if (t < 100) {
        float f[12];
        #pragma unroll
        for (int h = 0; h < 4; ++h) {
            f[h]     = cmpg[(h*64 + b)*200 + t];
            f[4 + h] = cmpg[(h*64 + b)*200 + 100 + t];
        }
        #pragma unroll
        for (int s = 0; s < 4; ++s) f[8 + s] = sel[b*400 + s*100 + t];
        float h1[32];
        #pragma unroll
        for (int k = 0; k < 32; ++k) h1[k] = b1[k];
        #pragma unroll
        for (int j = 0; j < 12; ++j) {
            const float* wr = w1 + j*32;
            #pragma unroll
            for (int k = 0; k < 32; ++k) h1[k] += f[j]*wr[k];
        }
        #pragma unroll
        for (int k = 0; k < 32; ++k) h1[k] = fmaxf(h1[k], 0.f);
        float acc[32];
        #pragma unroll
        for (int j = 0; j < 32; ++j) acc[j] = b2[j];
        #pragma unroll
        for (int k = 0; k < 32; ++k) {
            const float* wr = w2 + k*32;
            #pragma unroll
            for (int j = 0; j < 32; ++j) acc[j] += h1[k]*wr[j];
        }
        float out = b3[0];
        #pragma unroll
        for (int j = 0; j < 32; ++j) out += fmaxf(acc[j], 0.f)*w3[j];
        t1l[t] = tanhf(out)*6.0f;
    }
    __syncthreads();
    if (t == 0) {
        if (pre_action[0] > 0) t1l[pre_action[b*2]] = NEGV;
        float M = -INFINITY; int a1 = 0;
        for (int i = 0; i < 100; ++i) if (t1l[i] > M) { M = t1l[i]; a1 = i; }
        float S = 0.f;
        for (int i = 0; i < 100; ++i) S += __expf(t1l[i] - M);
        int* ia = (int*)sc;
        ia[b] = a1;
        sc[192 + b] = -__logf(S);
        ppd[0] = 1 + a1; ppd[1] = 101 + a1;
    }
    __syncthreads();
    int pp = ppd[0], pd = ppd[1];
    const float* hb = hhat + (size_t)b*N1*DD;
    xp[t] = hb[pp*DD + t];
    xd[t] = hb[pd*DD + t];
    __syncthreads();
    int j = t;
    unsigned short* qsh = qs;
    unsigned short* qsm = qs + 131072;
    unsigned short* qsl = qs + 262144;
    #pragma unroll
    for (int h = 0; h < 4; ++h) {
        const float* M1 = Mall + (4 + h)*16384;
        const float* M2 = Mall + (8 + h)*16384;
        float a1p = 0, a2p = 0, a1d = 0, a2d = 0;
        for (int i = 0; i < 128; ++i) {
            float w1v = M1[i*128 + j], w2v = M2[i*128 + j];
            a1p += xp[i]*w1v; a1d += xd[i]*w1v;
            a2p += xp[i]*w2v; a2d += xd[i]*w2v;
        }
        float vals[4] = {a1p*QSCALE, a2p*QSCALE, a1d*QSCALE, a2d*QSCALE};
        #pragma unroll
        for (int ty = 0; ty < 4; ++ty) {
            size_t o = ((size_t)(ty*4 + h)*64 + b)*128 + j;
            float v = vals[ty];
            unsigned short hi = f2bf(v); float r1 = v - bf2f(hi);
            unsigned short md = f2bf(r1);
            qsh[o] = hi; qsm[o] = md; qsl[o] = f2bf(r1 - bf2f(md));
        }
    }
}

/* ---- rowH(+b1)/colH via MFMA: carr = hhat(gather) @ q^T, then @ w1 ---- */
__global__ __launch_bounds__(256) void krowcol2(const int* __restrict__ sol_g,
                                                const float* __restrict__ w1,
                                                const float* __restrict__ b1,
                                                float* __restrict__ ws) {
    int b = blockIdx.x, zb = blockIdx.y;  /* zb 0..1 */
    int t = threadIdx.x, w = t >> 6, l = t & 63;
    __shared__ int sol[N1];
    __shared__ float carr[N1*17];
    __shared__ float w1s[512];
    __shared__ float b1s[32];
    if (t < N1) sol[t] = sol_g[b*N1 + t];
    for (int i = t; i < 512; i += 256) w1s[i] = w1[i];
    if (t < 32) b1s[t] = b1[t];
    __syncthreads();
    const unsigned short* qsh = (const unsigned short*)(ws + OFF_QS);
    const unsigned short* qsm = qsh + 131072;
    const unsigned short* qsl = qsh + 262144;
    const unsigned short* hbh = (const unsigned short*)(ws + OFF_HBF);
    const unsigned short* hbm = hbh + NELE;
    const unsigned short* hbl = hbh + 2u*NELE;
    int j = l & 15;
    short8v Bh[4], Bm[4], Bl[4];
    #pragma unroll
    for (int ks = 0; ks < 4; ++ks) {
        size_t qo = ((size_t)j*64 + b)*128 + ks*32 + (l >> 4)*8;
        Bh[ks] = *(const short8v*)(qsh + qo);
        Bm[ks] = *(const short8v*)(qsm + qo);
        Bl[ks] = *(const short8v*)(qsl + qo);
    }
    int mt0 = zb ? 7 : 0, mt1 = zb ? 13 : 7;
    for (int mt = mt0 + w; mt < mt1; mt += 4) {
        int rA = mt*16 + j; if (rA > 200) rA = 200;
        int rB = sol[rA];
        size_t o1 = ((size_t)b*N1 + rA)*DD;
        size_t o2 = ((size_t)b*N1 + rB)*DD;
        float4v acc1 = {0.f, 0.f, 0.f, 0.f};
        float4v acc2 = {0.f, 0.f, 0.f, 0.f};
        #pragma unroll
        for (int ks = 0; ks < 4; ++ks) {
            size_t k0 = ks*32 + (l >> 4)*8;
            short8v a1h = *(const short8v*)(hbh + o1 + k0);
            short8v a1m = *(const short8v*)(hbm + o1 + k0);
            short8v a1l = *(const short8v*)(hbl + o1 + k0);
            acc1 = __builtin_amdgcn_mfma_f32_16x16x32_bf16(a1h, Bh[ks], acc1, 0, 0, 0);
            acc1 = __builtin_amdgcn_mfma_f32_16x16x32_bf16(a1h, Bm[ks], acc1, 0, 0, 0);
            acc1 = __builtin_amdgcn_mfma_f32_16x16x32_bf16(a1m, Bh[ks], acc1, 0, 0, 0);
            acc1 = __builtin_amdgcn_mfma_f32_16x16x32_bf16(a1h, Bl[ks], acc1, 0, 0, 0);
            acc1 = __builtin_amdgcn_mfma_f32_16x16x32_bf16(a1l, Bh[ks], acc1, 0, 0, 0);
            acc1 = __builtin_amdgcn_mfma_f32_16x16x32_bf16(a1m, Bm[ks], acc1, 0, 0, 0);
            short8v a2h = *(const short8v*)(hbh + o2 + k0);
            short8v a2m = *(const short8v*)(hbm + o2 + k0);
            short8v a2l = *(const short8v*)(hbl + o2 + k0);
            acc2 = __builtin_amdgcn_mfma_f32_16x16x32_bf16(a2h, Bh[ks], acc2, 0, 0, 0);
            acc2 = __builtin_amdgcn_mfma_f32_16x16x32_bf16(a2h, Bm[ks], acc2, 0, 0, 0);
            acc2 = __builtin_amdgcn_mfma_f32_16x16x32_bf16(a2m, Bh[ks], acc2, 0, 0, 0);
            acc2 = __builtin_amdgcn_mfma_f32_16x16x32_bf16(a2h, Bl[ks], acc2, 0, 0, 0);
            acc2 = __builtin_amdgcn_mfma_f32_16x16x32_bf16(a2l, Bh[ks], acc2, 0, 0, 0);
            acc2 = __builtin_amdgcn_mfma_f32_16x16x32_bf16(a2m, Bm[ks], acc2, 0, 0, 0);
        }
        int kodd = (j >> 2) & 1;
        #pragma unroll
        for (int r = 0; r < 4; ++r) {
            int row = mt*16 + (l >> 4)*4 + r;
            if (row < N1) carr[row*17 + j] = kodd ? acc2[r] : acc1[r];
        }
    }
    __syncthreads();
    int rows0 = zb*112, nrows = zb ? 89 : 112;
    float* rowH = ws + OFF_ROWH;
    float* colH = ws + OFF_COLH;
    for (int idx = t; idx < nrows*32; idx += 256) {
        int n = rows0 + (idx >> 5), k = idx & 31;
        float rh = b1s[k], ch = 0.f;
        #pragma unroll
        for (int jj = 0; jj < 8; ++jj)  rh += carr[n*17 + jj]*w1s[jj*32 + k];
        #pragma unroll
        for (int jj = 8; jj < 16; ++jj) ch += carr[n*17 + jj]*w1s[jj*32 + k];
        rowH[((size_t)b*N1 + n)*32 + k] = rh;
        colH[((size_t)b*N1 + n)*32 + k] = ch;
    }
}

/* ---- t2: zero-LDS, col-regs, 4 waves/block, 52 rows x 64 cols ---- */
__global__ __launch_bounds__(256) void kt2(
        const unsigned char* __restrict__ maskt,
        const float* __restrict__ rowH, const float* __restrict__ colH,
        const unsigned short* __restrict__ w2f,
        const float* __restrict__ b2g, const float* __restrict__ w3g,
        const float* __restrict__ b3g,
        float* __restrict__ pm, float* __restrict__ ps, int* __restrict__ pi) {
    int b = blockIdx.x, cy = blockIdx.y, rz = blockIdx.z;
    int t = threadIdx.x, w = t >> 6, l = t & 63;
    int c0 = cy*64;
    int sg = l >> 4;
    const short8v* wf = (const short8v*)w2f;
    short8v w2hi0 = wf[0*64 + l];
    short8v w2lo0 = wf[1*64 + l];
    short8v w2hi1 = wf[2*64 + l];
    short8v w2lo1 = wf[3*64 + l];
    float4v b2f0 = *(const float4v*)(b2g + sg*4);
    float4v b2f1 = *(const float4v*)(b2g + 16 + sg*4);
    float4v w3f0 = *(const float4v*)(w3g + sg*4);
    float4v w3f1 = *(const float4v*)(w3g + 16 + sg*4);
    float b3v = b3g[0];
    float4v ca[4], cb[4];
    #pragma unroll
    for (int g = 0; g < 4; ++g) {
        int cc = c0 + 16*g + (l & 15); if (cc > 200) cc = 200;
        const float4v* cp = (const float4v*)(colH + ((size_t)b*N1 + cc)*32 + sg*8);
        ca[g] = cp[0]; cb[g] = cp[1];
    }
    int r0 = rz*52 + w*13;
    int c = c0 + l;
    bool cvalid = c < N1;
    int cS = cvalid ? c : 200;
    float m = -INFINITY, s = 0.f;
    int mi = 0x7fffffff;
    const float* rbase = rowH + (size_t)b*N1*32 + sg*8;
    union U8 { unsigned u[4]; short8v s8; };
    int rl0 = r0 > 200 ? 200 : r0;
    float4v ra = ((const float4v*)(rbase + (size_t)rl0*32))[0];
    float4v rb = ((const float4v*)(rbase + (size_t)rl0*32))[1];
    for (int rr = 0; rr < 13; ++rr) {
        int r = r0 + rr;
        int rn = r + 1; if (rn > 200) rn = 200;
        const float4v* rpn = (const float4v*)(rbase + (size_t)rn*32);
        float4v ra_n = rpn[0], rb_n = rpn[1];
        int rS = r > 200 ? 200 : r;
        unsigned char mv = maskt[(size_t)b*NN + (size_t)rS*N1 + cS];
        float outv = 0.f;
        #pragma unroll
        for (int g = 0; g < 4; ++g) {
            float h[8];
            #pragma unroll
            for (int e = 0; e < 4; ++e) {
                h[e]   = fmaxf(ra[e] + ca[g][e], 0.f);
                h[4+e] = fmaxf(rb[e] + cb[g][e], 0.f);
            }
            U8 B, L;
            #pragma unroll
            for (int e = 0; e < 4; ++e) {
                unsigned ph, pl;
                asm("v_cvt_pk_bf16_f32 %0, %1, %2" : "=v"(ph) : "v"(h[2*e]), "v"(h[2*e+1]));
                float h0 = __uint_as_float(ph << 16);
                float h1f = __uint_as_float(ph & 0xffff0000u);
                float l0 = h[2*e] - h0, l1 = h[2*e+1] - h1f;
                asm("v_cvt_pk_bf16_f32 %0, %1, %2" : "=v"(pl) : "v"(l0), "v"(l1));
                B.u[e] = ph; L.u[e] = pl;
            }
            float4v a0 = b2f0, a1 = b2f1;
            a0 = __builtin_amdgcn_mfma_f32_16x16x32_bf16(w2hi0, B.s8, a0, 0, 0, 0);
            a1 = __builtin_amdgcn_mfma_f32_16x16x32_bf16(w2hi1, B.s8, a1, 0, 0, 0);
            a0 = __builtin_amdgcn_mfma_f32_16x16x32_bf16(w2hi0, L.s8, a0, 0, 0, 0);
            a1 = __builtin_amdgcn_mfma_f32_16x16x32_bf16(w2hi1, L.s8, a1, 0, 0, 0);
            a0 = __builtin_amdgcn_mfma_f32_16x16x32_bf16(w2lo0, B.s8, a0, 0, 0, 0);
            a1 = __builtin_amdgcn_mfma_f32_16x16x32_bf16(w2lo1, B.s8, a1, 0, 0, 0);
            float p = 0.f;
            #pragma unroll
            for (int reg = 0; reg < 4; ++reg) {
                p += fmaxf(a0[reg], 0.f)*w3f0[reg];
                p += fmaxf(a1[reg], 0.f)*w3f1[reg];
            }
            p += __shfl_xor(p, 16);
            p += __shfl_xor(p, 32);
            if (sg == g) outv = p + b3v;
        }
        ra = ra_n; rb = rb_n;
        float ex = __expf(2.f*outv);
        float tv = 6.f - 12.f/(ex + 1.f);
        if (mv) tv = NEGV;
        if ((r < N1) && cvalid) {
            if (tv > m) { s = s*__expf(m - tv) + 1.f; m = tv; mi = r*N1 + c; }
            else        { s += __expf(tv - m); }
        }
    }
    #pragma unroll
    for (int off = 1; off < 64; off <<= 1) {
        float om = __shfl_xor(m, off);
        float os = __shfl_xor(s, off);
        int oi = __shfl_xor(mi, off);
        float M2 = fmaxf(m, om);
        float sn = (s > 0.f ? s*__expf(m - M2) : 0.f)
                 + (os > 0.f ? os*__expf(om - M2) : 0.f);
        int in_;
        if (m > om) in_ = mi; else if (om > m) in_ = oi; else in_ = (mi < oi ? mi : oi);
        m = M2; s = sn; mi = in_;
    }
    if (l == 0) {
        int slot = b*64 + cy*16 + rz*4 + w;
        pm[slot] = m; ps[slot] = s; pi[slot] = mi;
    }
}

/* ---- final reduce + outputs ---- */
__global__ void kfinal(float* __restrict__ out, const float* __restrict__ pm,
                       const float* __restrict__ ps, const int* __restrict__ pi,
                       const float* __restrict__ sc) {
    int b = blockIdx.x, lane = threadIdx.x;  /* 64 */
    float m = pm[b*64 + lane];
    float s = ps[b*64 + lane];
    int mi = pi[b*64 + lane];
    #pragma unroll
    for (int off = 1; off < 64; off <<= 1) {
        float om = __shfl_xor(m, off);
        float os = __shfl_xor(s, off);
        int oi = __shfl_xor(mi, off);
        float M2 = fmaxf(m, om);
        float sn = (s > 0.f ? s*__expf(m - M2) : 0.f)
                 + (os > 0.f ? os*__expf(om - M2) : 0.f);
        int in_;
        if (m > om) in_ = mi; else if (om > m) in_ = oi; else in_ = (mi < oi ? mi : oi);
        m = M2; s = sn; mi = in_;
    }
    if (lane == 0) {
        float ll2 = -__logf(s);
        const int* ia = (const int*)sc;
        out[b*3 + 0] = (float)ia[b];
        out[b*3 + 1] = (float)(mi / N1);
        out[b*3 + 2] = (float)(mi % N1);
        out[192 + b] = sc[192 + b] + ll2;
    }
}

extern "C" void kernel_launch(void* const* d_in, const int* in_sizes, int n_in,
                              void* d_out, int out_size, void* d_ws, size_t ws_size,
                              hipStream_t stream) {
    const float* h_wave    = (const float*)d_in[0];
    const int*   solution  = (const int*)d_in[1];
    const float* sel       = (const float*)d_in[2];
    const int*   pre_act   = (const int*)d_in[3];
    const unsigned char* maskt = (const unsigned char*)d_in[4];
    const float* Wn    = (const float*)d_in[5];
    const float* Wg    = (const float*)d_in[6];
    const float* rmWQ  = (const float*)d_in[7];
    const float* rmWK  = (const float*)d_in[8];
    const float* rm_w1 = (const float*)d_in[9];
    const float* rm_b1 = (const float*)d_in[10];
    const float* rm_w2 = (const float*)d_in[11];
    const float* rm_b2 = (const float*)d_in[12];
    const float* rm_w3 = (const float*)d_in[13];
    const float* rm_b3 = (const float*)d_in[14];
    const float* i1Wq  = (const float*)d_in[15];
    const float* i1Wk  = (const float*)d_in[16];
    const float* i2Wq  = (const float*)d_in[17];
    const float* i2Wk  = (const float*)d_in[18];
    const float* re_w1 = (const float*)d_in[19];
    const float* re_b1 = (const float*)d_in[20];
    const float* re_w2 = (const float*)d_in[21];
    const float* re_b2 = (const float*)d_in[22];
    const float* re_w3 = (const float*)d_in[23];
    const float* re_b3 = (const float*)d_in[24];
    float* ws = (float*)d_ws;
    float* out = (float*)d_out;

    kprep2<<<dim3(12, 4, 4), dim3(128), 0, stream>>>(rmWQ, rmWK, i1Wq, i1Wk, i2Wq, i2Wk, ws);
    kfrag<<<dim3(417), dim3(64), 0, stream>>>(Wn, re_w2, ws);
    khw3<<<dim3(6432), dim3(256), 0, stream>>>(h_wave, ws);
    khmaxg2<<<dim3(64), dim3(128), 0, stream>>>(h_wave, Wg, ws + OFF_G);
    khhat3<<<dim3(64, 4, 13), dim3(64), 0, stream>>>(ws + OFF_G, ws);
    kAC<<<dim3(64, 4), dim3(512), 0, stream>>>(solution, ws);
    krmq<<<dim3(64), dim3(128), 0, stream>>>(sel, pre_act, rm_w1, rm_b1, rm_w2, rm_b2,
                                             rm_w3, rm_b3, ws + OFF_M, ws + OFF_HHAT,
                                             ws + OFF_CMP, ws + OFF_SC,
                                             (unsigned short*)(ws + OFF_QS));
    krowcol2<<<dim3(64, 2), dim3(256), 0, stream>>>(solution, re_w1, re_b1, ws);
    kt2<<<dim3(64, 4, 4), dim3(256), 0, stream>>>(maskt, ws + OFF_ROWH, ws + OFF_COLH,
                                                  (const unsigned short*)(ws + OFF_W2F),
                                                  re_b2, re_w3, re_b3,
                                                  ws + OFF_PM, ws + OFF_PS,
                                                  (int*)(ws + OFF_PI));
    kfinal<<<dim3(64), dim3(64), 0, stream>>>(out, ws + OFF_PM, ws + OFF_PS,
                                              (const int*)(ws + OFF_PI), ws + OFF_SC);
}

// Round 10
// 315.307 us; speedup vs baseline: 2.0391x; 1.0038x over previous
//
#include <hip/hip_runtime.h>
#include <math.h>

#define BB 64
#define N1 201
#define DD 128
#define HALF 100
#define NN (N1*N1)
#define NEGV (-1e20f)
#define QSCALE 0.08838834764831845f  /* 1/sqrt(128) */
#define NELE 1646592u                /* 64*201*128 */

typedef __attribute__((ext_vector_type(8))) short short8v;
typedef __attribute__((ext_vector_type(4))) float float4v;

/* ws offsets in floats */
#define OFF_M    0u          /* 12*16384 f32 M matrices */
#define OFF_MF   196608u     /* 13 mats * 24576 (3-split bf16 frags) */
#define OFF_HWB  516096u     /* h_wave 3-split: 3*823296 */
#define OFF_HHAT 2985984u    /* f32 1646592 */
#define OFF_HBF  4632576u    /* hhat 3-split */
#define OFF_G    7102464u    /* 64*128 */
#define OFF_CMP  7110656u    /* 4*64*200 */
#define OFF_ROWH 7292928u    /* 64*201*32 */
#define OFF_COLH 7704576u    /* 64*201*32 */
#define OFF_SC   8116224u    /* 256 */
#define OFF_PM   8116480u    /* 64*64 */
#define OFF_PS   8120576u
#define OFF_PI   8124672u
#define OFF_W2F  8128768u    /* kt2 w2 frags (2-split), 1024 floats */
#define OFF_QS   8130816u    /* q 3-split: 3*131072 ushort = 196608 floats */

__device__ __forceinline__ unsigned short f2bf(float x) {
    unsigned u = __float_as_uint(x);
    unsigned r = u + 0x7fffu + ((u >> 16) & 1u);
    return (unsigned short)(r >> 16);
}
__device__ __forceinline__ float bf2f(unsigned short h) {
    return __uint_as_float(((unsigned)h) << 16);
}

/* ---- M_h = WQ_h @ WK_h^T : grid (12,4ig,4jg) ---- */
__global__ void kprep2(const float* __restrict__ rmWQ, const float* __restrict__ rmWK,
                       const float* __restrict__ i1Wq, const float* __restrict__ i1Wk,
                       const float* __restrict__ i2Wq, const float* __restrict__ i2Wk,
                       float* __restrict__ ws) {
    int m = blockIdx.x, ig = blockIdx.y, jg = blockIdx.z, t = threadIdx.x;  /* 128 */
    const float* WQ; const float* WK;
    if (m < 4)      { WQ = rmWQ + m*16384;     WK = rmWK + m*16384; }
    else if (m < 8) { WQ = i1Wq + (m-4)*16384; WK = i1Wk + (m-4)*16384; }
    else            { WQ = i2Wq + (m-8)*16384; WK = i2Wk + (m-8)*16384; }
    __shared__ float wq[32*132];
    __shared__ float wk[32*133];
    for (int idx = t; idx < 32*128; idx += 128) {
        int r = idx >> 7, e = idx & 127;
        wq[r*132 + e] = WQ[(ig*32 + r)*128 + e];
        wk[r*133 + e] = WK[(jg*32 + r)*128 + e];
    }
    __syncthreads();
    int j = t & 31, iq = t >> 5;
    #pragma unroll
    for (int i2 = 0; i2 < 8; ++i2) {
        int i = iq*8 + i2;
        float acc = 0.f;
        #pragma unroll 8
        for (int e = 0; e < 128; ++e) acc += wq[i*132 + e]*wk[j*133 + e];
        ws[OFF_M + m*16384 + (ig*32 + i)*128 + jg*32 + j] = acc;
    }
}

/* ---- 3-split bf16 MFMA B-fragments for 12 M's + Wn; block 416 = kt2 w2 frags ---- */
__global__ void kfrag(const float* __restrict__ Wn, const float* __restrict__ re_w2,
                      float* __restrict__ ws) {
    int bid = blockIdx.x;  /* 417 */
    int l = threadIdx.x;   /* 64 */
    if (bid == 416) {
        unsigned short* w2f = (unsigned short*)(ws + OFF_W2F);
        for (int idx = l; idx < 2048; idx += 64) {
            int fs = idx >> 9, ll = (idx >> 3) & 63, i = idx & 7;
            int j = 16*(fs >> 1) + (ll & 15);
            int k = ((ll >> 4)*8) + i;
            float v = re_w2[k*32 + j];
            unsigned short hi = f2bf(v);
            w2f[idx] = (fs & 1) ? f2bf(v - bf2f(hi)) : hi;
        }
        return;
    }
    int mat = bid >> 5, rem = bid & 31, nt = rem >> 2, ks = rem & 3;
    const float* src = (mat < 12) ? (ws + OFF_M + mat*16384) : Wn;
    unsigned short* mf = (unsigned short*)(ws + OFF_MF)
                       + (size_t)mat*49152 + (size_t)((nt*4 + ks)*3)*512 + l*8;
    #pragma unroll
    for (int i = 0; i < 8; ++i) {
        int k = ks*32 + (l >> 4)*8 + i;
        int col = nt*16 + (l & 15);
        float v = src[k*128 + col];
        unsigned short h = f2bf(v);
        float r1 = v - bf2f(h);
        unsigned short mm = f2bf(r1);
        unsigned short lo = f2bf(r1 - bf2f(mm));
        mf[i] = h; mf[512 + i] = mm; mf[1024 + i] = lo;
    }
}

/* ---- 3-split h_wave ---- */
__global__ void khw3(const float* __restrict__ hw, float* __restrict__ ws) {
    unsigned idx = blockIdx.x*256u + threadIdx.x;
    if (idx >= NELE) return;
    unsigned short* hh = (unsigned short*)(ws + OFF_HWB);
    unsigned short* hm = hh + NELE;
    unsigned short* hl = hh + 2u*NELE;
    float v = hw[idx];
    unsigned short a = f2bf(v);
    float r1 = v - bf2f(a);
    unsigned short b = f2bf(r1);
    unsigned short c = f2bf(r1 - bf2f(b));
    hh[idx] = a; hm[idx] = b; hl[idx] = c;
}

/* ---- hmax over N1 + g = hmax @ Wg (fused) ---- */
__global__ void khmaxg2(const float* __restrict__ hw, const float* __restrict__ Wg,
                        float* __restrict__ g) {
    int b = blockIdx.x, d = threadIdx.x;
    __shared__ float hm[128];
    float m = -INFINITY;
    const float* src = hw + (size_t)b*N1*DD + d;
    for (int n = 0; n < N1; ++n) m = fmaxf(m, src[n*DD]);
    hm[d] = m;
    __syncthreads();
    float acc = 0.f;
    for (int k = 0; k < 128; ++k) acc += hm[k] * Wg[k*128 + d];
    g[b*128 + d] = acc;
}

/* ---- h_hat = h_wave @ Wn + g via MFMA: grid (64,4cg,13mt), 1-wave blocks ---- */
__global__ __launch_bounds__(64) void khhat3(const float* __restrict__ g,
                                             float* __restrict__ ws) {
    int b = blockIdx.x, cg = blockIdx.y, mt = blockIdx.z;
    int l = threadIdx.x;
    const unsigned short* hwh = (const unsigned short*)(ws + OFF_HWB);
    const unsigned short* hwm = hwh + NELE;
    const unsigned short* hwl = hwh + 2u*NELE;
    const unsigned short* wnf = (const unsigned short*)(ws + OFF_MF) + (size_t)12*49152;
    float* hhat = ws + OFF_HHAT;
    unsigned short* hbh = (unsigned short*)(ws + OFF_HBF);
    unsigned short* hbm = hbh + NELE;
    unsigned short* hbl = hbh + 2u*NELE;
    int col0 = cg*32 + (l & 15);
    float g0 = g[b*128 + col0];
    float g1 = g[b*128 + col0 + 16];
    int arow = mt*16 + (l & 15); if (arow > 200) arow = 200;
    size_t abase = ((size_t)b*N1 + arow)*DD;
    float4v acc0 = {g0, g0, g0, g0};
    float4v acc1 = {g1, g1, g1, g1};
    #pragma unroll
    for (int ks = 0; ks < 4; ++ks) {
        size_t ao = abase + ks*32 + (l >> 4)*8;
        short8v ah = *(const short8v*)(hwh + ao);
        short8v am = *(const short8v*)(hwm + ao);
        short8v al = *(const short8v*)(hwl + ao);
        const short8v* bf0 = (const short8v*)(wnf + (size_t)(((cg*2 + 0)*4 + ks)*3)*512) + l;
        const short8v* bf1 = (const short8v*)(wnf + (size_t)(((cg*2 + 1)*4 + ks)*3)*512) + l;
        short8v bh0 = bf0[0], bm0 = bf0[64], bl0 = bf0[128];
        short8v bh1 = bf1[0], bm1 = bf1[64], bl1 = bf1[128];
        acc0 = __builtin_amdgcn_mfma_f32_16x16x32_bf16(ah, bh0, acc0, 0, 0, 0);
        acc1 = __builtin_amdgcn_mfma_f32_16x16x32_bf16(ah, bh1, acc1, 0, 0, 0);
        acc0 = __builtin_amdgcn_mfma_f32_16x16x32_bf16(ah, bm0, acc0, 0, 0, 0);
        acc1 = __builtin_amdgcn_mfma_f32_16x16x32_bf16(ah, bm1, acc1, 0, 0, 0);
        acc0 = __builtin_amdgcn_mfma_f32_16x16x32_bf16(am, bh0, acc0, 0, 0, 0);
        acc1 = __builtin_amdgcn_mfma_f32_16x16x32_bf16(am, bh1, acc1, 0, 0, 0);
        acc0 = __builtin_amdgcn_mfma_f32_16x16x32_bf16(ah, bl0, acc0, 0, 0, 0);
        acc1 = __builtin_amdgcn_mfma_f32_16x16x32_bf16(ah, bl1, acc1, 0, 0, 0);
        acc0 = __builtin_amdgcn_mfma_f32_16x16x32_bf16(al, bh0, acc0, 0, 0, 0);
        acc1 = __builtin_amdgcn_mfma_f32_16x16x32_bf16(al, bh1, acc1, 0, 0, 0);
        acc0 = __builtin_amdgcn_mfma_f32_16x16x32_bf16(am, bm0, acc0, 0, 0, 0);
        acc1 = __builtin_amdgcn_mfma_f32_16x16x32_bf16(am, bm1, acc1, 0, 0, 0);
    }
    #pragma unroll
    for (int r = 0; r < 4; ++r) {
        int row = mt*16 + (l >> 4)*4 + r;
        if (row < N1) {
            size_t i0 = ((size_t)b*N1 + row)*DD + col0;
            float v0 = acc0[r], v1 = acc1[r];
            hhat[i0] = v0; hhat[i0 + 16] = v1;
            unsigned short a0 = f2bf(v0); float r10 = v0 - bf2f(a0);
            unsigned short b0 = f2bf(r10);
            hbh[i0] = a0; hbm[i0] = b0; hbl[i0] = f2bf(r10 - bf2f(b0));
            unsigned short a1 = f2bf(v1); float r11 = v1 - bf2f(a1);
            unsigned short b1 = f2bf(r11);
            hbh[i0+16] = a1; hbm[i0+16] = b1; hbl[i0+16] = f2bf(r11 - bf2f(b1));
        }
    }
}

/* ---- fused A+comp: hoisted B-frags, reg-double-buffered A-frags, split acc ---- */
__global__ __launch_bounds__(512) void kAC(const int* __restrict__ solution,
                                           float* __restrict__ ws) {
    int b = blockIdx.x, h = blockIdx.y;
    int t = threadIdx.x, w = t >> 6, l = t & 63;
    __shared__ float As[N1*132];
    __shared__ int sol[N1], pre[N1], post[N1];
    if (t < N1) sol[t] = solution[b*N1 + t];
    __syncthreads();
    if (t < N1) { pre[sol[t]] = t; post[t] = sol[sol[t]]; }
    const unsigned short* hbh = (const unsigned short*)(ws + OFF_HBF);
    const unsigned short* hbm = hbh + NELE;
    const unsigned short* hbl = hbh + 2u*NELE;
    const unsigned short* mfm = (const unsigned short*)(ws + OFF_MF) + (size_t)h*49152;
    /* hoisted mt-invariant B-fragments (wave w owns col-tile w) */
    short8v Bh[4], Bm[4], Bl[4];
    #pragma unroll
    for (int ks = 0; ks < 4; ++ks) {
        const short8v* bf = (const short8v*)(mfm + (size_t)((w*4 + ks)*3)*512) + l;
        Bh[ks] = bf[0]; Bm[ks] = bf[64]; Bl[ks] = bf[128];
    }
    int lrow = l & 15, lko = (l >> 4)*8;
    /* A-frag prefetch buffer (next mt) */
    short8v Ah[4], Am[4], Al[4];
    {
        int arow = lrow;   /* mt=0 */
        size_t abase = ((size_t)b*N1 + arow)*DD + lko;
        #pragma unroll
        for (int ks = 0; ks < 4; ++ks) {
            Ah[ks] = *(const short8v*)(hbh + abase + ks*32);
            Am[ks] = *(const short8v*)(hbm + abase + ks*32);
            Al[ks] = *(const short8v*)(hbl + abase + ks*32);
        }
    }
    for (int mt = 0; mt < 13; ++mt) {
        /* current = prefetched */
        short8v Ch[4], Cm[4], Cl[4];
        #pragma unroll
        for (int ks = 0; ks < 4; ++ks) { Ch[ks] = Ah[ks]; Cm[ks] = Am[ks]; Cl[ks] = Al[ks]; }
        /* issue next-mt loads before compute */
        if (mt < 12) {
            int arow = (mt + 1)*16 + lrow; if (arow > 200) arow = 200;
            size_t abase = ((size_t)b*N1 + arow)*DD + lko;
            #pragma unroll
            for (int ks = 0; ks < 4; ++ks) {
                Ah[ks] = *(const short8v*)(hbh + abase + ks*32);
                Am[ks] = *(const short8v*)(hbm + abase + ks*32);
                Al[ks] = *(const short8v*)(hbl + abase + ks*32);
            }
        }
        float4v acc0 = {0.f, 0.f, 0.f, 0.f};
        float4v acc1 = {0.f, 0.f, 0.f, 0.f};
        #pragma unroll
        for (int ks = 0; ks < 4; ++ks) {
            float4v& acc = (ks & 1) ? acc1 : acc0;
            acc = __builtin_amdgcn_mfma_f32_16x16x32_bf16(Ch[ks], Bh[ks], acc, 0, 0, 0);
            acc = __builtin_amdgcn_mfma_f32_16x16x32_bf16(Ch[ks], Bm[ks], acc, 0, 0, 0);
            acc = __builtin_amdgcn_mfma_f32_16x16x32_bf16(Cm[ks], Bh[ks], acc, 0, 0, 0);
            acc = __builtin_amdgcn_mfma_f32_16x16x32_bf16(Ch[ks], Bl[ks], acc, 0, 0, 0);
            acc = __builtin_amdgcn_mfma_f32_16x16x32_bf16(Cl[ks], Bh[ks], acc, 0, 0, 0);
            acc = __builtin_amdgcn_mfma_f32_16x16x32_bf16(Cm[ks], Bm[ks], acc, 0, 0, 0);
        }
        int col = w*16 + lrow;
        #pragma unroll
        for (int r = 0; r < 4; ++r) {
            int row = mt*16 + (l >> 4)*4 + r;
            if (row < N1) As[row*132 + col] = acc0[r] + acc1[r];
        }
    }
    __syncthreads();
    const float2* X = (const float2*)(ws + OFF_HHAT) + (size_t)b*N1*64;
    float* cmp = ws + OFF_CMP + (h*64 + b)*200;
    /* comp with one-iteration lookahead on gathered X loads */
    int n0 = 1 + w;
    int pn = pre[n0];
    float2 xn = X[n0*64 + l], xp = X[post[n0]*64 + l];
    for (int n = n0; n <= 200; n += 8) {
        float2 cxn = xn, cxp = xp;
        int cpn = pn;
        int nn = n + 8;
        if (nn <= 200) {
            pn = pre[nn];
            xn = X[nn*64 + l];
            xp = X[post[nn]*64 + l];
        }
        float2 ap = *(const float2*)&As[cpn*132 + 2*l];
        float2 an = *(const float2*)&As[n*132 + 2*l];
        float v = ap.x*(cxn.x - cxp.x) + ap.y*(cxn.y - cxp.y) + an.x*cxp.x + an.y*cxp.y;
        #pragma unroll
        for (int off = 32; off; off >>= 1) v += __shfl_xor(v, off);
        if (l == 0) cmp[n - 1] = v;
    }
}

/* ---- removal MLP + softmax/argmax + q vectors (3-split out) ---- */
__global__ void krmq(const float* __restrict__ sel, const int* __restrict__ pre_action,
                     const float* __restrict__ w1, const float* __restrict__ b1,
                     const float* __restrict__ w2, const float* __restrict__ b2,
                     const float* __restrict__ w3, const float* __restrict__ b3,
                     const float* __restrict__ Mall, const float* __restrict__ hhat,
                     const float* __restrict__ cmpg, float* __restrict__ sc,
                     unsigned short* __restrict__ qs) {
    int b = blockIdx.x, t = threadIdx.x;  /* 128 */
    __shared__ float t1l[100];
    __shared__ int ppd[2];
    __shared__ float xp[128], xd[128];
    if (t < 100) {
        float f[12];
        #pragma unroll
        for (int h = 0; h < 4; ++h) {
            f[h]     = cmpg[(h*64 + b)*200 + t];
            f[4 + h] = cmpg[(h*64 + b)*200 + 100 + t];
        }
        #pragma unroll
        for (int s = 0; s < 4; ++s) f[8 + s] = sel[b*400 + s*100 + t];
        float h1[32];
        #pragma unroll
        for (int k = 0; k < 32; ++k) h1[k] = b1[k];
        #pragma unroll
        for (int j = 0; j < 12; ++j) {
            const float* wr = w1 + j*32;
            #pragma unroll
            for (int k = 0; k < 32; ++k) h1[k] += f[j]*wr[k];
        }
        #pragma unroll
        for (int k = 0; k < 32; ++k) h1[k] = fmaxf(h1[k], 0.f);
        float acc[32];
        #pragma unroll
        for (int j = 0; j < 32; ++j) acc[j] = b2[j];
        #pragma unroll
        for (int k = 0; k < 32; ++k) {
            const float* wr = w2 + k*32;
            #pragma unroll
            for (int j = 0; j < 32; ++j) acc[j] += h1[k]*wr[j];
        }
        float out = b3[0];
        #pragma unroll
        for (int j = 0; j < 32; ++j) out += fmaxf(acc[j], 0.f)*w3[j];
        t1l[t] = tanhf(out)*6.0f;
    }
    __syncthreads();
    if (t == 0) {
        if (pre_action[0] > 0) t1l[pre_action[b*2]] = NEGV;
        float M = -INFINITY; int a1 = 0;
        for (int i = 0; i < 100; ++i) if (t1l[i] > M) { M = t1l[i]; a1 = i; }
        float S = 0.f;
        for (int i = 0; i < 100; ++i) S += __expf(t1l[i] - M);
        int* ia = (int*)sc;
        ia[b] = a1;
        sc[192 + b] = -__logf(S);
        ppd[0] = 1 + a1; ppd[1] = 101 + a1;
    }
    __syncthreads();
    int pp = ppd[0], pd = ppd[1];
    const float* hb = hhat + (size_t)b*N1*DD;
    xp[t] = hb[pp*DD + t];
    xd[t] = hb[pd*DD + t];
    __syncthreads();
    int j = t;
    unsigned short* qsh = qs;
    unsigned short* qsm = qs + 131072;
    unsigned short* qsl = qs + 262144;
    #pragma unroll
    for (int h = 0; h < 4; ++h) {
        const float* M1 = Mall + (4 + h)*16384;
        const float* M2 = Mall + (8 + h)*16384;
        float a1p = 0, a2p = 0, a1d = 0, a2d = 0;
        for (int i = 0; i < 128; ++i) {
            float w1v = M1[i*128 + j], w2v = M2[i*128 + j];
            a1p += xp[i]*w1v; a1d += xd[i]*w1v;
            a2p += xp[i]*w2v; a2d += xd[i]*w2v;
        }
        float vals[4] = {a1p*QSCALE, a2p*QSCALE, a1d*QSCALE, a2d*QSCALE};
        #pragma unroll
        for (int ty = 0; ty < 4; ++ty) {
            size_t o = ((size_t)(ty*4 + h)*64 + b)*128 + j;
            float v = vals[ty];
            unsigned short hi = f2bf(v); float r1 = v - bf2f(hi);
            unsigned short md = f2bf(r1);
            qsh[o] = hi; qsm[o] = md; qsl[o] = f2bf(r1 - bf2f(md));
        }
    }
}

/* ---- rowH(+b1)/colH via MFMA: carr = hhat(gather) @ q^T, then @ w1 ---- */
__global__ __launch_bounds__(256) void krowcol2(const int* __restrict__ sol_g,
                                                const float* __restrict__ w1,
                                                const float* __restrict__ b1,
                                                float* __restrict__ ws) {
    int b = blockIdx.x, zb = blockIdx.y;  /* zb 0..1 */
    int t = threadIdx.x, w = t >> 6, l = t & 63;
    __shared__ int sol[N1];
    __shared__ float carr[N1*17];
    __shared__ float w1s[512];
    __shared__ float b1s[32];
    if (t < N1) sol[t] = sol_g[b*N1 + t];
    for (int i = t; i < 512; i += 256) w1s[i] = w1[i];
    if (t < 32) b1s[t] = b1[t];
    __syncthreads();
    const unsigned short* qsh = (const unsigned short*)(ws + OFF_QS);
    const unsigned short* qsm = qsh + 131072;
    const unsigned short* qsl = qsh + 262144;
    const unsigned short* hbh = (const unsigned short*)(ws + OFF_HBF);
    const unsigned short* hbm = hbh + NELE;
    const unsigned short* hbl = hbh + 2u*NELE;
    int j = l & 15;
    short8v Bh[4], Bm[4], Bl[4];
    #pragma unroll
    for (int ks = 0; ks < 4; ++ks) {
        size_t qo = ((size_t)j*64 + b)*128 + ks*32 + (l >> 4)*8;
        Bh[ks] = *(const short8v*)(qsh + qo);
        Bm[ks] = *(const short8v*)(qsm + qo);
        Bl[ks] = *(const short8v*)(qsl + qo);
    }
    int mt0 = zb ? 7 : 0, mt1 = zb ? 13 : 7;
    for (int mt = mt0 + w; mt < mt1; mt += 4) {
        int rA = mt*16 + j; if (rA > 200) rA = 200;
        int rB = sol[rA];
        size_t o1 = ((size_t)b*N1 + rA)*DD;
        size_t o2 = ((size_t)b*N1 + rB)*DD;
        float4v acc1 = {0.f, 0.f, 0.f, 0.f};
        float4v acc2 = {0.f, 0.f, 0.f, 0.f};
        #pragma unroll
        for (int ks = 0; ks < 4; ++ks) {
            size_t k0 = ks*32 + (l >> 4)*8;
            short8v a1h = *(const short8v*)(hbh + o1 + k0);
            short8v a1m = *(const short8v*)(hbm + o1 + k0);
            short8v a1l = *(const short8v*)(hbl + o1 + k0);
            acc1 = __builtin_amdgcn_mfma_f32_16x16x32_bf16(a1h, Bh[ks], acc1, 0, 0, 0);
            acc1 = __builtin_amdgcn_mfma_f32_16x16x32_bf16(a1h, Bm[ks], acc1, 0, 0, 0);
            acc1 = __builtin_amdgcn_mfma_f32_16x16x32_bf16(a1m, Bh[ks], acc1, 0, 0, 0);
            acc1 = __builtin_amdgcn_mfma_f32_16x16x32_bf16(a1h, Bl[ks], acc1, 0, 0, 0);
            acc1 = __builtin_amdgcn_mfma_f32_16x16x32_bf16(a1l, Bh[ks], acc1, 0, 0, 0);
            acc1 = __builtin_amdgcn_mfma_f32_16x16x32_bf16(a1m, Bm[ks], acc1, 0, 0, 0);
            short8v a2h = *(const short8v*)(hbh + o2 + k0);
            short8v a2m = *(const short8v*)(hbm + o2 + k0);
            short8v a2l = *(const short8v*)(hbl + o2 + k0);
            acc2 = __builtin_amdgcn_mfma_f32_16x16x32_bf16(a2h, Bh[ks], acc2, 0, 0, 0);
            acc2 = __builtin_amdgcn_mfma_f32_16x16x32_bf16(a2h, Bm[ks], acc2, 0, 0, 0);
            acc2 = __builtin_amdgcn_mfma_f32_16x16x32_bf16(a2m, Bh[ks], acc2, 0, 0, 0);
            acc2 = __builtin_amdgcn_mfma_f32_16x16x32_bf16(a2h, Bl[ks], acc2, 0, 0, 0);
            acc2 = __builtin_amdgcn_mfma_f32_16x16x32_bf16(a2l, Bh[ks], acc2, 0, 0, 0);
            acc2 = __builtin_amdgcn_mfma_f32_16x16x32_bf16(a2m, Bm[ks], acc2, 0, 0, 0);
        }
        int kodd = (j >> 2) & 1;
        #pragma unroll
        for (int r = 0; r < 4; ++r) {
            int row = mt*16 + (l >> 4)*4 + r;
            if (row < N1) carr[row*17 + j] = kodd ? acc2[r] : acc1[r];
        }
    }
    __syncthreads();
    int rows0 = zb*112, nrows = zb ? 89 : 112;
    float* rowH = ws + OFF_ROWH;
    float* colH = ws + OFF_COLH;
    for (int idx = t; idx < nrows*32; idx += 256) {
        int n = rows0 + (idx >> 5), k = idx & 31;
        float rh = b1s[k], ch = 0.f;
        #pragma unroll
        for (int jj = 0; jj < 8; ++jj)  rh += carr[n*17 + jj]*w1s[jj*32 + k];
        #pragma unroll
        for (int jj = 8; jj < 16; ++jj) ch += carr[n*17 + jj]*w1s[jj*32 + k];
        rowH[((size_t)b*N1 + n)*32 + k] = rh;
        colH[((size_t)b*N1 + n)*32 + k] = ch;
    }
}

/* ---- t2: zero-LDS, col-regs, 4 waves/block, 52 rows x 64 cols ---- */
__global__ __launch_bounds__(256) void kt2(
        const unsigned char* __restrict__ maskt,
        const float* __restrict__ rowH, const float* __restrict__ colH,
        const unsigned short* __restrict__ w2f,
        const float* __restrict__ b2g, const float* __restrict__ w3g,
        const float* __restrict__ b3g,
        float* __restrict__ pm, float* __restrict__ ps, int* __restrict__ pi) {
    int b = blockIdx.x, cy = blockIdx.y, rz = blockIdx.z;
    int t = threadIdx.x, w = t >> 6, l = t & 63;
    int c0 = cy*64;
    int sg = l >> 4;
    const short8v* wf = (const short8v*)w2f;
    short8v w2hi0 = wf[0*64 + l];
    short8v w2lo0 = wf[1*64 + l];
    short8v w2hi1 = wf[2*64 + l];
    short8v w2lo1 = wf[3*64 + l];
    float4v b2f0 = *(const float4v*)(b2g + sg*4);
    float4v b2f1 = *(const float4v*)(b2g + 16 + sg*4);
    float4v w3f0 = *(const float4v*)(w3g + sg*4);
    float4v w3f1 = *(const float4v*)(w3g + 16 + sg*4);
    float b3v = b3g[0];
    float4v ca[4], cb[4];
    #pragma unroll
    for (int g = 0; g < 4; ++g) {
        int cc = c0 + 16*g + (l & 15); if (cc > 200) cc = 200;
        const float4v* cp = (const float4v*)(colH + ((size_t)b*N1 + cc)*32 + sg*8);
        ca[g] = cp[0]; cb[g] = cp[1];
    }
    int r0 = rz*52 + w*13;
    int c = c0 + l;
    bool cvalid = c < N1;
    int cS = cvalid ? c : 200;
    float m = -INFINITY, s = 0.f;
    int mi = 0x7fffffff;
    const float* rbase = rowH + (size_t)b*N1*32 + sg*8;
    union U8 { unsigned u[4]; short8v s8; };
    int rl0 = r0 > 200 ? 200 : r0;
    float4v ra = ((const float4v*)(rbase + (size_t)rl0*32))[0];
    float4v rb = ((const float4v*)(rbase + (size_t)rl0*32))[1];
    for (int rr = 0; rr < 13; ++rr) {
        int r = r0 + rr;
        int rn = r + 1; if (rn > 200) rn = 200;
        const float4v* rpn = (const float4v*)(rbase + (size_t)rn*32);
        float4v ra_n = rpn[0], rb_n = rpn[1];
        int rS = r > 200 ? 200 : r;
        unsigned char mv = maskt[(size_t)b*NN + (size_t)rS*N1 + cS];
        float outv = 0.f;
        #pragma unroll
        for (int g = 0; g < 4; ++g) {
            float h[8];
            #pragma unroll
            for (int e = 0; e < 4; ++e) {
                h[e]   = fmaxf(ra[e] + ca[g][e], 0.f);
                h[4+e] = fmaxf(rb[e] + cb[g][e], 0.f);
            }
            U8 B, L;
            #pragma unroll
            for (int e = 0; e < 4; ++e) {
                unsigned ph, pl;
                asm("v_cvt_pk_bf16_f32 %0, %1, %2" : "=v"(ph) : "v"(h[2*e]), "v"(h[2*e+1]));
                float h0 = __uint_as_float(ph << 16);
                float h1f = __uint_as_float(ph & 0xffff0000u);
                float l0 = h[2*e] - h0, l1 = h[2*e+1] - h1f;
                asm("v_cvt_pk_bf16_f32 %0, %1, %2" : "=v"(pl) : "v"(l0), "v"(l1));
                B.u[e] = ph; L.u[e] = pl;
            }
            float4v a0 = b2f0, a1 = b2f1;
            a0 = __builtin_amdgcn_mfma_f32_16x16x32_bf16(w2hi0, B.s8, a0, 0, 0, 0);
            a1 = __builtin_amdgcn_mfma_f32_16x16x32_bf16(w2hi1, B.s8, a1, 0, 0, 0);
            a0 = __builtin_amdgcn_mfma_f32_16x16x32_bf16(w2hi0, L.s8, a0, 0, 0, 0);
            a1 = __builtin_amdgcn_mfma_f32_16x16x32_bf16(w2hi1, L.s8, a1, 0, 0, 0);
            a0 = __builtin_amdgcn_mfma_f32_16x16x32_bf16(w2lo0, B.s8, a0, 0, 0, 0);
            a1 = __builtin_amdgcn_mfma_f32_16x16x32_bf16(w2lo1, B.s8, a1, 0, 0, 0);
            float p = 0.f;
            #pragma unroll
            for (int reg = 0; reg < 4; ++reg) {
                p += fmaxf(a0[reg], 0.f)*w3f0[reg];
                p += fmaxf(a1[reg], 0.f)*w3f1[reg];
            }
            p += __shfl_xor(p, 16);
            p += __shfl_xor(p, 32);
            if (sg == g) outv = p + b3v;
        }
        ra = ra_n; rb = rb_n;
        float ex = __expf(2.f*outv);
        float tv = 6.f - 12.f/(ex + 1.f);
        if (mv) tv = NEGV;
        if ((r < N1) && cvalid) {
            if (tv > m) { s = s*__expf(m - tv) + 1.f; m = tv; mi = r*N1 + c; }
            else        { s += __expf(tv - m); }
        }
    }
    #pragma unroll
    for (int off = 1; off < 64; off <<= 1) {
        float om = __shfl_xor(m, off);
        float os = __shfl_xor(s, off);
        int oi = __shfl_xor(mi, off);
        float M2 = fmaxf(m, om);
        float sn = (s > 0.f ? s*__expf(m - M2) : 0.f)
                 + (os > 0.f ? os*__expf(om - M2) : 0.f);
        int in_;
        if (m > om) in_ = mi; else if (om > m) in_ = oi; else in_ = (mi < oi ? mi : oi);
        m = M2; s = sn; mi = in_;
    }
    if (l == 0) {
        int slot = b*64 + cy*16 + rz*4 + w;
        pm[slot] = m; ps[slot] = s; pi[slot] = mi;
    }
}

/* ---- final reduce + outputs ---- */
__global__ void kfinal(float* __restrict__ out, const float* __restrict__ pm,
                       const float* __restrict__ ps, const int* __restrict__ pi,
                       const float* __restrict__ sc) {
    int b = blockIdx.x, lane = threadIdx.x;  /* 64 */
    float m = pm[b*64 + lane];
    float s = ps[b*64 + lane];
    int mi = pi[b*64 + lane];
    #pragma unroll
    for (int off = 1; off < 64; off <<= 1) {
        float om = __shfl_xor(m, off);
        float os = __shfl_xor(s, off);
        int oi = __shfl_xor(mi, off);
        float M2 = fmaxf(m, om);
        float sn = (s > 0.f ? s*__expf(m - M2) : 0.f)
                 + (os > 0.f ? os*__expf(om - M2) : 0.f);
        int in_;
        if (m > om) in_ = mi; else if (om > m) in_ = oi; else in_ = (mi < oi ? mi : oi);
        m = M2; s = sn; mi = in_;
    }
    if (lane == 0) {
        float ll2 = -__logf(s);
        const int* ia = (const int*)sc;
        out[b*3 + 0] = (float)ia[b];
        out[b*3 + 1] = (float)(mi / N1);
        out[b*3 + 2] = (float)(mi % N1);
        out[192 + b] = sc[192 + b] + ll2;
    }
}

extern "C" void kernel_launch(void* const* d_in, const int* in_sizes, int n_in,
                              void* d_out, int out_size, void* d_ws, size_t ws_size,
                              hipStream_t stream) {
    const float* h_wave    = (const float*)d_in[0];
    const int*   solution  = (const int*)d_in[1];
    const float* sel       = (const float*)d_in[2];
    const int*   pre_act   = (const int*)d_in[3];
    const unsigned char* maskt = (const unsigned char*)d_in[4];
    const float* Wn    = (const float*)d_in[5];
    const float* Wg    = (const float*)d_in[6];
    const float* rmWQ  = (const float*)d_in[7];
    const float* rmWK  = (const float*)d_in[8];
    const float* rm_w1 = (const float*)d_in[9];
    const float* rm_b1 = (const float*)d_in[10];
    const float* rm_w2 = (const float*)d_in[11];
    const float* rm_b2 = (const float*)d_in[12];
    const float* rm_w3 = (const float*)d_in[13];
    const float* rm_b3 = (const float*)d_in[14];
    const float* i1Wq  = (const float*)d_in[15];
    const float* i1Wk  = (const float*)d_in[16];
    const float* i2Wq  = (const float*)d_in[17];
    const float* i2Wk  = (const float*)d_in[18];
    const float* re_w1 = (const float*)d_in[19];
    const float* re_b1 = (const float*)d_in[20];
    const float* re_w2 = (const float*)d_in[21];
    const float* re_b2 = (const float*)d_in[22];
    const float* re_w3 = (const float*)d_in[23];
    const float* re_b3 = (const float*)d_in[24];
    float* ws = (float*)d_ws;
    float* out = (float*)d_out;

    kprep2<<<dim3(12, 4, 4), dim3(128), 0, stream>>>(rmWQ, rmWK, i1Wq, i1Wk, i2Wq, i2Wk, ws);
    kfrag<<<dim3(417), dim3(64), 0, stream>>>(Wn, re_w2, ws);
    khw3<<<dim3(6432), dim3(256), 0, stream>>>(h_wave, ws);
    khmaxg2<<<dim3(64), dim3(128), 0, stream>>>(h_wave, Wg, ws + OFF_G);
    khhat3<<<dim3(64, 4, 13), dim3(64), 0, stream>>>(ws + OFF_G, ws);
    kAC<<<dim3(64, 4), dim3(512), 0, stream>>>(solution, ws);
    krmq<<<dim3(64), dim3(128), 0, stream>>>(sel, pre_act, rm_w1, rm_b1, rm_w2, rm_b2,
                                             rm_w3, rm_b3, ws + OFF_M, ws + OFF_HHAT,
                                             ws + OFF_CMP, ws + OFF_SC,
                                             (unsigned short*)(ws + OFF_QS));
    krowcol2<<<dim3(64, 2), dim3(256), 0, stream>>>(solution, re_w1, re_b1, ws);
    kt2<<<dim3(64, 4, 4), dim3(256), 0, stream>>>(maskt, ws + OFF_ROWH, ws + OFF_COLH,
                                                  (const unsigned short*)(ws + OFF_W2F),
                                                  re_b2, re_w3, re_b3,
                                                  ws + OFF_PM, ws + OFF_PS,
                                                  (int*)(ws + OFF_PI));
    kfinal<<<dim3(64), dim3(64), 0, stream>>>(out, ws + OFF_PM, ws + OFF_PS,
                                              (const int*)(ws + OFF_PI), ws + OFF_SC);
}

// Round 11
// 302.297 us; speedup vs baseline: 2.1268x; 1.0430x over previous
//
#include <hip/hip_runtime.h>
#include <math.h>

#define BB 64
#define N1 201
#define DD 128
#define HALF 100
#define NN (N1*N1)
#define NEGV (-1e20f)
#define QSCALE 0.08838834764831845f  /* 1/sqrt(128) */
#define NELE 1646592u                /* 64*201*128 */

typedef __attribute__((ext_vector_type(8))) short short8v;
typedef __attribute__((ext_vector_type(4))) float float4v;

/* ws offsets in floats */
#define OFF_M    0u          /* 12*16384 f32 M matrices */
#define OFF_MF   196608u     /* 13 mats * 24576 (3-split bf16 frags) */
#define OFF_HWB  516096u     /* h_wave 3-split: 3*823296 */
#define OFF_HHAT 2985984u    /* f32 1646592 */
#define OFF_HBF  4632576u    /* hhat 3-split */
#define OFF_G    7102464u    /* 64*128 */
#define OFF_CMP  7110656u    /* 4*64*200 */
#define OFF_ROWH 7292928u    /* 64*201*32 */
#define OFF_COLH 7704576u    /* 64*201*32 */
#define OFF_SC   8116224u    /* 256 */
#define OFF_PM   8116480u    /* 64*64 */
#define OFF_PS   8120576u
#define OFF_PI   8124672u
#define OFF_W2F  8128768u    /* kt2 w2 frags (2-split), 1024 floats */
#define OFF_QS   8130816u    /* q 3-split: 3*131072 ushort = 196608 floats */

__device__ __forceinline__ unsigned short f2bf(float x) {
    unsigned u = __float_as_uint(x);
    unsigned r = u + 0x7fffu + ((u >> 16) & 1u);
    return (unsigned short)(r >> 16);
}
__device__ __forceinline__ float bf2f(unsigned short h) {
    return __uint_as_float(((unsigned)h) << 16);
}

/* ---- M_h = WQ_h @ WK_h^T : grid (12,4ig,4jg) ---- */
__global__ void kprep2(const float* __restrict__ rmWQ, const float* __restrict__ rmWK,
                       const float* __restrict__ i1Wq, const float* __restrict__ i1Wk,
                       const float* __restrict__ i2Wq, const float* __restrict__ i2Wk,
                       float* __restrict__ ws) {
    int m = blockIdx.x, ig = blockIdx.y, jg = blockIdx.z, t = threadIdx.x;  /* 128 */
    const float* WQ; const float* WK;
    if (m < 4)      { WQ = rmWQ + m*16384;     WK = rmWK + m*16384; }
    else if (m < 8) { WQ = i1Wq + (m-4)*16384; WK = i1Wk + (m-4)*16384; }
    else            { WQ = i2Wq + (m-8)*16384; WK = i2Wk + (m-8)*16384; }
    __shared__ float wq[32*132];
    __shared__ float wk[32*133];
    for (int idx = t; idx < 32*128; idx += 128) {
        int r = idx >> 7, e = idx & 127;
        wq[r*132 + e] = WQ[(ig*32 + r)*128 + e];
        wk[r*133 + e] = WK[(jg*32 + r)*128 + e];
    }
    __syncthreads();
    int j = t & 31, iq = t >> 5;
    #pragma unroll
    for (int i2 = 0; i2 < 8; ++i2) {
        int i = iq*8 + i2;
        float acc = 0.f;
        #pragma unroll 8
        for (int e = 0; e < 128; ++e) acc += wq[i*132 + e]*wk[j*133 + e];
        ws[OFF_M + m*16384 + (ig*32 + i)*128 + jg*32 + j] = acc;
    }
}

/* ---- 3-split bf16 MFMA B-fragments for 12 M's + Wn; block 416 = kt2 w2 frags ---- */
__global__ void kfrag(const float* __restrict__ Wn, const float* __restrict__ re_w2,
                      float* __restrict__ ws) {
    int bid = blockIdx.x;  /* 417 */
    int l = threadIdx.x;   /* 64 */
    if (bid == 416) {
        unsigned short* w2f = (unsigned short*)(ws + OFF_W2F);
        for (int idx = l; idx < 2048; idx += 64) {
            int fs = idx >> 9, ll = (idx >> 3) & 63, i = idx & 7;
            int j = 16*(fs >> 1) + (ll & 15);
            int k = ((ll >> 4)*8) + i;
            float v = re_w2[k*32 + j];
            unsigned short hi = f2bf(v);
            w2f[idx] = (fs & 1) ? f2bf(v - bf2f(hi)) : hi;
        }
        return;
    }
    int mat = bid >> 5, rem = bid & 31, nt = rem >> 2, ks = rem & 3;
    const float* src = (mat < 12) ? (ws + OFF_M + mat*16384) : Wn;
    unsigned short* mf = (unsigned short*)(ws + OFF_MF)
                       + (size_t)mat*49152 + (size_t)((nt*4 + ks)*3)*512 + l*8;
    #pragma unroll
    for (int i = 0; i < 8; ++i) {
        int k = ks*32 + (l >> 4)*8 + i;
        int col = nt*16 + (l & 15);
        float v = src[k*128 + col];
        unsigned short h = f2bf(v);
        float r1 = v - bf2f(h);
        unsigned short mm = f2bf(r1);
        unsigned short lo = f2bf(r1 - bf2f(mm));
        mf[i] = h; mf[512 + i] = mm; mf[1024 + i] = lo;
    }
}

/* ---- 3-split h_wave ; XCD-affine: b = bid & 63 ---- */
__global__ void khw3(const float* __restrict__ hw, float* __restrict__ ws) {
    int i = blockIdx.x;            /* 64*101 */
    int b = i & 63, ch = i >> 6;   /* ch 0..100 */
    unsigned off = (unsigned)ch*256u + threadIdx.x;
    if (off >= 25728u) return;
    unsigned idx = (unsigned)b*25728u + off;
    unsigned short* hh = (unsigned short*)(ws + OFF_HWB);
    unsigned short* hm = hh + NELE;
    unsigned short* hl = hh + 2u*NELE;
    float v = hw[idx];
    unsigned short a = f2bf(v);
    float r1 = v - bf2f(a);
    unsigned short b2 = f2bf(r1);
    unsigned short c = f2bf(r1 - bf2f(b2));
    hh[idx] = a; hm[idx] = b2; hl[idx] = c;
}

/* ---- hmax over N1 + g = hmax @ Wg (fused); b = blockIdx.x (b%8 = XCD) ---- */
__global__ void khmaxg2(const float* __restrict__ hw, const float* __restrict__ Wg,
                        float* __restrict__ g) {
    int b = blockIdx.x, d = threadIdx.x;
    __shared__ float hm[128];
    float m = -INFINITY;
    const float* src = hw + (size_t)b*N1*DD + d;
    for (int n = 0; n < N1; ++n) m = fmaxf(m, src[n*DD]);
    hm[d] = m;
    __syncthreads();
    float acc = 0.f;
    for (int k = 0; k < 128; ++k) acc += hm[k] * Wg[k*128 + d];
    g[b*128 + d] = acc;
}

/* ---- h_hat via MFMA: 1D grid 3328, XCD-affine b = bid & 63 ---- */
__global__ __launch_bounds__(64) void khhat3(const float* __restrict__ g,
                                             float* __restrict__ ws) {
    int i = blockIdx.x;
    int b = i & 63, r_ = i >> 6;       /* r_ 0..51 */
    int cg = r_ & 3, mt = r_ >> 2;     /* cg 0..3, mt 0..12 */
    int l = threadIdx.x;
    const unsigned short* hwh = (const unsigned short*)(ws + OFF_HWB);
    const unsigned short* hwm = hwh + NELE;
    const unsigned short* hwl = hwh + 2u*NELE;
    const unsigned short* wnf = (const unsigned short*)(ws + OFF_MF) + (size_t)12*49152;
    float* hhat = ws + OFF_HHAT;
    unsigned short* hbh = (unsigned short*)(ws + OFF_HBF);
    unsigned short* hbm = hbh + NELE;
    unsigned short* hbl = hbh + 2u*NELE;
    int col0 = cg*32 + (l & 15);
    float g0 = g[b*128 + col0];
    float g1 = g[b*128 + col0 + 16];
    int arow = mt*16 + (l & 15); if (arow > 200) arow = 200;
    size_t abase = ((size_t)b*N1 + arow)*DD;
    float4v acc0 = {g0, g0, g0, g0};
    float4v acc1 = {g1, g1, g1, g1};
    #pragma unroll
    for (int ks = 0; ks < 4; ++ks) {
        size_t ao = abase + ks*32 + (l >> 4)*8;
        short8v ah = *(const short8v*)(hwh + ao);
        short8v am = *(const short8v*)(hwm + ao);
        short8v al = *(const short8v*)(hwl + ao);
        const short8v* bf0 = (const short8v*)(wnf + (size_t)(((cg*2 + 0)*4 + ks)*3)*512) + l;
        const short8v* bf1 = (const short8v*)(wnf + (size_t)(((cg*2 + 1)*4 + ks)*3)*512) + l;
        short8v bh0 = bf0[0], bm0 = bf0[64], bl0 = bf0[128];
        short8v bh1 = bf1[0], bm1 = bf1[64], bl1 = bf1[128];
        acc0 = __builtin_amdgcn_mfma_f32_16x16x32_bf16(ah, bh0, acc0, 0, 0, 0);
        acc1 = __builtin_amdgcn_mfma_f32_16x16x32_bf16(ah, bh1, acc1, 0, 0, 0);
        acc0 = __builtin_amdgcn_mfma_f32_16x16x32_bf16(ah, bm0, acc0, 0, 0, 0);
        acc1 = __builtin_amdgcn_mfma_f32_16x16x32_bf16(ah, bm1, acc1, 0, 0, 0);
        acc0 = __builtin_amdgcn_mfma_f32_16x16x32_bf16(am, bh0, acc0, 0, 0, 0);
        acc1 = __builtin_amdgcn_mfma_f32_16x16x32_bf16(am, bh1, acc1, 0, 0, 0);
        acc0 = __builtin_amdgcn_mfma_f32_16x16x32_bf16(ah, bl0, acc0, 0, 0, 0);
        acc1 = __builtin_amdgcn_mfma_f32_16x16x32_bf16(ah, bl1, acc1, 0, 0, 0);
        acc0 = __builtin_amdgcn_mfma_f32_16x16x32_bf16(al, bh0, acc0, 0, 0, 0);
        acc1 = __builtin_amdgcn_mfma_f32_16x16x32_bf16(al, bh1, acc1, 0, 0, 0);
        acc0 = __builtin_amdgcn_mfma_f32_16x16x32_bf16(am, bm0, acc0, 0, 0, 0);
        acc1 = __builtin_amdgcn_mfma_f32_16x16x32_bf16(am, bm1, acc1, 0, 0, 0);
    }
    #pragma unroll
    for (int r = 0; r < 4; ++r) {
        int row = mt*16 + (l >> 4)*4 + r;
        if (row < N1) {
            size_t i0 = ((size_t)b*N1 + row)*DD + col0;
            float v0 = acc0[r], v1 = acc1[r];
            hhat[i0] = v0; hhat[i0 + 16] = v1;
            unsigned short a0 = f2bf(v0); float r10 = v0 - bf2f(a0);
            unsigned short b0 = f2bf(r10);
            hbh[i0] = a0; hbm[i0] = b0; hbl[i0] = f2bf(r10 - bf2f(b0));
            unsigned short a1 = f2bf(v1); float r11 = v1 - bf2f(a1);
            unsigned short b1 = f2bf(r11);
            hbh[i0+16] = a1; hbm[i0+16] = b1; hbl[i0+16] = f2bf(r11 - bf2f(b1));
        }
    }
}

/* ---- fused A+comp: 1D grid 256, XCD-affine b = bid & 63 ---- */
__global__ __launch_bounds__(512) void kAC(const int* __restrict__ solution,
                                           float* __restrict__ ws) {
    int bid = blockIdx.x;
    int b = bid & 63, h = bid >> 6;
    int t = threadIdx.x, w = t >> 6, l = t & 63;
    __shared__ float As[N1*132];
    __shared__ int sol[N1], pre[N1], post[N1];
    if (t < N1) sol[t] = solution[b*N1 + t];
    __syncthreads();
    if (t < N1) { pre[sol[t]] = t; post[t] = sol[sol[t]]; }
    const unsigned short* hbh = (const unsigned short*)(ws + OFF_HBF);
    const unsigned short* hbm = hbh + NELE;
    const unsigned short* hbl = hbh + 2u*NELE;
    const unsigned short* mfm = (const unsigned short*)(ws + OFF_MF) + (size_t)h*49152;
    short8v Bh[4], Bm[4], Bl[4];
    #pragma unroll
    for (int ks = 0; ks < 4; ++ks) {
        const short8v* bf = (const short8v*)(mfm + (size_t)((w*4 + ks)*3)*512) + l;
        Bh[ks] = bf[0]; Bm[ks] = bf[64]; Bl[ks] = bf[128];
    }
    int lrow = l & 15, lko = (l >> 4)*8;
    short8v Ah[4], Am[4], Al[4];
    {
        int arow = lrow;
        size_t abase = ((size_t)b*N1 + arow)*DD + lko;
        #pragma unroll
        for (int ks = 0; ks < 4; ++ks) {
            Ah[ks] = *(const short8v*)(hbh + abase + ks*32);
            Am[ks] = *(const short8v*)(hbm + abase + ks*32);
            Al[ks] = *(const short8v*)(hbl + abase + ks*32);
        }
    }
    for (int mt = 0; mt < 13; ++mt) {
        short8v Ch[4], Cm[4], Cl[4];
        #pragma unroll
        for (int ks = 0; ks < 4; ++ks) { Ch[ks] = Ah[ks]; Cm[ks] = Am[ks]; Cl[ks] = Al[ks]; }
        if (mt < 12) {
            int arow = (mt + 1)*16 + lrow; if (arow > 200) arow = 200;
            size_t abase = ((size_t)b*N1 + arow)*DD + lko;
            #pragma unroll
            for (int ks = 0; ks < 4; ++ks) {
                Ah[ks] = *(const short8v*)(hbh + abase + ks*32);
                Am[ks] = *(const short8v*)(hbm + abase + ks*32);
                Al[ks] = *(const short8v*)(hbl + abase + ks*32);
            }
        }
        float4v acc0 = {0.f, 0.f, 0.f, 0.f};
        float4v acc1 = {0.f, 0.f, 0.f, 0.f};
        #pragma unroll
        for (int ks = 0; ks < 4; ++ks) {
            float4v& acc = (ks & 1) ? acc1 : acc0;
            acc = __builtin_amdgcn_mfma_f32_16x16x32_bf16(Ch[ks], Bh[ks], acc, 0, 0, 0);
            acc = __builtin_amdgcn_mfma_f32_16x16x32_bf16(Ch[ks], Bm[ks], acc, 0, 0, 0);
            acc = __builtin_amdgcn_mfma_f32_16x16x32_bf16(Cm[ks], Bh[ks], acc, 0, 0, 0);
            acc = __builtin_amdgcn_mfma_f32_16x16x32_bf16(Ch[ks], Bl[ks], acc, 0, 0, 0);
            acc = __builtin_amdgcn_mfma_f32_16x16x32_bf16(Cl[ks], Bh[ks], acc, 0, 0, 0);
            acc = __builtin_amdgcn_mfma_f32_16x16x32_bf16(Cm[ks], Bm[ks], acc, 0, 0, 0);
        }
        int col = w*16 + lrow;
        #pragma unroll
        for (int r = 0; r < 4; ++r) {
            int row = mt*16 + (l >> 4)*4 + r;
            if (row < N1) As[row*132 + col] = acc0[r] + acc1[r];
        }
    }
    __syncthreads();
    const float2* X = (const float2*)(ws + OFF_HHAT) + (size_t)b*N1*64;
    float* cmp = ws + OFF_CMP + (h*64 + b)*200;
    int n0 = 1 + w;
    int pn = pre[n0];
    float2 xn = X[n0*64 + l], xp = X[post[n0]*64 + l];
    for (int n = n0; n <= 200; n += 8) {
        float2 cxn = xn, cxp = xp;
        int cpn = pn;
        int nn = n + 8;
        if (nn <= 200) {
            pn = pre[nn];
            xn = X[nn*64 + l];
            xp = X[post[nn]*64 + l];
        }
        float2 ap = *(const float2*)&As[cpn*132 + 2*l];
        float2 an = *(const float2*)&As[n*132 + 2*l];
        float v = ap.x*(cxn.x - cxp.x) + ap.y*(cxn.y - cxp.y) + an.x*cxp.x + an.y*cxp.y;
        #pragma unroll
        for (int off = 32; off; off >>= 1) v += __shfl_xor(v, off);
        if (l == 0) cmp[n - 1] = v;
    }
}

/* ---- removal MLP + softmax/argmax + q vectors (3-split out) ---- */
__global__ void krmq(const float* __restrict__ sel, const int* __restrict__ pre_action,
                     const float* __restrict__ w1, const float* __restrict__ b1,
                     const float* __restrict__ w2, const float* __restrict__ b2,
                     const float* __restrict__ w3, const float* __restrict__ b3,
                     const float* __restrict__ Mall, const float* __restrict__ hhat,
                     const float* __restrict__ cmpg, float* __restrict__ sc,
                     unsigned short* __restrict__ qs) {
    int b = blockIdx.x, t = threadIdx.x;  /* 128 */
    __shared__ float t1l[100];
    __shared__ int ppd[2];
    __shared__ float xp[128], xd[128];
    if (t < 100) {
        float f[12];
        #pragma unroll
        for (int h = 0; h < 4; ++h) {
            f[h]     = cmpg[(h*64 + b)*200 + t];
            f[4 + h] = cmpg[(h*64 + b)*200 + 100 + t];
        }
        #pragma unroll
        for (int s = 0; s < 4; ++s) f[8 + s] = sel[b*400 + s*100 + t];
        float h1[32];
        #pragma unroll
        for (int k = 0; k < 32; ++k) h1[k] = b1[k];
        #pragma unroll
        for (int j = 0; j < 12; ++j) {
            const float* wr = w1 + j*32;
            #pragma unroll
            for (int k = 0; k < 32; ++k) h1[k] += f[j]*wr[k];
        }
        #pragma unroll
        for (int k = 0; k < 32; ++k) h1[k] = fmaxf(h1[k], 0.f);
        float acc[32];
        #pragma unroll
        for (int j = 0; j < 32; ++j) acc[j] = b2[j];
        #pragma unroll
        for (int k = 0; k < 32; ++k) {
            const float* wr = w2 + k*32;
            #pragma unroll
            for (int j = 0; j < 32; ++j) acc[j] += h1[k]*wr[j];
        }
        float out = b3[0];
        #pragma unroll
        for (int j = 0; j < 32; ++j) out += fmaxf(acc[j], 0.f)*w3[j];
        t1l[t] = tanhf(out)*6.0f;
    }
    __syncthreads();
    if (t == 0) {
        if (pre_action[0] > 0) t1l[pre_action[b*2]] = NEGV;
        float M = -INFINITY; int a1 = 0;
        for (int i = 0; i < 100; ++i) if (t1l[i] > M) { M = t1l[i]; a1 = i; }
        float S = 0.f;
        for (int i = 0; i < 100; ++i) S += __expf(t1l[i] - M);
        int* ia = (int*)sc;
        ia[b] = a1;
        sc[192 + b] = -__logf(S);
        ppd[0] = 1 + a1; ppd[1] = 101 + a1;
    }
    __syncthreads();
    int pp = ppd[0], pd = ppd[1];
    const float* hb = hhat + (size_t)b*N1*DD;
    xp[t] = hb[pp*DD + t];
    xd[t] = hb[pd*DD + t];
    __syncthreads();
    int j = t;
    unsigned short* qsh = qs;
    unsigned short* qsm = qs + 131072;
    unsigned short* qsl = qs + 262144;
    #pragma unroll
    for (int h = 0; h < 4; ++h) {
        const float* M1 = Mall + (4 + h)*16384;
        const float* M2 = Mall + (8 + h)*16384;
        float a1p = 0, a2p = 0, a1d = 0, a2d = 0;
        for (int i = 0; i < 128; ++i) {
            float w1v = M1[i*128 + j], w2v = M2[i*128 + j];
            a1p += xp[i]*w1v; a1d += xd[i]*w1v;
            a2p += xp[i]*w2v; a2d += xd[i]*w2v;
        }
        float vals[4] = {a1p*QSCALE, a2p*QSCALE, a1d*QSCALE, a2d*QSCALE};
        #pragma unroll
        for (int ty = 0; ty < 4; ++ty) {
            size_t o = ((size_t)(ty*4 + h)*64 + b)*128 + j;
            float v = vals[ty];
            unsigned short hi = f2bf(v); float r1 = v - bf2f(hi);
            unsigned short md = f2bf(r1);
            qsh[o] = hi; qsm[o] = md; qsl[o] = f2bf(r1 - bf2f(md));
        }
    }
}

/* ---- rowH/colH via MFMA: 1D grid 128, XCD-affine b = bid & 63 ---- */
__global__ __launch_bounds__(256) void krowcol2(const int* __restrict__ sol_g,
                                                const float* __restrict__ w1,
                                                const float* __restrict__ b1,
                                                float* __restrict__ ws) {
    int bid = blockIdx.x;
    int b = bid & 63, zb = bid >> 6;
    int t = threadIdx.x, w = t >> 6, l = t & 63;
    __shared__ int sol[N1];
    __shared__ float carr[N1*17];
    __shared__ float w1s[512];
    __shared__ float b1s[32];
    if (t < N1) sol[t] = sol_g[b*N1 + t];
    for (int i = t; i < 512; i += 256) w1s[i] = w1[i];
    if (t < 32) b1s[t] = b1[t];
    __syncthreads();
    const unsigned short* qsh = (const unsigned short*)(ws + OFF_QS);
    const unsigned short* qsm = qsh + 131072;
    const unsigned short* qsl = qsh + 262144;
    const unsigned short* hbh = (const unsigned short*)(ws + OFF_HBF);
    const unsigned short* hbm = hbh + NELE;
    const unsigned short* hbl = hbh + 2u*NELE;
    int j = l & 15;
    short8v Bh[4], Bm[4], Bl[4];
    #pragma unroll
    for (int ks = 0; ks < 4; ++ks) {
        size_t qo = ((size_t)j*64 + b)*128 + ks*32 + (l >> 4)*8;
        Bh[ks] = *(const short8v*)(qsh + qo);
        Bm[ks] = *(const short8v*)(qsm + qo);
        Bl[ks] = *(const short8v*)(qsl + qo);
    }
    int mt0 = zb ? 7 : 0, mt1 = zb ? 13 : 7;
    for (int mt = mt0 + w; mt < mt1; mt += 4) {
        int rA = mt*16 + j; if (rA > 200) rA = 200;
        int rB = sol[rA];
        size_t o1 = ((size_t)b*N1 + rA)*DD;
        size_t o2 = ((size_t)b*N1 + rB)*DD;
        float4v acc1 = {0.f, 0.f, 0.f, 0.f};
        float4v acc2 = {0.f, 0.f, 0.f, 0.f};
        #pragma unroll
        for (int ks = 0; ks < 4; ++ks) {
            size_t k0 = ks*32 + (l >> 4)*8;
            short8v a1h = *(const short8v*)(hbh + o1 + k0);
            short8v a1m = *(const short8v*)(hbm + o1 + k0);
            short8v a1l = *(const short8v*)(hbl + o1 + k0);
            acc1 = __builtin_amdgcn_mfma_f32_16x16x32_bf16(a1h, Bh[ks], acc1, 0, 0, 0);
            acc1 = __builtin_amdgcn_mfma_f32_16x16x32_bf16(a1h, Bm[ks], acc1, 0, 0, 0);
            acc1 = __builtin_amdgcn_mfma_f32_16x16x32_bf16(a1m, Bh[ks], acc1, 0, 0, 0);
            acc1 = __builtin_amdgcn_mfma_f32_16x16x32_bf16(a1h, Bl[ks], acc1, 0, 0, 0);
            acc1 = __builtin_amdgcn_mfma_f32_16x16x32_bf16(a1l, Bh[ks], acc1, 0, 0, 0);
            acc1 = __builtin_amdgcn_mfma_f32_16x16x32_bf16(a1m, Bm[ks], acc1, 0, 0, 0);
            short8v a2h = *(const short8v*)(hbh + o2 + k0);
            short8v a2m = *(const short8v*)(hbm + o2 + k0);
            short8v a2l = *(const short8v*)(hbl + o2 + k0);
            acc2 = __builtin_amdgcn_mfma_f32_16x16x32_bf16(a2h, Bh[ks], acc2, 0, 0, 0);
            acc2 = __builtin_amdgcn_mfma_f32_16x16x32_bf16(a2h, Bm[ks], acc2, 0, 0, 0);
            acc2 = __builtin_amdgcn_mfma_f32_16x16x32_bf16(a2m, Bh[ks], acc2, 0, 0, 0);
            acc2 = __builtin_amdgcn_mfma_f32_16x16x32_bf16(a2h, Bl[ks], acc2, 0, 0, 0);
            acc2 = __builtin_amdgcn_mfma_f32_16x16x32_bf16(a2l, Bh[ks], acc2, 0, 0, 0);
            acc2 = __builtin_amdgcn_mfma_f32_16x16x32_bf16(a2m, Bm[ks], acc2, 0, 0, 0);
        }
        int kodd = (j >> 2) & 1;
        #pragma unroll
        for (int r = 0; r < 4; ++r) {
            int row = mt*16 + (l >> 4)*4 + r;
            if (row < N1) carr[row*17 + j] = kodd ? acc2[r] : acc1[r];
        }
    }
    __syncthreads();
    int rows0 = zb*112, nrows = zb ? 89 : 112;
    float* rowH = ws + OFF_ROWH;
    float* colH = ws + OFF_COLH;
    for (int idx = t; idx < nrows*32; idx += 256) {
        int n = rows0 + (idx >> 5), k = idx & 31;
        float rh = b1s[k], ch = 0.f;
        #pragma unroll
        for (int jj = 0; jj < 8; ++jj)  rh += carr[n*17 + jj]*w1s[jj*32 + k];
        #pragma unroll
        for (int jj = 8; jj < 16; ++jj) ch += carr[n*17 + jj]*w1s[jj*32 + k];
        rowH[((size_t)b*N1 + n)*32 + k] = rh;
        colH[((size_t)b*N1 + n)*32 + k] = ch;
    }
}

/* ---- t2: zero-LDS; 1D grid 1024, XCD-affine b = bid & 63 ---- */
__global__ __launch_bounds__(256) void kt2(
        const unsigned char* __restrict__ maskt,
        const float* __restrict__ rowH, const float* __restrict__ colH,
        const unsigned short* __restrict__ w2f,
        const float* __restrict__ b2g, const float* __restrict__ w3g,
        const float* __restrict__ b3g,
        float* __restrict__ pm, float* __restrict__ ps, int* __restrict__ pi) {
    int bid = blockIdx.x;
    int b = bid & 63, r_ = bid >> 6;   /* r_ 0..15 */
    int cy = r_ & 3, rz = r_ >> 2;
    int t = threadIdx.x, w = t >> 6, l = t & 63;
    int c0 = cy*64;
    int sg = l >> 4;
    const short8v* wf = (const short8v*)w2f;
    short8v w2hi0 = wf[0*64 + l];
    short8v w2lo0 = wf[1*64 + l];
    short8v w2hi1 = wf[2*64 + l];
    short8v w2lo1 = wf[3*64 + l];
    float4v b2f0 = *(const float4v*)(b2g + sg*4);
    float4v b2f1 = *(const float4v*)(b2g + 16 + sg*4);
    float4v w3f0 = *(const float4v*)(w3g + sg*4);
    float4v w3f1 = *(const float4v*)(w3g + 16 + sg*4);
    float b3v = b3g[0];
    float4v ca[4], cb[4];
    #pragma unroll
    for (int g = 0; g < 4; ++g) {
        int cc = c0 + 16*g + (l & 15); if (cc > 200) cc = 200;
        const float4v* cp = (const float4v*)(colH + ((size_t)b*N1 + cc)*32 + sg*8);
        ca[g] = cp[0]; cb[g] = cp[1];
    }
    int r0 = rz*52 + w*13;
    int c = c0 + l;
    bool cvalid = c < N1;
    int cS = cvalid ? c : 200;
    float m = -INFINITY, s = 0.f;
    int mi = 0x7fffffff;
    const float* rbase = rowH + (size_t)b*N1*32 + sg*8;
    union U8 { unsigned u[4]; short8v s8; };
    int rl0 = r0 > 200 ? 200 : r0;
    float4v ra = ((const float4v*)(rbase + (size_t)rl0*32))[0];
    float4v rb = ((const float4v*)(rbase + (size_t)rl0*32))[1];
    for (int rr = 0; rr < 13; ++rr) {
        int r = r0 + rr;
        int rn = r + 1; if (rn > 200) rn = 200;
        const float4v* rpn = (const float4v*)(rbase + (size_t)rn*32);
        float4v ra_n = rpn[0], rb_n = rpn[1];
        int rS = r > 200 ? 200 : r;
        unsigned char mv = maskt[(size_t)b*NN + (size_t)rS*N1 + cS];
        float outv = 0.f;
        #pragma unroll
        for (int g = 0; g < 4; ++g) {
            float h[8];
            #pragma unroll
            for (int e = 0; e < 4; ++e) {
                h[e]   = fmaxf(ra[e] + ca[g][e], 0.f);
                h[4+e] = fmaxf(rb[e] + cb[g][e], 0.f);
            }
            U8 B, L;
            #pragma unroll
            for (int e = 0; e < 4; ++e) {
                unsigned ph, pl;
                asm("v_cvt_pk_bf16_f32 %0, %1, %2" : "=v"(ph) : "v"(h[2*e]), "v"(h[2*e+1]));
                float h0 = __uint_as_float(ph << 16);
                float h1f = __uint_as_float(ph & 0xffff0000u);
                float l0 = h[2*e] - h0, l1 = h[2*e+1] - h1f;
                asm("v_cvt_pk_bf16_f32 %0, %1, %2" : "=v"(pl) : "v"(l0), "v"(l1));
                B.u[e] = ph; L.u[e] = pl;
            }
            float4v a0 = b2f0, a1 = b2f1;
            a0 = __builtin_amdgcn_mfma_f32_16x16x32_bf16(w2hi0, B.s8, a0, 0, 0, 0);
            a1 = __builtin_amdgcn_mfma_f32_16x16x32_bf16(w2hi1, B.s8, a1, 0, 0, 0);
            a0 = __builtin_amdgcn_mfma_f32_16x16x32_bf16(w2hi0, L.s8, a0, 0, 0, 0);
            a1 = __builtin_amdgcn_mfma_f32_16x16x32_bf16(w2hi1, L.s8, a1, 0, 0, 0);
            a0 = __builtin_amdgcn_mfma_f32_16x16x32_bf16(w2lo0, B.s8, a0, 0, 0, 0);
            a1 = __builtin_amdgcn_mfma_f32_16x16x32_bf16(w2lo1, B.s8, a1, 0, 0, 0);
            float p = 0.f;
            #pragma unroll
            for (int reg = 0; reg < 4; ++reg) {
                p += fmaxf(a0[reg], 0.f)*w3f0[reg];
                p += fmaxf(a1[reg], 0.f)*w3f1[reg];
            }
            p += __shfl_xor(p, 16);
            p += __shfl_xor(p, 32);
            if (sg == g) outv = p + b3v;
        }
        ra = ra_n; rb = rb_n;
        float ex = __expf(2.f*outv);
        float tv = 6.f - 12.f/(ex + 1.f);
        if (mv) tv = NEGV;
        if ((r < N1) && cvalid) {
            if (tv > m) { s = s*__expf(m - tv) + 1.f; m = tv; mi = r*N1 + c; }
            else        { s += __expf(tv - m); }
        }
    }
    #pragma unroll
    for (int off = 1; off < 64; off <<= 1) {
        float om = __shfl_xor(m, off);
        float os = __shfl_xor(s, off);
        int oi = __shfl_xor(mi, off);
        float M2 = fmaxf(m, om);
        float sn = (s > 0.f ? s*__expf(m - M2) : 0.f)
                 + (os > 0.f ? os*__expf(om - M2) : 0.f);
        int in_;
        if (m > om) in_ = mi; else if (om > m) in_ = oi; else in_ = (mi < oi ? mi : oi);
        m = M2; s = sn; mi = in_;
    }
    if (l == 0) {
        int slot = b*64 + cy*16 + rz*4 + w;
        pm[slot] = m; ps[slot] = s; pi[slot] = mi;
    }
}

/* ---- final reduce + outputs ---- */
__global__ void kfinal(float* __restrict__ out, const float* __restrict__ pm,
                       const float* __restrict__ ps, const int* __restrict__ pi,
                       const float* __restrict__ sc) {
    int b = blockIdx.x, lane = threadIdx.x;  /* 64 */
    float m = pm[b*64 + lane];
    float s = ps[b*64 + lane];
    int mi = pi[b*64 + lane];
    #pragma unroll
    for (int off = 1; off < 64; off <<= 1) {
        float om = __shfl_xor(m, off);
        float os = __shfl_xor(s, off);
        int oi = __shfl_xor(mi, off);
        float M2 = fmaxf(m, om);
        float sn = (s > 0.f ? s*__expf(m - M2) : 0.f)
                 + (os > 0.f ? os*__expf(om - M2) : 0.f);
        int in_;
        if (m > om) in_ = mi; else if (om > m) in_ = oi; else in_ = (mi < oi ? mi : oi);
        m = M2; s = sn; mi = in_;
    }
    if (lane == 0) {
        float ll2 = -__logf(s);
        const int* ia = (const int*)sc;
        out[b*3 + 0] = (float)ia[b];
        out[b*3 + 1] = (float)(mi / N1);
        out[b*3 + 2] = (float)(mi % N1);
        out[192 + b] = sc[192 + b] + ll2;
    }
}

extern "C" void kernel_launch(void* const* d_in, const int* in_sizes, int n_in,
                              void* d_out, int out_size, void* d_ws, size_t ws_size,
                              hipStream_t stream) {
    const float* h_wave    = (const float*)d_in[0];
    const int*   solution  = (const int*)d_in[1];
    const float* sel       = (const float*)d_in[2];
    const int*   pre_act   = (const int*)d_in[3];
    const unsigned char* maskt = (const unsigned char*)d_in[4];
    const float* Wn    = (const float*)d_in[5];
    const float* Wg    = (const float*)d_in[6];
    const float* rmWQ  = (const float*)d_in[7];
    const float* rmWK  = (const float*)d_in[8];
    const float* rm_w1 = (const float*)d_in[9];
    const float* rm_b1 = (const float*)d_in[10];
    const float* rm_w2 = (const float*)d_in[11];
    const float* rm_b2 = (const float*)d_in[12];
    const float* rm_w3 = (const float*)d_in[13];
    const float* rm_b3 = (const float*)d_in[14];
    const float* i1Wq  = (const float*)d_in[15];
    const float* i1Wk  = (const float*)d_in[16];
    const float* i2Wq  = (const float*)d_in[17];
    const float* i2Wk  = (const float*)d_in[18];
    const float* re_w1 = (const float*)d_in[19];
    const float* re_b1 = (const float*)d_in[20];
    const float* re_w2 = (const float*)d_in[21];
    const float* re_b2 = (const float*)d_in[22];
    const float* re_w3 = (const float*)d_in[23];
    const float* re_b3 = (const float*)d_in[24];
    float* ws = (float*)d_ws;
    float* out = (float*)d_out;

    kprep2<<<dim3(12, 4, 4), dim3(128), 0, stream>>>(rmWQ, rmWK, i1Wq, i1Wk, i2Wq, i2Wk, ws);
    kfrag<<<dim3(417), dim3(64), 0, stream>>>(Wn, re_w2, ws);
    khw3<<<dim3(64*101), dim3(256), 0, stream>>>(h_wave, ws);
    khmaxg2<<<dim3(64), dim3(128), 0, stream>>>(h_wave, Wg, ws + OFF_G);
    khhat3<<<dim3(3328), dim3(64), 0, stream>>>(ws + OFF_G, ws);
    kAC<<<dim3(256), dim3(512), 0, stream>>>(solution, ws);
    krmq<<<dim3(64), dim3(128), 0, stream>>>(sel, pre_act, rm_w1, rm_b1, rm_w2, rm_b2,
                                             rm_w3, rm_b3, ws + OFF_M, ws + OFF_HHAT,
                                             ws + OFF_CMP, ws + OFF_SC,
                                             (unsigned short*)(ws + OFF_QS));
    krowcol2<<<dim3(128), dim3(256), 0, stream>>>(solution, re_w1, re_b1, ws);
    kt2<<<dim3(1024), dim3(256), 0, stream>>>(maskt, ws + OFF_ROWH, ws + OFF_COLH,
                                              (const unsigned short*)(ws + OFF_W2F),
                                              re_b2, re_w3, re_b3,
                                              ws + OFF_PM, ws + OFF_PS,
                                              (int*)(ws + OFF_PI));
    kfinal<<<dim3(64), dim3(64), 0, stream>>>(out, ws + OFF_PM, ws + OFF_PS,
                                              (const int*)(ws + OFF_PI), ws + OFF_SC);
}